// Round 4
// baseline (27325.150 us; speedup 1.0000x reference)
//
#include <hip/hip_runtime.h>

#define DEV __device__ __forceinline__

DEV float fast_rcp(float x) {
#if __has_builtin(__builtin_amdgcn_rcpf)
  return __builtin_amdgcn_rcpf(x);
#else
  return 1.0f / x;
#endif
}
DEV float sigm(float x) { return fast_rcp(1.0f + __expf(-x)); }
DEV float tanh_f(float x) {
  float e = __expf(-2.0f * fabsf(x));
  float t = 1.0f - 2.0f * e * fast_rcp(1.0f + e);
  return copysignf(t, x);
}
DEV float lrelu(float x) { return x > 0.0f ? x : 0.01f * x; }

DEV float wave_sum(float v) {
#pragma unroll
  for (int m = 32; m; m >>= 1) v += __shfl_xor(v, m);
  return v;
}
DEV float wave_max(float v) {
#pragma unroll
  for (int m = 32; m; m >>= 1) v = fmaxf(v, __shfl_xor(v, m));
  return v;
}
DEV float dot4(float4 w, float4 x, float acc) {
  acc = fmaf(w.x, x.x, acc);
  acc = fmaf(w.y, x.y, acc);
  acc = fmaf(w.z, x.z, acc);
  acc = fmaf(w.w, x.w, acc);
  return acc;
}

// ---------------------------------------------------------------------------
// Persistent-GRU encoder, R7. Diagnosis history:
//  R4 (256thr, SPW5, b32 weights): 1510us, LDS-return-path bound (model:
//     ~25k clk/CU/step LDS vs ~6.3k VALU/SIMD -> VALUBusy 47%). Clean codegen.
//  R5 (512thr cap128) / R6 (640thr cap168): SPILLED (14-19GB scratch HBM).
//     Lesson: ANY forced VGPR cap on this body spills; low VGPR_Count + huge
//     FETCH_SIZE is the signature.
// R7 changes, staying in the no-cap codegen envelope:
//  * quad-packed b128 weight layout W4[q][j][12]: lane j reads its 3 gates x
//    4 k-rows as 3 ds_read_b128 (vs 12 ds_read_b32). Start banks (j*12)%32
//    tile all 32 banks across each 8-lane group -> conflict-free.
//  * SPW=10 x 4 waves x 256 blocks = 40 seqs/block -> ONE balanced round,
//    and weight re-reads amortize over 10 seqs.
//  * __launch_bounds__(256,1): explicit 1-wave/EU floor -> VGPR budget 512,
//    nothing to spill against (occupancy is LDS-bound at 1 block/CU anyway).
//  * LDS: Whh0 quads 0..13 + W1x/W1h quads (46 quads) + state + x-stage =
//    162,816 B; Whh0 quads 14,15 + Wih0 (18 dw) live in registers.
// lane = hidden unit j (owns all 3 gates -> no shuffles, no in-loop barriers;
// wave-private LDS state, program-order ds dependencies).
// ---------------------------------------------------------------------------
constexpr int E_SPW = 10;
constexpr int E_WAVES = 4;
// LDS dword offsets
constexpr int L_W0H = 0;                       // Whh0 quads 0..13: 14*768
constexpr int L_W1X = 10752;                   // Wih1 quads 0..15
constexpr int L_W1H = 23040;                   // Whh1 quads 0..15
constexpr int L_HB = 35328;                    // + wave*1280: [s][128] h0|h1
constexpr int L_XS = 40448;                    // + wave*64: x stage (60 used)
constexpr int E_DW = 40704;
constexpr int E_LDS = E_DW * 4;                // 162,816 B <= 160 KiB

__launch_bounds__(256, 1)
__global__ void gru2_enc(const float* __restrict__ x,      // [10240][60][6]
                         const float* __restrict__ wx0b,   // [6][192] j3-interleave
                         const float* __restrict__ w4h0,   // [16][64][12] quads
                         const float* __restrict__ w4x1,   // [16][64][12]
                         const float* __restrict__ w4h1,   // [16][64][12]
                         const float* __restrict__ bih0, const float* __restrict__ bhh0,
                         const float* __restrict__ bih1, const float* __restrict__ bhh1,
                         float* __restrict__ h_out) {      // [10240][64]
  extern __shared__ float lds[];
  const int tid = threadIdx.x;
  const int wave = tid >> 6;
  const int j = tid & 63;
  const int j3 = j * 3;
  const int j12 = j * 12;
  const int HBW = L_HB + wave * (E_SPW * 128);
  const int XSW = L_XS + wave * 64;

  // cooperative weight load into LDS (coalesced float4)
  {
    const float4* s0 = (const float4*)w4h0;    // quads 0..13 = first 10752 dw
    for (int i = tid; i < 10752 / 4; i += 256) ((float4*)(lds + L_W0H))[i] = s0[i];
    const float4* s1 = (const float4*)w4x1;
    for (int i = tid; i < 12288 / 4; i += 256) ((float4*)(lds + L_W1X))[i] = s1[i];
    const float4* s2 = (const float4*)w4h1;
    for (int i = tid; i < 12288 / 4; i += 256) ((float4*)(lds + L_W1H))[i] = s2[i];
  }
  // register weights: Wih0 (6 rows x 3) and Whh0 quads 14,15
  float wx0[6][3];
#pragma unroll
  for (int k = 0; k < 6; ++k)
#pragma unroll
    for (int g = 0; g < 3; ++g) wx0[k][g] = wx0b[k * 192 + j3 + g];
  const float4 whA14 = *(const float4*)&w4h0[(14 * 64 + j) * 12];
  const float4 whB14 = *(const float4*)&w4h0[(14 * 64 + j) * 12 + 4];
  const float4 whC14 = *(const float4*)&w4h0[(14 * 64 + j) * 12 + 8];
  const float4 whA15 = *(const float4*)&w4h0[(15 * 64 + j) * 12];
  const float4 whB15 = *(const float4*)&w4h0[(15 * 64 + j) * 12 + 4];
  const float4 whC15 = *(const float4*)&w4h0[(15 * 64 + j) * 12 + 8];

  const float br0 = bih0[j] + bhh0[j];
  const float bz0 = bih0[64 + j] + bhh0[64 + j];
  const float bxn0 = bih0[128 + j];
  const float bhn0 = bhh0[128 + j];
  const float br1 = bih1[j] + bhh1[j];
  const float bz1 = bih1[64 + j] + bhh1[64 + j];
  const float bxn1 = bih1[128 + j];
  const float bhn1 = bhh1[128 + j];

  float h0r[E_SPW], h1r[E_SPW];
#pragma unroll
  for (int s = 0; s < E_SPW; ++s) {
    h0r[s] = 0.0f; h1r[s] = 0.0f;
    lds[HBW + s * 128 + j] = 0.0f;
    lds[HBW + s * 128 + 64 + j] = 0.0f;
  }
  __syncthreads();  // the only barrier (weights + zeroed state visible)

  const int seq0 = blockIdx.x * (E_WAVES * E_SPW) + wave * E_SPW;
  // x loader: lane li<60 covers (seq si, component ci)
  const int si = j / 6;            // wave-lane -> seq index (0..9 for li<60)
  const int ci = j - si * 6;
  const bool xlane = (j < 60);
  const float* xg = x + (size_t)(seq0 + si) * 360 + ci;

// 16-quad 64-wide dot: weights b128 from LDS, h b128 broadcasts from LDS
#define DOT16(WB, HOFF, AN)                                                   \
  _Pragma("unroll") for (int q = 0; q < 16; ++q) {                            \
    const float4 wA = *(const float4*)&lds[(WB) + q * 768 + j12];             \
    const float4 wB = *(const float4*)&lds[(WB) + q * 768 + j12 + 4];         \
    const float4 wC = *(const float4*)&lds[(WB) + q * 768 + j12 + 8];         \
    _Pragma("unroll") for (int s = 0; s < E_SPW; ++s) {                       \
      const float4 hv = *(const float4*)&lds[HBW + s * 128 + (HOFF) + q * 4]; \
      ar[s] = fmaf(wA.x, hv.x, ar[s]);                                        \
      az[s] = fmaf(wA.y, hv.x, az[s]);                                        \
      AN[s] = fmaf(wA.z, hv.x, AN[s]);                                        \
      ar[s] = fmaf(wA.w, hv.y, ar[s]);                                        \
      az[s] = fmaf(wB.x, hv.y, az[s]);                                        \
      AN[s] = fmaf(wB.y, hv.y, AN[s]);                                        \
      ar[s] = fmaf(wB.z, hv.z, ar[s]);                                        \
      az[s] = fmaf(wB.w, hv.z, az[s]);                                        \
      AN[s] = fmaf(wC.x, hv.z, AN[s]);                                        \
      ar[s] = fmaf(wC.y, hv.w, ar[s]);                                        \
      az[s] = fmaf(wC.z, hv.w, az[s]);                                        \
      AN[s] = fmaf(wC.w, hv.w, AN[s]);                                        \
    }                                                                         \
  }

// one register-resident quad (Whh0 q14/q15)
#define REG_QUAD(QA, QB, QC, Q, AN)                                           \
  _Pragma("unroll") for (int s = 0; s < E_SPW; ++s) {                         \
    const float4 hv = *(const float4*)&lds[HBW + s * 128 + (Q) * 4];          \
    ar[s] = fmaf(QA.x, hv.x, ar[s]);                                          \
    az[s] = fmaf(QA.y, hv.x, az[s]);                                          \
    AN[s] = fmaf(QA.z, hv.x, AN[s]);                                          \
    ar[s] = fmaf(QA.w, hv.y, ar[s]);                                          \
    az[s] = fmaf(QB.x, hv.y, az[s]);                                          \
    AN[s] = fmaf(QB.y, hv.y, AN[s]);                                          \
    ar[s] = fmaf(QB.z, hv.z, ar[s]);                                          \
    az[s] = fmaf(QB.w, hv.z, az[s]);                                          \
    AN[s] = fmaf(QC.x, hv.z, AN[s]);                                          \
    ar[s] = fmaf(QC.y, hv.w, ar[s]);                                          \
    az[s] = fmaf(QC.z, hv.w, az[s]);                                          \
    AN[s] = fmaf(QC.w, hv.w, AN[s]);                                          \
  }

  float xcur = xlane ? xg[0] : 0.0f;  // t = 0

  for (int t = 0; t < 60; ++t) {
    // prefetch next step's x component (consumed next iteration)
    float xnext = (xlane && t + 1 < 60) ? xg[(size_t)(t + 1) * 6] : 0.0f;

    float ar[E_SPW], az[E_SPW], anx[E_SPW], anh[E_SPW];
#pragma unroll
    for (int s = 0; s < E_SPW; ++s) { ar[s] = 0.f; az[s] = 0.f; anx[s] = 0.f; anh[s] = 0.f; }

    // ---- layer0 h-part: quads 0..13 from LDS, 14..15 from registers
#pragma unroll
    for (int q = 0; q < 14; ++q) {
      const float4 wA = *(const float4*)&lds[L_W0H + q * 768 + j12];
      const float4 wB = *(const float4*)&lds[L_W0H + q * 768 + j12 + 4];
      const float4 wC = *(const float4*)&lds[L_W0H + q * 768 + j12 + 8];
#pragma unroll
      for (int s = 0; s < E_SPW; ++s) {
        const float4 hv = *(const float4*)&lds[HBW + s * 128 + q * 4];
        ar[s] = fmaf(wA.x, hv.x, ar[s]);
        az[s] = fmaf(wA.y, hv.x, az[s]);
        anh[s] = fmaf(wA.z, hv.x, anh[s]);
        ar[s] = fmaf(wA.w, hv.y, ar[s]);
        az[s] = fmaf(wB.x, hv.y, az[s]);
        anh[s] = fmaf(wB.y, hv.y, anh[s]);
        ar[s] = fmaf(wB.z, hv.z, ar[s]);
        az[s] = fmaf(wB.w, hv.z, az[s]);
        anh[s] = fmaf(wC.x, hv.z, anh[s]);
        ar[s] = fmaf(wC.y, hv.w, ar[s]);
        az[s] = fmaf(wC.z, hv.w, az[s]);
        anh[s] = fmaf(wC.w, hv.w, anh[s]);
      }
    }
    REG_QUAD(whA14, whB14, whC14, 14, anh)
    REG_QUAD(whA15, whB15, whC15, 15, anh)

    // ---- stage x[t] (wave-private; ds ordering by program order)
    if (xlane) lds[XSW + j] = xcur;
    // ---- layer0 x-part from register weights + staged broadcasts
#pragma unroll
    for (int s = 0; s < E_SPW; ++s) {
      const float2 xa = *(const float2*)&lds[XSW + s * 6];
      const float2 xb = *(const float2*)&lds[XSW + s * 6 + 2];
      const float2 xc = *(const float2*)&lds[XSW + s * 6 + 4];
      ar[s] = fmaf(wx0[0][0], xa.x, ar[s]);
      az[s] = fmaf(wx0[0][1], xa.x, az[s]);
      anx[s] = fmaf(wx0[0][2], xa.x, anx[s]);
      ar[s] = fmaf(wx0[1][0], xa.y, ar[s]);
      az[s] = fmaf(wx0[1][1], xa.y, az[s]);
      anx[s] = fmaf(wx0[1][2], xa.y, anx[s]);
      ar[s] = fmaf(wx0[2][0], xb.x, ar[s]);
      az[s] = fmaf(wx0[2][1], xb.x, az[s]);
      anx[s] = fmaf(wx0[2][2], xb.x, anx[s]);
      ar[s] = fmaf(wx0[3][0], xb.y, ar[s]);
      az[s] = fmaf(wx0[3][1], xb.y, az[s]);
      anx[s] = fmaf(wx0[3][2], xb.y, anx[s]);
      ar[s] = fmaf(wx0[4][0], xc.x, ar[s]);
      az[s] = fmaf(wx0[4][1], xc.x, az[s]);
      anx[s] = fmaf(wx0[4][2], xc.x, anx[s]);
      ar[s] = fmaf(wx0[5][0], xc.y, ar[s]);
      az[s] = fmaf(wx0[5][1], xc.y, az[s]);
      anx[s] = fmaf(wx0[5][2], xc.y, anx[s]);
    }
    // ---- layer0 epilogue: lane j owns all 3 gates of unit j
#pragma unroll
    for (int s = 0; s < E_SPW; ++s) {
      float r = sigm(ar[s] + br0);
      float z = sigm(az[s] + bz0);
      float n = tanh_f(anx[s] + bxn0 + r * (anh[s] + bhn0));
      float h0 = (1.0f - z) * n + z * h0r[s];
      h0r[s] = h0;
      lds[HBW + s * 128 + j] = h0;
    }

#pragma unroll
    for (int s = 0; s < E_SPW; ++s) { ar[s] = 0.f; az[s] = 0.f; anx[s] = 0.f; anh[s] = 0.f; }
    // ---- layer1 x-part over fresh h0, then h-part over h1_old
    DOT16(L_W1X, 0, anx)
    DOT16(L_W1H, 64, anh)
    // ---- layer1 epilogue
#pragma unroll
    for (int s = 0; s < E_SPW; ++s) {
      float r = sigm(ar[s] + br1);
      float z = sigm(az[s] + bz1);
      float n = tanh_f(anx[s] + bxn1 + r * (anh[s] + bhn1));
      float h1 = (1.0f - z) * n + z * h1r[s];
      h1r[s] = h1;
      lds[HBW + s * 128 + 64 + j] = h1;
    }
    xcur = xnext;
  }

#pragma unroll
  for (int s = 0; s < E_SPW; ++s)
    h_out[(size_t)(seq0 + s) * 64 + j] = h1r[s];
#undef DOT16
#undef REG_QUAD
}

// ---------------------------------------------------------------------------
// Single-layer GRU for the ALSTM (I = 64). 8 waves/block (2/SIMD), 1 seq per
// wave -> grid 64 blocks. Unchanged from R3 (validated; small share of time).
// ---------------------------------------------------------------------------
constexpr int A_W_DW = 128 * 192;  // 24576
constexpr int A_WAVES = 8;
constexpr int A_LDS = (A_W_DW + A_WAVES * 128) * 4;  // 102400 B

__launch_bounds__(512, 2)
__global__ void gru1(const float* __restrict__ xin,  // [N][T][64]
                     const float* __restrict__ w3,   // [128][192]
                     const float* __restrict__ bih, const float* __restrict__ bhh,
                     int T,
                     float* __restrict__ rout) {     // [N][T][64]
  extern __shared__ float lds[];
  const int tid = threadIdx.x;
  const int wave = tid >> 6;
  const int j = tid & 63;
  const int j3 = j * 3;
  const int XB = A_W_DW + wave * 128;  // [0..63]=x_t, [64..127]=h

  {
    const float4* sp = (const float4*)w3;
    for (int i = tid; i < A_W_DW / 4; i += 512) ((float4*)lds)[i] = sp[i];
  }
  const float br = bih[j] + bhh[j];
  const float bz = bih[64 + j] + bhh[64 + j];
  const float bxn = bih[128 + j];
  const float bhn = bhh[128 + j];

  float hr = 0.0f;
  lds[XB + 64 + j] = 0.0f;
  __syncthreads();

  const int seq = blockIdx.x * A_WAVES + wave;
  const float* xs = xin + (size_t)seq * T * 64;

#define A_QUAD(WROW0, HOFF, AN)                                            \
  {                                                                        \
    float4 hv = *(const float4*)&lds[XB + (HOFF)];                         \
    _Pragma("unroll") for (int c = 0; c < 4; ++c) {                        \
      const float wr = lds[((WROW0) + c) * 192 + j3];                      \
      const float wz = lds[((WROW0) + c) * 192 + j3 + 1];                  \
      const float wn = lds[((WROW0) + c) * 192 + j3 + 2];                  \
      const float hc = (c == 0) ? hv.x : (c == 1) ? hv.y                   \
                      : (c == 2) ? hv.z : hv.w;                            \
      ar = fmaf(wr, hc, ar);                                               \
      az = fmaf(wz, hc, az);                                               \
      AN = fmaf(wn, hc, AN);                                               \
    }                                                                      \
  }

  float xcur = xs[j];  // t = 0
  for (int t = 0; t < T; ++t) {
    float xnext = (t + 1 < T) ? xs[(size_t)(t + 1) * 64 + j] : 0.0f;
    lds[XB + j] = xcur;  // wave-private; ordered by lgkmcnt

    float ar = 0.f, az = 0.f, anx = 0.f, anh = 0.f;
#pragma unroll
    for (int kq = 0; kq < 16; ++kq) A_QUAD(kq * 4, kq * 4, anx);        // input
#pragma unroll
    for (int kq = 0; kq < 16; ++kq) A_QUAD(64 + kq * 4, 64 + kq * 4, anh);  // rec

    float r = sigm(ar + br);
    float z = sigm(az + bz);
    float n = tanh_f(anx + bxn + r * (anh + bhn));
    float h = (1.0f - z) * n + z * hr;
    hr = h;
    lds[XB + 64 + j] = h;
    rout[((size_t)seq * T + t) * 64 + j] = h;
    xcur = xnext;
  }
#undef A_QUAD
}

// ---------------------------------------------------------------------------
// Weight prep. Sections (8 blocks each):
//  0: wx0   [6][192] j3-interleave  <- Wih0 (192x6)
//  1: w4h0  [16][64][12] quad-pack  <- Whh0 (192x64)
//  2: w4x1  [16][64][12]            <- Wih1 (192x64)
//  3: w4h1  [16][64][12]            <- Whh1 (192x64)
//  4: a0    [128][192] w3-format    <- aWih0+aWhh0
//  5: a1    [128][192] w3-format    <- aWih1+aWhh1
// quad-pack: dst[(q*64+j)*12 + kk*3+g] = W[(g*64+j)*64 + q*4+kk]
// ---------------------------------------------------------------------------
__global__ void w3_prep(const float* __restrict__ Wih0, const float* __restrict__ Whh0,
                        const float* __restrict__ Wih1, const float* __restrict__ Whh1,
                        const float* __restrict__ aWih0, const float* __restrict__ aWhh0,
                        const float* __restrict__ aWih1, const float* __restrict__ aWhh1,
                        float* __restrict__ d_wx0, float* __restrict__ d_w4h0,
                        float* __restrict__ d_w4x1, float* __restrict__ d_w4h1,
                        float* __restrict__ d_a0, float* __restrict__ d_a1) {
  const int sec = blockIdx.x >> 3;
  const int bi = blockIdx.x & 7;

  if (sec == 0) {  // wx0: [6][192], idx = k*192 + j*3 + g
    for (int idx = bi * blockDim.x + threadIdx.x; idx < 6 * 192; idx += 8 * blockDim.x) {
      const int k = idx / 192;
      const int rem = idx - k * 192;
      const int jj = rem / 3;
      const int g = rem - jj * 3;
      d_wx0[idx] = Wih0[(g * 64 + jj) * 6 + k];
    }
  } else if (sec <= 3) {  // quad-pack sections
    const float* src = (sec == 1) ? Whh0 : (sec == 2) ? Wih1 : Whh1;
    float* dst = (sec == 1) ? d_w4h0 : (sec == 2) ? d_w4x1 : d_w4h1;
    for (int idx = bi * blockDim.x + threadIdx.x; idx < 12288; idx += 8 * blockDim.x) {
      const int q = idx / 768;
      const int rem = idx - q * 768;
      const int jj = rem / 12;
      const int r = rem - jj * 12;
      const int kk = r / 3;
      const int g = r - kk * 3;
      dst[idx] = src[(g * 64 + jj) * 64 + q * 4 + kk];
    }
  } else {  // ALSTM w3 format: [128][192]
    const float* Wih = (sec == 4) ? aWih0 : aWih1;
    const float* Whh = (sec == 4) ? aWhh0 : aWhh1;
    float* dst = (sec == 4) ? d_a0 : d_a1;
    for (int idx = bi * blockDim.x + threadIdx.x; idx < 128 * 192; idx += 8 * blockDim.x) {
      const int k = idx / 192;
      const int rem = idx - k * 192;
      const int jj = rem / 3;
      const int g = rem - jj * 3;
      dst[idx] = (k < 64) ? Wih[(g * 64 + jj) * 64 + k] : Whh[(g * 64 + jj) * 64 + (k - 64)];
    }
  }
}

// ---------------------------------------------------------------------------
// GAT algebraic prep
// ---------------------------------------------------------------------------
__global__ void gat_prep(const float* __restrict__ tW, const float* __restrict__ tb,
                         const float* __restrict__ a, float* __restrict__ vbuf) {
  const int d = threadIdx.x;  // 64 threads
  float vd = 0.0f, vs = 0.0f;
  for (int e = 0; e < 64; ++e) {
    float w = tW[e * 64 + d];
    vd = fmaf(w, a[e], vd);
    vs = fmaf(w, a[64 + e], vs);
  }
  vbuf[d] = vd;
  vbuf[64 + d] = vs;
  if (d == 0) {
    float cd = 0.0f, cs = 0.0f;
    for (int e = 0; e < 64; ++e) {
      cd = fmaf(tb[e], a[e], cd);
      cs = fmaf(tb[e], a[64 + e], cs);
    }
    vbuf[128] = cd;
    vbuf[129] = cs;
  }
}

__global__ void gat_svals(const float* __restrict__ h_enc, const float* __restrict__ vbuf,
                          float* __restrict__ s_src, float* __restrict__ s_dst) {
  const int wave = (blockIdx.x * blockDim.x + threadIdx.x) >> 6;
  const int lane = threadIdx.x & 63;
  float h = h_enc[(size_t)wave * 64 + lane];
  float pd = h * vbuf[lane];
  float ps = h * vbuf[64 + lane];
  pd = wave_sum(pd);
  ps = wave_sum(ps);
  if (lane == 0) {
    s_dst[wave] = pd + vbuf[128];
    s_src[wave] = ps + vbuf[129];
  }
}

// ---------------------------------------------------------------------------
// Dense all-pairs attention per group k (m=512)
// ---------------------------------------------------------------------------
__launch_bounds__(256)
__global__ void gat_attn(const float* __restrict__ h_enc,
                         const float* __restrict__ s_src,
                         const float* __restrict__ s_dst,
                         float* __restrict__ hout) {
  const int k = blockIdx.x >> 7;
  const int tile = blockIdx.x & 127;
  const int wv = threadIdx.x >> 6;
  const int lane = threadIdx.x & 63;
  const int i = tile * 4 + wv;
  __shared__ float sdbuf[512];
  __shared__ __align__(16) float pbuf[4][512];

  for (int u = threadIdx.x; u < 512; u += 256) sdbuf[u] = s_dst[k * 512 + u];
  __syncthreads();

  const float si = s_src[k * 512 + i];
  float ev[8];
  float mx = -1e30f;
#pragma unroll
  for (int u = 0; u < 8; ++u) {
    ev[u] = lrelu(si + sdbuf[lane + u * 64]);
    mx = fmaxf(mx, ev[u]);
  }
  mx = wave_max(mx);
  float lsum = 0.0f;
#pragma unroll
  for (int u = 0; u < 8; ++u) {
    float p = __expf(ev[u] - mx);
    pbuf[wv][lane + u * 64] = p;
    lsum += p;
  }
  lsum = wave_sum(lsum);
  const float inv = fast_rcp(lsum);

  const float* hk = h_enc + (size_t)k * 512 * 64;
  const float4* pv = (const float4*)pbuf[wv];
  float acc0 = 0.0f, acc1 = 0.0f;
#pragma unroll 2
  for (int jj = 0; jj < 128; ++jj) {
    float4 p = pv[jj];
    const float* hp = hk + (size_t)(jj * 4) * 64 + lane;
    acc0 = fmaf(p.x, hp[0], acc0);
    acc1 = fmaf(p.y, hp[64], acc1);
    acc0 = fmaf(p.z, hp[128], acc0);
    acc1 = fmaf(p.w, hp[192], acc1);
  }
  hout[((size_t)k * 512 + i) * 64 + lane] =
      (acc0 + acc1) * inv + hk[(size_t)i * 64 + lane];
}

// ---------------------------------------------------------------------------
// Post-GAT transform + pred head + ALSTM input transform
// ---------------------------------------------------------------------------
__launch_bounds__(256)
__global__ void gat_out(const float* __restrict__ hin,
                        const float* __restrict__ fcW, const float* __restrict__ fcb,
                        const float* __restrict__ fcoW, const float* __restrict__ fcob,
                        const float* __restrict__ alinW, const float* __restrict__ alinb,
                        float* __restrict__ zout, float* __restrict__ pred) {
  const int wv = threadIdx.x >> 6;
  const int lane = threadIdx.x & 63;
  const int n = blockIdx.x * 4 + wv;  // [0,10240)
  const int k = n >> 9;
  const int i = n & 511;
  __shared__ __align__(16) float rbuf[4][64];
  __shared__ __align__(16) float rbuf2[4][64];

  float4 fw[16], aw[16];
  {
    const float4* p1 = (const float4*)(fcW + lane * 64);
    const float4* p2 = (const float4*)(alinW + lane * 64);
#pragma unroll
    for (int kk = 0; kk < 16; ++kk) fw[kk] = p1[kk];
#pragma unroll
    for (int kk = 0; kk < 16; ++kk) aw[kk] = p2[kk];
  }

  rbuf[wv][lane] = hin[(size_t)n * 64 + lane];
  float h2 = fcb[lane];
  const float4* rv = (const float4*)rbuf[wv];
#pragma unroll
  for (int kk = 0; kk < 16; ++kk) h2 = dot4(fw[kk], rv[kk], h2);

  if (k == 19) {
    float pv = lrelu(h2) * fcoW[lane];
    pv = wave_sum(pv);
    if (lane == 0) pred[i] = pv + fcob[0];
  }

  rbuf2[wv][lane] = h2;
  float zz = alinb[lane];
  const float4* rv2 = (const float4*)rbuf2[wv];
#pragma unroll
  for (int kk = 0; kk < 16; ++kk) zz = dot4(aw[kk], rv2[kk], zz);
  zout[((size_t)i * 20 + k) * 64 + lane] = tanh_f(zz);
}

// ---------------------------------------------------------------------------
// ALSTM attention head
// ---------------------------------------------------------------------------
__launch_bounds__(256)
__global__ void alstm_head(const float* __restrict__ r1,  // [512][20][64]
                           const float* __restrict__ W1,  // [32][64]
                           const float* __restrict__ b1,  // [32]
                           const float* __restrict__ W2,  // [32]
                           const float* __restrict__ Wo,  // [128]
                           const float* __restrict__ bo,  // [1]
                           float* __restrict__ alstm_out) {
  const int wv = threadIdx.x >> 6;
  const int lane = threadIdx.x & 63;
  const int i = blockIdx.x * 4 + wv;  // [0,512)
  const int e = lane & 31;
  __shared__ __align__(16) float rbuf[4][64];
  __shared__ float scb[4][20];

  float4 w1r[16];
  {
    const float4* p = (const float4*)(W1 + e * 64);
#pragma unroll
    for (int kk = 0; kk < 16; ++kk) w1r[kk] = p[kk];
  }
  const float b1e = b1[e];
  const float w2e = W2[e];

  for (int k = 0; k < 20; ++k) {
    rbuf[wv][lane] = r1[((size_t)i * 20 + k) * 64 + lane];
    float u = b1e;
    const float4* rp = (const float4*)rbuf[wv];
#pragma unroll
    for (int kk = 0; kk < 16; ++kk) u = dot4(w1r[kk], rp[kk], u);
    u = tanh_f(u) * w2e;
#pragma unroll
    for (int m = 16; m; m >>= 1) u += __shfl_xor(u, m);
    if (lane == 0) scb[wv][k] = u;
  }

  float mx = -1e30f;
#pragma unroll
  for (int k = 0; k < 20; ++k) mx = fmaxf(mx, scb[wv][k]);
  float p[20];
  float l = 0.0f;
#pragma unroll
  for (int k = 0; k < 20; ++k) {
    p[k] = __expf(scb[wv][k] - mx);
    l += p[k];
  }
  const float inv = fast_rcp(l);

  float oa = 0.0f, rlast = 0.0f;
#pragma unroll
  for (int k = 0; k < 20; ++k) {
    float rv = r1[((size_t)i * 20 + k) * 64 + lane];
    oa = fmaf(p[k], rv, oa);
    if (k == 19) rlast = rv;
  }
  oa *= inv;
  float v = fmaf(Wo[lane], rlast, Wo[64 + lane] * oa);
  v = wave_sum(v);
  if (lane == 0) alstm_out[i] = v + bo[0];
}

// ---------------------------------------------------------------------------
extern "C" void kernel_launch(void* const* d_in, const int* in_sizes, int n_in,
                              void* d_out, int out_size, void* d_ws, size_t ws_size,
                              hipStream_t stream) {
  const float* x      = (const float*)d_in[0];
  const float* Wih0   = (const float*)d_in[1];
  const float* Whh0   = (const float*)d_in[2];
  const float* bih0   = (const float*)d_in[3];
  const float* bhh0   = (const float*)d_in[4];
  const float* Wih1   = (const float*)d_in[5];
  const float* Whh1   = (const float*)d_in[6];
  const float* bih1   = (const float*)d_in[7];
  const float* bhh1   = (const float*)d_in[8];
  const float* transW = (const float*)d_in[9];
  const float* transb = (const float*)d_in[10];
  const float* a_vec  = (const float*)d_in[11];
  const float* fcW    = (const float*)d_in[12];
  const float* fcb    = (const float*)d_in[13];
  const float* fcoW   = (const float*)d_in[14];
  const float* fcob   = (const float*)d_in[15];
  const float* alinW  = (const float*)d_in[16];
  const float* alinb  = (const float*)d_in[17];
  const float* aWih0  = (const float*)d_in[18];
  const float* aWhh0  = (const float*)d_in[19];
  const float* abih0  = (const float*)d_in[20];
  const float* abhh0  = (const float*)d_in[21];
  const float* aWih1  = (const float*)d_in[22];
  const float* aWhh1  = (const float*)d_in[23];
  const float* abih1  = (const float*)d_in[24];
  const float* abhh1  = (const float*)d_in[25];
  const float* att1W  = (const float*)d_in[26];
  const float* att1b  = (const float*)d_in[27];
  const float* att2W  = (const float*)d_in[28];
  const float* aloutW = (const float*)d_in[29];
  const float* aloutb = (const float*)d_in[30];

  float* out = (float*)d_out;  // [0:512) alstm_out, [512:1024) pred

  float* W = (float*)d_ws;
  float* h_enc = W; W += 10240 * 64;      // reused as r0 (steps 7-8)
  float* vbuf  = W; W += 256;
  float* s_src = W; W += 10240;
  float* s_dst = W; W += 10240;
  float* hout  = W; W += 10240 * 64;
  float* zbuf  = W; W += 512 * 20 * 64;
  float* r1    = W; W += 512 * 20 * 64;
  float* w3a0  = W; W += 24576;
  float* w3a1  = W; W += 24576;
  // time-disjoint aliases: encoder weight buffers live in the zbuf region
  // (consumed at step 2; zbuf written at step 6).
  float* wx0b = zbuf;                  // 1152
  float* w4h0 = zbuf + 1152;           // 12288
  float* w4x1 = zbuf + 13440;          // 12288
  float* w4h1 = zbuf + 25728;          // 12288 (end 38016 << 655360)

  static bool attr_done = false;
  if (!attr_done) {
    hipFuncSetAttribute((const void*)gru2_enc,
                        hipFuncAttributeMaxDynamicSharedMemorySize, E_LDS);
    hipFuncSetAttribute((const void*)gru1,
                        hipFuncAttributeMaxDynamicSharedMemorySize, A_LDS);
    attr_done = true;
  }

  // 1) weight prep (encoder quad-pack + ALSTM w3)
  w3_prep<<<48, 256, 0, stream>>>(Wih0, Whh0, Wih1, Whh1, aWih0, aWhh0,
                                  aWih1, aWhh1, wx0b, w4h0, w4x1, w4h1,
                                  w3a0, w3a1);
  // 2) fused 2-layer persistent GRU encoder: 256 blocks x 4 waves x SPW=10
  //    = 10240 seqs in ONE balanced round
  gru2_enc<<<256, 256, E_LDS, stream>>>(x, wx0b, w4h0, w4x1, w4h1,
                                        bih0, bhh0, bih1, bhh1, h_enc);
  // 3) GAT score-vector prep
  gat_prep<<<1, 64, 0, stream>>>(transW, transb, a_vec, vbuf);
  // 4) per-row s_src/s_dst
  gat_svals<<<2560, 256, 0, stream>>>(h_enc, vbuf, s_src, s_dst);
  // 5) dense attention + residual
  gat_attn<<<2560, 256, 0, stream>>>(h_enc, s_src, s_dst, hout);
  // 6) fc + pred head + ALSTM input transform (z in [i][k][64])
  gat_out<<<2560, 256, 0, stream>>>(hout, fcW, fcb, fcoW, fcob, alinW, alinb,
                                    zbuf, out + 512);
  // 7) ALSTM GRU layer 0: z -> r0 (reuses h_enc storage)
  gru1<<<64, 512, A_LDS, stream>>>(zbuf, w3a0, abih0, abhh0, 20, h_enc);
  // 8) ALSTM GRU layer 1: r0 -> r1
  gru1<<<64, 512, A_LDS, stream>>>(h_enc, w3a1, abih1, abhh1, 20, r1);
  // 9) ALSTM attention head -> alstm_out
  alstm_head<<<128, 256, 0, stream>>>(r1, att1W, att1b, att2W, aloutW, aloutb,
                                      out);
}

// Round 5
// 1938.924 us; speedup vs baseline: 14.0929x; 14.0929x over previous
//
#include <hip/hip_runtime.h>

#define DEV __device__ __forceinline__

DEV float fast_rcp(float x) {
#if __has_builtin(__builtin_amdgcn_rcpf)
  return __builtin_amdgcn_rcpf(x);
#else
  return 1.0f / x;
#endif
}
DEV float sigm(float x) { return fast_rcp(1.0f + __expf(-x)); }
DEV float tanh_f(float x) {
  float e = __expf(-2.0f * fabsf(x));
  float t = 1.0f - 2.0f * e * fast_rcp(1.0f + e);
  return copysignf(t, x);
}
DEV float lrelu(float x) { return x > 0.0f ? x : 0.01f * x; }

DEV float wave_sum(float v) {
#pragma unroll
  for (int m = 32; m; m >>= 1) v += __shfl_xor(v, m);
  return v;
}
DEV float wave_max(float v) {
#pragma unroll
  for (int m = 32; m; m >>= 1) v = fmaxf(v, __shfl_xor(v, m));
  return v;
}
DEV float dot4(float4 w, float4 x, float acc) {
  acc = fmaf(w.x, x.x, acc);
  acc = fmaf(w.y, x.y, acc);
  acc = fmaf(w.z, x.z, acc);
  acc = fmaf(w.w, x.w, acc);
  return acc;
}

// ---------------------------------------------------------------------------
// Persistent-GRU encoder, R8. Failure history drives two hard rules:
//  RULE 1 (R5/R6/R7 spills): NEVER fully unroll the quad loops. Full unroll
//    hoists all quads' weight loads -> >256 live VGPRs -> scratch (signature:
//    VGPR=cap + GB-scale FETCH_SIZE). Quad loops are unroll(disable); only
//    the SPW s-loop is unrolled (accs must be statically indexed).
//  RULE 2 (R7 conflicts, 2.04e8): weight b128 reads must be CONTIGUOUS
//    64-lane x 16B tiles. 3-plane layout [quad][plane][64][4]; the per-lane
//    12-dword interleave ((12j)%32 has period 8 -> 8-way conflict) is banned.
// Structure (validated R1/R7): lane = hidden unit j, owns all 3 gates of j
// -> no shuffles, no in-loop barriers; wave-private LDS state; one block/CU
// (LDS 162,816B), 256 blocks x 4 waves x SPW=10 = 10240 seqs in ONE round.
// Weights LDS-resident except Wih0 (18/lane) + Whh0 quads 14,15 (24/lane).
// h reads are same-address b128 broadcasts (no conflict by definition).
// ---------------------------------------------------------------------------
constexpr int E_SPW = 10;
constexpr int E_WAVES = 4;
// LDS dword offsets
constexpr int L_W0H = 0;                       // Whh0 quads 0..13: 14*768
constexpr int L_W1X = 10752;                   // Wih1 quads 0..15: 16*768
constexpr int L_W1H = 23040;                   // Whh1 quads 0..15
constexpr int L_HB = 35328;                    // + wave*1280: [s][128] h0|h1
constexpr int L_XS = 40448;                    // + wave*64: x stage (60 used)
constexpr int E_DW = 40704;
constexpr int E_LDS = E_DW * 4;                // 162,816 B <= 160 KiB

// 12 FMAs of one quad: weights wA/wB/wC (3-plane), h quad hv.
// m = kk*3+g flat; plane p=m/4, comp c=m%4  (same mapping R7 verified).
#define FMA12(AR, AZ, AN)                                                  \
  AR = fmaf(wA.x, hv.x, AR);                                               \
  AZ = fmaf(wA.y, hv.x, AZ);                                               \
  AN = fmaf(wA.z, hv.x, AN);                                               \
  AR = fmaf(wA.w, hv.y, AR);                                               \
  AZ = fmaf(wB.x, hv.y, AZ);                                               \
  AN = fmaf(wB.y, hv.y, AN);                                               \
  AR = fmaf(wB.z, hv.z, AR);                                               \
  AZ = fmaf(wB.w, hv.z, AZ);                                               \
  AN = fmaf(wC.x, hv.z, AN);                                               \
  AR = fmaf(wC.y, hv.w, AR);                                               \
  AZ = fmaf(wC.z, hv.w, AZ);                                               \
  AN = fmaf(wC.w, hv.w, AN);

__launch_bounds__(256, 1)
__global__ void gru2_enc(const float* __restrict__ x,      // [10240][60][6]
                         const float* __restrict__ wx0b,   // [6][192] j3-interleave
                         const float* __restrict__ w4h0,   // [16][3][64][4] planes
                         const float* __restrict__ w4x1,   // [16][3][64][4]
                         const float* __restrict__ w4h1,   // [16][3][64][4]
                         const float* __restrict__ bih0, const float* __restrict__ bhh0,
                         const float* __restrict__ bih1, const float* __restrict__ bhh1,
                         float* __restrict__ h_out) {      // [10240][64]
  extern __shared__ float lds[];
  const int tid = threadIdx.x;
  const int wave = tid >> 6;
  const int j = tid & 63;
  const int j3 = j * 3;
  const int j4 = j * 4;
  const int HBW = L_HB + wave * (E_SPW * 128);
  const int XSW = L_XS + wave * 64;

  // cooperative weight load into LDS (coalesced float4; layouts contiguous)
  {
    const float4* s0 = (const float4*)w4h0;    // quads 0..13 = first 10752 dw
    for (int i = tid; i < 10752 / 4; i += 256) ((float4*)(lds + L_W0H))[i] = s0[i];
    const float4* s1 = (const float4*)w4x1;
    for (int i = tid; i < 12288 / 4; i += 256) ((float4*)(lds + L_W1X))[i] = s1[i];
    const float4* s2 = (const float4*)w4h1;
    for (int i = tid; i < 12288 / 4; i += 256) ((float4*)(lds + L_W1H))[i] = s2[i];
  }
  // register weights: Wih0 (6 rows x 3) and Whh0 quads 14,15 (3 planes each)
  float wx0[6][3];
#pragma unroll
  for (int k = 0; k < 6; ++k)
#pragma unroll
    for (int g = 0; g < 3; ++g) wx0[k][g] = wx0b[k * 192 + j3 + g];
  const float4 whA14 = *(const float4*)&w4h0[(14 * 3 + 0) * 256 + j4];
  const float4 whB14 = *(const float4*)&w4h0[(14 * 3 + 1) * 256 + j4];
  const float4 whC14 = *(const float4*)&w4h0[(14 * 3 + 2) * 256 + j4];
  const float4 whA15 = *(const float4*)&w4h0[(15 * 3 + 0) * 256 + j4];
  const float4 whB15 = *(const float4*)&w4h0[(15 * 3 + 1) * 256 + j4];
  const float4 whC15 = *(const float4*)&w4h0[(15 * 3 + 2) * 256 + j4];

  const float br0 = bih0[j] + bhh0[j];
  const float bz0 = bih0[64 + j] + bhh0[64 + j];
  const float bxn0 = bih0[128 + j];
  const float bhn0 = bhh0[128 + j];
  const float br1 = bih1[j] + bhh1[j];
  const float bz1 = bih1[64 + j] + bhh1[64 + j];
  const float bxn1 = bih1[128 + j];
  const float bhn1 = bhh1[128 + j];

  float h0r[E_SPW], h1r[E_SPW];
#pragma unroll
  for (int s = 0; s < E_SPW; ++s) {
    h0r[s] = 0.0f; h1r[s] = 0.0f;
    lds[HBW + s * 128 + j] = 0.0f;
    lds[HBW + s * 128 + 64 + j] = 0.0f;
  }
  __syncthreads();  // the only barrier (weights + zeroed state visible)

  const int seq0 = blockIdx.x * (E_WAVES * E_SPW) + wave * E_SPW;
  // x loader: lane j<60 covers (seq si, component ci)
  const int si = j / 6;
  const int ci = j - si * 6;
  const bool xlane = (j < 60);
  const float* xg = x + (size_t)(seq0 + si) * 360 + ci;

  float xcur = xlane ? xg[0] : 0.0f;  // t = 0

  for (int t = 0; t < 60; ++t) {
    float xnext = (xlane && t + 1 < 60) ? xg[(size_t)(t + 1) * 6] : 0.0f;

    float ar[E_SPW], az[E_SPW], anx[E_SPW], anh[E_SPW];
#pragma unroll
    for (int s = 0; s < E_SPW; ++s) { ar[s] = 0.f; az[s] = 0.f; anx[s] = 0.f; anh[s] = 0.f; }

    // ---- layer0 h-part: quads 0..13 from LDS (ROLLED; see RULE 1)
#pragma clang loop unroll(disable)
    for (int q = 0; q < 14; ++q) {
      const int wb = L_W0H + q * 768 + j4;
      const float4 wA = *(const float4*)&lds[wb];
      const float4 wB = *(const float4*)&lds[wb + 256];
      const float4 wC = *(const float4*)&lds[wb + 512];
      const int hb = HBW + q * 4;
#pragma unroll
      for (int s = 0; s < E_SPW; ++s) {
        const float4 hv = *(const float4*)&lds[hb + s * 128];
        FMA12(ar[s], az[s], anh[s])
      }
    }
    // quads 14,15 from registers
    {
      const float4 wA = whA14, wB = whB14, wC = whC14;
#pragma unroll
      for (int s = 0; s < E_SPW; ++s) {
        const float4 hv = *(const float4*)&lds[HBW + s * 128 + 56];
        FMA12(ar[s], az[s], anh[s])
      }
    }
    {
      const float4 wA = whA15, wB = whB15, wC = whC15;
#pragma unroll
      for (int s = 0; s < E_SPW; ++s) {
        const float4 hv = *(const float4*)&lds[HBW + s * 128 + 60];
        FMA12(ar[s], az[s], anh[s])
      }
    }

    // ---- stage x[t] (wave-private; ds ordering by program order)
    if (xlane) lds[XSW + j] = xcur;
    // ---- layer0 x-part from register weights + staged broadcasts
#pragma unroll
    for (int s = 0; s < E_SPW; ++s) {
      const float2 xa = *(const float2*)&lds[XSW + s * 6];
      const float2 xb = *(const float2*)&lds[XSW + s * 6 + 2];
      const float2 xc = *(const float2*)&lds[XSW + s * 6 + 4];
      ar[s] = fmaf(wx0[0][0], xa.x, ar[s]);
      az[s] = fmaf(wx0[0][1], xa.x, az[s]);
      anx[s] = fmaf(wx0[0][2], xa.x, anx[s]);
      ar[s] = fmaf(wx0[1][0], xa.y, ar[s]);
      az[s] = fmaf(wx0[1][1], xa.y, az[s]);
      anx[s] = fmaf(wx0[1][2], xa.y, anx[s]);
      ar[s] = fmaf(wx0[2][0], xb.x, ar[s]);
      az[s] = fmaf(wx0[2][1], xb.x, az[s]);
      anx[s] = fmaf(wx0[2][2], xb.x, anx[s]);
      ar[s] = fmaf(wx0[3][0], xb.y, ar[s]);
      az[s] = fmaf(wx0[3][1], xb.y, az[s]);
      anx[s] = fmaf(wx0[3][2], xb.y, anx[s]);
      ar[s] = fmaf(wx0[4][0], xc.x, ar[s]);
      az[s] = fmaf(wx0[4][1], xc.x, az[s]);
      anx[s] = fmaf(wx0[4][2], xc.x, anx[s]);
      ar[s] = fmaf(wx0[5][0], xc.y, ar[s]);
      az[s] = fmaf(wx0[5][1], xc.y, az[s]);
      anx[s] = fmaf(wx0[5][2], xc.y, anx[s]);
    }
    // ---- layer0 epilogue: lane j owns all 3 gates of unit j
#pragma unroll
    for (int s = 0; s < E_SPW; ++s) {
      float r = sigm(ar[s] + br0);
      float z = sigm(az[s] + bz0);
      float n = tanh_f(anx[s] + bxn0 + r * (anh[s] + bhn0));
      float h0 = (1.0f - z) * n + z * h0r[s];
      h0r[s] = h0;
      lds[HBW + s * 128 + j] = h0;
    }

#pragma unroll
    for (int s = 0; s < E_SPW; ++s) { ar[s] = 0.f; az[s] = 0.f; anx[s] = 0.f; anh[s] = 0.f; }
    // ---- layer1 x-part over fresh h0 (ROLLED)
#pragma clang loop unroll(disable)
    for (int q = 0; q < 16; ++q) {
      const int wb = L_W1X + q * 768 + j4;
      const float4 wA = *(const float4*)&lds[wb];
      const float4 wB = *(const float4*)&lds[wb + 256];
      const float4 wC = *(const float4*)&lds[wb + 512];
      const int hb = HBW + q * 4;
#pragma unroll
      for (int s = 0; s < E_SPW; ++s) {
        const float4 hv = *(const float4*)&lds[hb + s * 128];
        FMA12(ar[s], az[s], anx[s])
      }
    }
    // ---- layer1 h-part over h1_old (ROLLED)
#pragma clang loop unroll(disable)
    for (int q = 0; q < 16; ++q) {
      const int wb = L_W1H + q * 768 + j4;
      const float4 wA = *(const float4*)&lds[wb];
      const float4 wB = *(const float4*)&lds[wb + 256];
      const float4 wC = *(const float4*)&lds[wb + 512];
      const int hb = HBW + 64 + q * 4;
#pragma unroll
      for (int s = 0; s < E_SPW; ++s) {
        const float4 hv = *(const float4*)&lds[hb + s * 128];
        FMA12(ar[s], az[s], anh[s])
      }
    }
    // ---- layer1 epilogue
#pragma unroll
    for (int s = 0; s < E_SPW; ++s) {
      float r = sigm(ar[s] + br1);
      float z = sigm(az[s] + bz1);
      float n = tanh_f(anx[s] + bxn1 + r * (anh[s] + bhn1));
      float h1 = (1.0f - z) * n + z * h1r[s];
      h1r[s] = h1;
      lds[HBW + s * 128 + 64 + j] = h1;
    }
    xcur = xnext;
  }

#pragma unroll
  for (int s = 0; s < E_SPW; ++s)
    h_out[(size_t)(seq0 + s) * 64 + j] = h1r[s];
}

// ---------------------------------------------------------------------------
// Single-layer GRU for the ALSTM (I = 64). 8 waves/block (2/SIMD), 1 seq per
// wave -> grid 64 blocks. Unchanged (validated R2-R4; small share of time).
// ---------------------------------------------------------------------------
constexpr int A_W_DW = 128 * 192;  // 24576
constexpr int A_WAVES = 8;
constexpr int A_LDS = (A_W_DW + A_WAVES * 128) * 4;  // 102400 B

__launch_bounds__(512, 2)
__global__ void gru1(const float* __restrict__ xin,  // [N][T][64]
                     const float* __restrict__ w3,   // [128][192]
                     const float* __restrict__ bih, const float* __restrict__ bhh,
                     int T,
                     float* __restrict__ rout) {     // [N][T][64]
  extern __shared__ float lds[];
  const int tid = threadIdx.x;
  const int wave = tid >> 6;
  const int j = tid & 63;
  const int j3 = j * 3;
  const int XB = A_W_DW + wave * 128;  // [0..63]=x_t, [64..127]=h

  {
    const float4* sp = (const float4*)w3;
    for (int i = tid; i < A_W_DW / 4; i += 512) ((float4*)lds)[i] = sp[i];
  }
  const float br = bih[j] + bhh[j];
  const float bz = bih[64 + j] + bhh[64 + j];
  const float bxn = bih[128 + j];
  const float bhn = bhh[128 + j];

  float hr = 0.0f;
  lds[XB + 64 + j] = 0.0f;
  __syncthreads();

  const int seq = blockIdx.x * A_WAVES + wave;
  const float* xs = xin + (size_t)seq * T * 64;

#define A_QUAD(WROW0, HOFF, AN)                                            \
  {                                                                        \
    float4 hv = *(const float4*)&lds[XB + (HOFF)];                         \
    _Pragma("unroll") for (int c = 0; c < 4; ++c) {                        \
      const float wr = lds[((WROW0) + c) * 192 + j3];                      \
      const float wz = lds[((WROW0) + c) * 192 + j3 + 1];                  \
      const float wn = lds[((WROW0) + c) * 192 + j3 + 2];                  \
      const float hc = (c == 0) ? hv.x : (c == 1) ? hv.y                   \
                      : (c == 2) ? hv.z : hv.w;                            \
      ar = fmaf(wr, hc, ar);                                               \
      az = fmaf(wz, hc, az);                                               \
      AN = fmaf(wn, hc, AN);                                               \
    }                                                                      \
  }

  float xcur = xs[j];  // t = 0
  for (int t = 0; t < T; ++t) {
    float xnext = (t + 1 < T) ? xs[(size_t)(t + 1) * 64 + j] : 0.0f;
    lds[XB + j] = xcur;  // wave-private; ordered by lgkmcnt

    float ar = 0.f, az = 0.f, anx = 0.f, anh = 0.f;
#pragma unroll
    for (int kq = 0; kq < 16; ++kq) A_QUAD(kq * 4, kq * 4, anx);        // input
#pragma unroll
    for (int kq = 0; kq < 16; ++kq) A_QUAD(64 + kq * 4, 64 + kq * 4, anh);  // rec

    float r = sigm(ar + br);
    float z = sigm(az + bz);
    float n = tanh_f(anx + bxn + r * (anh + bhn));
    float h = (1.0f - z) * n + z * hr;
    hr = h;
    lds[XB + 64 + j] = h;
    rout[((size_t)seq * T + t) * 64 + j] = h;
    xcur = xnext;
  }
#undef A_QUAD
}

// ---------------------------------------------------------------------------
// Weight prep. Sections (8 blocks each):
//  0: wx0   [6][192] j3-interleave  <- Wih0 (192x6)
//  1: w4h0  [16][3][64][4] planes   <- Whh0 (192x64)
//  2: w4x1  [16][3][64][4]          <- Wih1 (192x64)
//  3: w4h1  [16][3][64][4]          <- Whh1 (192x64)
//  4: a0    [128][192] w3-format    <- aWih0+aWhh0
//  5: a1    [128][192] w3-format    <- aWih1+aWhh1
// plane-pack: idx=(q,p,j,c); m=p*4+c; kk=m/3; g=m%3;
//   dst[idx] = W[(g*64+j)*64 + q*4+kk]
// ---------------------------------------------------------------------------
__global__ void w3_prep(const float* __restrict__ Wih0, const float* __restrict__ Whh0,
                        const float* __restrict__ Wih1, const float* __restrict__ Whh1,
                        const float* __restrict__ aWih0, const float* __restrict__ aWhh0,
                        const float* __restrict__ aWih1, const float* __restrict__ aWhh1,
                        float* __restrict__ d_wx0, float* __restrict__ d_w4h0,
                        float* __restrict__ d_w4x1, float* __restrict__ d_w4h1,
                        float* __restrict__ d_a0, float* __restrict__ d_a1) {
  const int sec = blockIdx.x >> 3;
  const int bi = blockIdx.x & 7;

  if (sec == 0) {  // wx0: [6][192], idx = k*192 + j*3 + g
    for (int idx = bi * blockDim.x + threadIdx.x; idx < 6 * 192; idx += 8 * blockDim.x) {
      const int k = idx / 192;
      const int rem = idx - k * 192;
      const int jj = rem / 3;
      const int g = rem - jj * 3;
      d_wx0[idx] = Wih0[(g * 64 + jj) * 6 + k];
    }
  } else if (sec <= 3) {  // 3-plane quad-pack sections
    const float* src = (sec == 1) ? Whh0 : (sec == 2) ? Wih1 : Whh1;
    float* dst = (sec == 1) ? d_w4h0 : (sec == 2) ? d_w4x1 : d_w4h1;
    for (int idx = bi * blockDim.x + threadIdx.x; idx < 12288; idx += 8 * blockDim.x) {
      const int q = idx / 768;
      const int r768 = idx - q * 768;
      const int p = r768 / 256;
      const int r256 = r768 - p * 256;
      const int jj = r256 / 4;
      const int c = r256 - jj * 4;
      const int m = p * 4 + c;
      const int kk = m / 3;
      const int g = m - kk * 3;
      dst[idx] = src[(g * 64 + jj) * 64 + q * 4 + kk];
    }
  } else {  // ALSTM w3 format: [128][192]
    const float* Wih = (sec == 4) ? aWih0 : aWih1;
    const float* Whh = (sec == 4) ? aWhh0 : aWhh1;
    float* dst = (sec == 4) ? d_a0 : d_a1;
    for (int idx = bi * blockDim.x + threadIdx.x; idx < 128 * 192; idx += 8 * blockDim.x) {
      const int k = idx / 192;
      const int rem = idx - k * 192;
      const int jj = rem / 3;
      const int g = rem - jj * 3;
      dst[idx] = (k < 64) ? Wih[(g * 64 + jj) * 64 + k] : Whh[(g * 64 + jj) * 64 + (k - 64)];
    }
  }
}

// ---------------------------------------------------------------------------
// GAT algebraic prep
// ---------------------------------------------------------------------------
__global__ void gat_prep(const float* __restrict__ tW, const float* __restrict__ tb,
                         const float* __restrict__ a, float* __restrict__ vbuf) {
  const int d = threadIdx.x;  // 64 threads
  float vd = 0.0f, vs = 0.0f;
  for (int e = 0; e < 64; ++e) {
    float w = tW[e * 64 + d];
    vd = fmaf(w, a[e], vd);
    vs = fmaf(w, a[64 + e], vs);
  }
  vbuf[d] = vd;
  vbuf[64 + d] = vs;
  if (d == 0) {
    float cd = 0.0f, cs = 0.0f;
    for (int e = 0; e < 64; ++e) {
      cd = fmaf(tb[e], a[e], cd);
      cs = fmaf(tb[e], a[64 + e], cs);
    }
    vbuf[128] = cd;
    vbuf[129] = cs;
  }
}

__global__ void gat_svals(const float* __restrict__ h_enc, const float* __restrict__ vbuf,
                          float* __restrict__ s_src, float* __restrict__ s_dst) {
  const int wave = (blockIdx.x * blockDim.x + threadIdx.x) >> 6;
  const int lane = threadIdx.x & 63;
  float h = h_enc[(size_t)wave * 64 + lane];
  float pd = h * vbuf[lane];
  float ps = h * vbuf[64 + lane];
  pd = wave_sum(pd);
  ps = wave_sum(ps);
  if (lane == 0) {
    s_dst[wave] = pd + vbuf[128];
    s_src[wave] = ps + vbuf[129];
  }
}

// ---------------------------------------------------------------------------
// Dense all-pairs attention per group k (m=512)
// ---------------------------------------------------------------------------
__launch_bounds__(256)
__global__ void gat_attn(const float* __restrict__ h_enc,
                         const float* __restrict__ s_src,
                         const float* __restrict__ s_dst,
                         float* __restrict__ hout) {
  const int k = blockIdx.x >> 7;
  const int tile = blockIdx.x & 127;
  const int wv = threadIdx.x >> 6;
  const int lane = threadIdx.x & 63;
  const int i = tile * 4 + wv;
  __shared__ float sdbuf[512];
  __shared__ __align__(16) float pbuf[4][512];

  for (int u = threadIdx.x; u < 512; u += 256) sdbuf[u] = s_dst[k * 512 + u];
  __syncthreads();

  const float si = s_src[k * 512 + i];
  float ev[8];
  float mx = -1e30f;
#pragma unroll
  for (int u = 0; u < 8; ++u) {
    ev[u] = lrelu(si + sdbuf[lane + u * 64]);
    mx = fmaxf(mx, ev[u]);
  }
  mx = wave_max(mx);
  float lsum = 0.0f;
#pragma unroll
  for (int u = 0; u < 8; ++u) {
    float p = __expf(ev[u] - mx);
    pbuf[wv][lane + u * 64] = p;
    lsum += p;
  }
  lsum = wave_sum(lsum);
  const float inv = fast_rcp(lsum);

  const float* hk = h_enc + (size_t)k * 512 * 64;
  const float4* pv = (const float4*)pbuf[wv];
  float acc0 = 0.0f, acc1 = 0.0f;
#pragma unroll 2
  for (int jj = 0; jj < 128; ++jj) {
    float4 p = pv[jj];
    const float* hp = hk + (size_t)(jj * 4) * 64 + lane;
    acc0 = fmaf(p.x, hp[0], acc0);
    acc1 = fmaf(p.y, hp[64], acc1);
    acc0 = fmaf(p.z, hp[128], acc0);
    acc1 = fmaf(p.w, hp[192], acc1);
  }
  hout[((size_t)k * 512 + i) * 64 + lane] =
      (acc0 + acc1) * inv + hk[(size_t)i * 64 + lane];
}

// ---------------------------------------------------------------------------
// Post-GAT transform + pred head + ALSTM input transform
// ---------------------------------------------------------------------------
__launch_bounds__(256)
__global__ void gat_out(const float* __restrict__ hin,
                        const float* __restrict__ fcW, const float* __restrict__ fcb,
                        const float* __restrict__ fcoW, const float* __restrict__ fcob,
                        const float* __restrict__ alinW, const float* __restrict__ alinb,
                        float* __restrict__ zout, float* __restrict__ pred) {
  const int wv = threadIdx.x >> 6;
  const int lane = threadIdx.x & 63;
  const int n = blockIdx.x * 4 + wv;  // [0,10240)
  const int k = n >> 9;
  const int i = n & 511;
  __shared__ __align__(16) float rbuf[4][64];
  __shared__ __align__(16) float rbuf2[4][64];

  float4 fw[16], aw[16];
  {
    const float4* p1 = (const float4*)(fcW + lane * 64);
    const float4* p2 = (const float4*)(alinW + lane * 64);
#pragma unroll
    for (int kk = 0; kk < 16; ++kk) fw[kk] = p1[kk];
#pragma unroll
    for (int kk = 0; kk < 16; ++kk) aw[kk] = p2[kk];
  }

  rbuf[wv][lane] = hin[(size_t)n * 64 + lane];
  float h2 = fcb[lane];
  const float4* rv = (const float4*)rbuf[wv];
#pragma unroll
  for (int kk = 0; kk < 16; ++kk) h2 = dot4(fw[kk], rv[kk], h2);

  if (k == 19) {
    float pv = lrelu(h2) * fcoW[lane];
    pv = wave_sum(pv);
    if (lane == 0) pred[i] = pv + fcob[0];
  }

  rbuf2[wv][lane] = h2;
  float zz = alinb[lane];
  const float4* rv2 = (const float4*)rbuf2[wv];
#pragma unroll
  for (int kk = 0; kk < 16; ++kk) zz = dot4(aw[kk], rv2[kk], zz);
  zout[((size_t)i * 20 + k) * 64 + lane] = tanh_f(zz);
}

// ---------------------------------------------------------------------------
// ALSTM attention head
// ---------------------------------------------------------------------------
__launch_bounds__(256)
__global__ void alstm_head(const float* __restrict__ r1,  // [512][20][64]
                           const float* __restrict__ W1,  // [32][64]
                           const float* __restrict__ b1,  // [32]
                           const float* __restrict__ W2,  // [32]
                           const float* __restrict__ Wo,  // [128]
                           const float* __restrict__ bo,  // [1]
                           float* __restrict__ alstm_out) {
  const int wv = threadIdx.x >> 6;
  const int lane = threadIdx.x & 63;
  const int i = blockIdx.x * 4 + wv;  // [0,512)
  const int e = lane & 31;
  __shared__ __align__(16) float rbuf[4][64];
  __shared__ float scb[4][20];

  float4 w1r[16];
  {
    const float4* p = (const float4*)(W1 + e * 64);
#pragma unroll
    for (int kk = 0; kk < 16; ++kk) w1r[kk] = p[kk];
  }
  const float b1e = b1[e];
  const float w2e = W2[e];

  for (int k = 0; k < 20; ++k) {
    rbuf[wv][lane] = r1[((size_t)i * 20 + k) * 64 + lane];
    float u = b1e;
    const float4* rp = (const float4*)rbuf[wv];
#pragma unroll
    for (int kk = 0; kk < 16; ++kk) u = dot4(w1r[kk], rp[kk], u);
    u = tanh_f(u) * w2e;
#pragma unroll
    for (int m = 16; m; m >>= 1) u += __shfl_xor(u, m);
    if (lane == 0) scb[wv][k] = u;
  }

  float mx = -1e30f;
#pragma unroll
  for (int k = 0; k < 20; ++k) mx = fmaxf(mx, scb[wv][k]);
  float p[20];
  float l = 0.0f;
#pragma unroll
  for (int k = 0; k < 20; ++k) {
    p[k] = __expf(scb[wv][k] - mx);
    l += p[k];
  }
  const float inv = fast_rcp(l);

  float oa = 0.0f, rlast = 0.0f;
#pragma unroll
  for (int k = 0; k < 20; ++k) {
    float rv = r1[((size_t)i * 20 + k) * 64 + lane];
    oa = fmaf(p[k], rv, oa);
    if (k == 19) rlast = rv;
  }
  oa *= inv;
  float v = fmaf(Wo[lane], rlast, Wo[64 + lane] * oa);
  v = wave_sum(v);
  if (lane == 0) alstm_out[i] = v + bo[0];
}

// ---------------------------------------------------------------------------
extern "C" void kernel_launch(void* const* d_in, const int* in_sizes, int n_in,
                              void* d_out, int out_size, void* d_ws, size_t ws_size,
                              hipStream_t stream) {
  const float* x      = (const float*)d_in[0];
  const float* Wih0   = (const float*)d_in[1];
  const float* Whh0   = (const float*)d_in[2];
  const float* bih0   = (const float*)d_in[3];
  const float* bhh0   = (const float*)d_in[4];
  const float* Wih1   = (const float*)d_in[5];
  const float* Whh1   = (const float*)d_in[6];
  const float* bih1   = (const float*)d_in[7];
  const float* bhh1   = (const float*)d_in[8];
  const float* transW = (const float*)d_in[9];
  const float* transb = (const float*)d_in[10];
  const float* a_vec  = (const float*)d_in[11];
  const float* fcW    = (const float*)d_in[12];
  const float* fcb    = (const float*)d_in[13];
  const float* fcoW   = (const float*)d_in[14];
  const float* fcob   = (const float*)d_in[15];
  const float* alinW  = (const float*)d_in[16];
  const float* alinb  = (const float*)d_in[17];
  const float* aWih0  = (const float*)d_in[18];
  const float* aWhh0  = (const float*)d_in[19];
  const float* abih0  = (const float*)d_in[20];
  const float* abhh0  = (const float*)d_in[21];
  const float* aWih1  = (const float*)d_in[22];
  const float* aWhh1  = (const float*)d_in[23];
  const float* abih1  = (const float*)d_in[24];
  const float* abhh1  = (const float*)d_in[25];
  const float* att1W  = (const float*)d_in[26];
  const float* att1b  = (const float*)d_in[27];
  const float* att2W  = (const float*)d_in[28];
  const float* aloutW = (const float*)d_in[29];
  const float* aloutb = (const float*)d_in[30];

  float* out = (float*)d_out;  // [0:512) alstm_out, [512:1024) pred

  float* W = (float*)d_ws;
  float* h_enc = W; W += 10240 * 64;      // reused as r0 (steps 7-8)
  float* vbuf  = W; W += 256;
  float* s_src = W; W += 10240;
  float* s_dst = W; W += 10240;
  float* hout  = W; W += 10240 * 64;
  float* zbuf  = W; W += 512 * 20 * 64;
  float* r1    = W; W += 512 * 20 * 64;
  float* w3a0  = W; W += 24576;
  float* w3a1  = W; W += 24576;
  // time-disjoint aliases: encoder weight buffers live in the zbuf region
  // (consumed at step 2; zbuf written at step 6).
  float* wx0b = zbuf;                  // 1152
  float* w4h0 = zbuf + 1152;           // 12288
  float* w4x1 = zbuf + 13440;          // 12288
  float* w4h1 = zbuf + 25728;          // 12288 (end 38016 << 655360)

  static bool attr_done = false;
  if (!attr_done) {
    hipFuncSetAttribute((const void*)gru2_enc,
                        hipFuncAttributeMaxDynamicSharedMemorySize, E_LDS);
    hipFuncSetAttribute((const void*)gru1,
                        hipFuncAttributeMaxDynamicSharedMemorySize, A_LDS);
    attr_done = true;
  }

  // 1) weight prep (encoder 3-plane quad-pack + ALSTM w3)
  w3_prep<<<48, 256, 0, stream>>>(Wih0, Whh0, Wih1, Whh1, aWih0, aWhh0,
                                  aWih1, aWhh1, wx0b, w4h0, w4x1, w4h1,
                                  w3a0, w3a1);
  // 2) fused 2-layer persistent GRU encoder: 256 blocks x 4 waves x SPW=10
  //    = 10240 seqs in ONE balanced round
  gru2_enc<<<256, 256, E_LDS, stream>>>(x, wx0b, w4h0, w4x1, w4h1,
                                        bih0, bhh0, bih1, bhh1, h_enc);
  // 3) GAT score-vector prep
  gat_prep<<<1, 64, 0, stream>>>(transW, transb, a_vec, vbuf);
  // 4) per-row s_src/s_dst
  gat_svals<<<2560, 256, 0, stream>>>(h_enc, vbuf, s_src, s_dst);
  // 5) dense attention + residual
  gat_attn<<<2560, 256, 0, stream>>>(h_enc, s_src, s_dst, hout);
  // 6) fc + pred head + ALSTM input transform (z in [i][k][64])
  gat_out<<<2560, 256, 0, stream>>>(hout, fcW, fcb, fcoW, fcob, alinW, alinb,
                                    zbuf, out + 512);
  // 7) ALSTM GRU layer 0: z -> r0 (reuses h_enc storage)
  gru1<<<64, 512, A_LDS, stream>>>(zbuf, w3a0, abih0, abhh0, 20, h_enc);
  // 8) ALSTM GRU layer 1: r0 -> r1
  gru1<<<64, 512, A_LDS, stream>>>(h_enc, w3a1, abih1, abhh1, 20, r1);
  // 9) ALSTM attention head -> alstm_out
  alstm_head<<<128, 256, 0, stream>>>(r1, att1W, att1b, att2W, aloutW, aloutb,
                                      out);
}

// Round 6
// 1823.000 us; speedup vs baseline: 14.9891x; 1.0636x over previous
//
#include <hip/hip_runtime.h>

#define DEV __device__ __forceinline__

DEV float fast_rcp(float x) {
#if __has_builtin(__builtin_amdgcn_rcpf)
  return __builtin_amdgcn_rcpf(x);
#else
  return 1.0f / x;
#endif
}
DEV float sigm(float x) { return fast_rcp(1.0f + __expf(-x)); }
DEV float tanh_f(float x) {
  float e = __expf(-2.0f * fabsf(x));
  float t = 1.0f - 2.0f * e * fast_rcp(1.0f + e);
  return copysignf(t, x);
}
DEV float lrelu(float x) { return x > 0.0f ? x : 0.01f * x; }

DEV float wave_sum(float v) {
#pragma unroll
  for (int m = 32; m; m >>= 1) v += __shfl_xor(v, m);
  return v;
}
DEV float wave_max(float v) {
#pragma unroll
  for (int m = 32; m; m >>= 1) v = fmaxf(v, __shfl_xor(v, m));
  return v;
}
DEV float dot4(float4 w, float4 x, float acc) {
  acc = fmaf(w.x, x.x, acc);
  acc = fmaf(w.y, x.y, acc);
  acc = fmaf(w.z, x.z, acc);
  acc = fmaf(w.w, x.w, acc);
  return acc;
}

// ---------------------------------------------------------------------------
// Persistent-GRU encoder, R9. Hard rules from the failure history:
//  RULE 1 (R5/R6/R7 spills): quad loops stay ROLLED (unroll(disable)); only
//    the SPW s-loop unrolls. Full unroll hoists all weight loads -> spill.
//  RULE 2 (R7, 2.04e8 conflicts): weight b128 reads are contiguous 64-lane
//    16B tiles via 3-plane layout [quad][plane][64][4].
//  RULE 3 (R5/R6): never pass a min-waves launch-bounds arg on this body —
//    the 8-wave block shape already caps VGPR at 256 (2 waves/SIMD), which
//    the ~110-140-reg rolled body fits without spilling.
// R8 measurement: 1677us, VALUBusy 42%, occupancy 1 wave/SIMD; conflicts
// 2.043e8 == R7's -> h-broadcast b128s cost ~8cyc return-path each
// (broadcast saves bank conflicts, NOT return bandwidth). LDS floor ~20k
// cyc/step, VALU ~28k, measured 67k -> single-wave serialization.
// R9: 512 thr = 8 waves (2/SIMD) x SPW=5 -> VALU/LDS overlap across sibling
// waves. Same 40 seqs/block, 256 blocks, ONE balanced round. LDS unchanged
// at 162,816 B (state 8x5x128 + x-stage 8x32).
// ---------------------------------------------------------------------------
constexpr int E_SPW = 5;
constexpr int E_WAVES = 8;
// LDS dword offsets
constexpr int L_W0H = 0;                       // Whh0 quads 0..13: 14*768
constexpr int L_W1X = 10752;                   // Wih1 quads 0..15: 16*768
constexpr int L_W1H = 23040;                   // Whh1 quads 0..15
constexpr int L_HB = 35328;                    // + wave*640: [s][128] h0|h1
constexpr int L_XS = 40448;                    // + wave*32: x stage (30 used)
constexpr int E_DW = 40704;
constexpr int E_LDS = E_DW * 4;                // 162,816 B <= 160 KiB

// 12 FMAs of one quad: weights wA/wB/wC (3-plane), h quad hv.
// m = kk*3+g flat; plane p=m/4, comp c=m%4  (mapping verified R7/R8).
#define FMA12(AR, AZ, AN)                                                  \
  AR = fmaf(wA.x, hv.x, AR);                                               \
  AZ = fmaf(wA.y, hv.x, AZ);                                               \
  AN = fmaf(wA.z, hv.x, AN);                                               \
  AR = fmaf(wA.w, hv.y, AR);                                               \
  AZ = fmaf(wB.x, hv.y, AZ);                                               \
  AN = fmaf(wB.y, hv.y, AN);                                               \
  AR = fmaf(wB.z, hv.z, AR);                                               \
  AZ = fmaf(wB.w, hv.z, AZ);                                               \
  AN = fmaf(wC.x, hv.z, AN);                                               \
  AR = fmaf(wC.y, hv.w, AR);                                               \
  AZ = fmaf(wC.z, hv.w, AZ);                                               \
  AN = fmaf(wC.w, hv.w, AN);

__launch_bounds__(512)
__global__ void gru2_enc(const float* __restrict__ x,      // [10240][60][6]
                         const float* __restrict__ wx0b,   // [6][192] j3-interleave
                         const float* __restrict__ w4h0,   // [16][3][64][4] planes
                         const float* __restrict__ w4x1,   // [16][3][64][4]
                         const float* __restrict__ w4h1,   // [16][3][64][4]
                         const float* __restrict__ bih0, const float* __restrict__ bhh0,
                         const float* __restrict__ bih1, const float* __restrict__ bhh1,
                         float* __restrict__ h_out) {      // [10240][64]
  extern __shared__ float lds[];
  const int tid = threadIdx.x;
  const int wave = tid >> 6;
  const int j = tid & 63;
  const int j3 = j * 3;
  const int j4 = j * 4;
  const int HBW = L_HB + wave * (E_SPW * 128);
  const int XSW = L_XS + wave * 32;

  // cooperative weight load into LDS (coalesced float4; layouts contiguous)
  {
    const float4* s0 = (const float4*)w4h0;    // quads 0..13 = first 10752 dw
    for (int i = tid; i < 10752 / 4; i += 512) ((float4*)(lds + L_W0H))[i] = s0[i];
    const float4* s1 = (const float4*)w4x1;
    for (int i = tid; i < 12288 / 4; i += 512) ((float4*)(lds + L_W1X))[i] = s1[i];
    const float4* s2 = (const float4*)w4h1;
    for (int i = tid; i < 12288 / 4; i += 512) ((float4*)(lds + L_W1H))[i] = s2[i];
  }
  // register weights: Wih0 (6 rows x 3) and Whh0 quads 14,15 (3 planes each)
  float wx0[6][3];
#pragma unroll
  for (int k = 0; k < 6; ++k)
#pragma unroll
    for (int g = 0; g < 3; ++g) wx0[k][g] = wx0b[k * 192 + j3 + g];
  const float4 whA14 = *(const float4*)&w4h0[(14 * 3 + 0) * 256 + j4];
  const float4 whB14 = *(const float4*)&w4h0[(14 * 3 + 1) * 256 + j4];
  const float4 whC14 = *(const float4*)&w4h0[(14 * 3 + 2) * 256 + j4];
  const float4 whA15 = *(const float4*)&w4h0[(15 * 3 + 0) * 256 + j4];
  const float4 whB15 = *(const float4*)&w4h0[(15 * 3 + 1) * 256 + j4];
  const float4 whC15 = *(const float4*)&w4h0[(15 * 3 + 2) * 256 + j4];

  const float br0 = bih0[j] + bhh0[j];
  const float bz0 = bih0[64 + j] + bhh0[64 + j];
  const float bxn0 = bih0[128 + j];
  const float bhn0 = bhh0[128 + j];
  const float br1 = bih1[j] + bhh1[j];
  const float bz1 = bih1[64 + j] + bhh1[64 + j];
  const float bxn1 = bih1[128 + j];
  const float bhn1 = bhh1[128 + j];

  float h0r[E_SPW], h1r[E_SPW];
#pragma unroll
  for (int s = 0; s < E_SPW; ++s) {
    h0r[s] = 0.0f; h1r[s] = 0.0f;
    lds[HBW + s * 128 + j] = 0.0f;
    lds[HBW + s * 128 + 64 + j] = 0.0f;
  }
  __syncthreads();  // the only barrier (weights + zeroed state visible)

  const int seq0 = blockIdx.x * (E_WAVES * E_SPW) + wave * E_SPW;
  // x loader: lane j<30 covers (seq si, component ci)
  const int si = j / 6;
  const int ci = j - si * 6;
  const bool xlane = (j < 6 * E_SPW);
  const float* xg = x + (size_t)(seq0 + si) * 360 + ci;

  float xcur = xlane ? xg[0] : 0.0f;  // t = 0

  for (int t = 0; t < 60; ++t) {
    float xnext = (xlane && t + 1 < 60) ? xg[(size_t)(t + 1) * 6] : 0.0f;

    float ar[E_SPW], az[E_SPW], anx[E_SPW], anh[E_SPW];
#pragma unroll
    for (int s = 0; s < E_SPW; ++s) { ar[s] = 0.f; az[s] = 0.f; anx[s] = 0.f; anh[s] = 0.f; }

    // ---- layer0 h-part: quads 0..13 from LDS (ROLLED; RULE 1)
#pragma clang loop unroll(disable)
    for (int q = 0; q < 14; ++q) {
      const int wb = L_W0H + q * 768 + j4;
      const float4 wA = *(const float4*)&lds[wb];
      const float4 wB = *(const float4*)&lds[wb + 256];
      const float4 wC = *(const float4*)&lds[wb + 512];
      const int hb = HBW + q * 4;
#pragma unroll
      for (int s = 0; s < E_SPW; ++s) {
        const float4 hv = *(const float4*)&lds[hb + s * 128];
        FMA12(ar[s], az[s], anh[s])
      }
    }
    // quads 14,15 from registers
    {
      const float4 wA = whA14, wB = whB14, wC = whC14;
#pragma unroll
      for (int s = 0; s < E_SPW; ++s) {
        const float4 hv = *(const float4*)&lds[HBW + s * 128 + 56];
        FMA12(ar[s], az[s], anh[s])
      }
    }
    {
      const float4 wA = whA15, wB = whB15, wC = whC15;
#pragma unroll
      for (int s = 0; s < E_SPW; ++s) {
        const float4 hv = *(const float4*)&lds[HBW + s * 128 + 60];
        FMA12(ar[s], az[s], anh[s])
      }
    }

    // ---- stage x[t] (wave-private; ds ordering by program order)
    if (xlane) lds[XSW + j] = xcur;
    // ---- layer0 x-part from register weights + staged broadcasts
#pragma unroll
    for (int s = 0; s < E_SPW; ++s) {
      const float2 xa = *(const float2*)&lds[XSW + s * 6];
      const float2 xb = *(const float2*)&lds[XSW + s * 6 + 2];
      const float2 xc = *(const float2*)&lds[XSW + s * 6 + 4];
      ar[s] = fmaf(wx0[0][0], xa.x, ar[s]);
      az[s] = fmaf(wx0[0][1], xa.x, az[s]);
      anx[s] = fmaf(wx0[0][2], xa.x, anx[s]);
      ar[s] = fmaf(wx0[1][0], xa.y, ar[s]);
      az[s] = fmaf(wx0[1][1], xa.y, az[s]);
      anx[s] = fmaf(wx0[1][2], xa.y, anx[s]);
      ar[s] = fmaf(wx0[2][0], xb.x, ar[s]);
      az[s] = fmaf(wx0[2][1], xb.x, az[s]);
      anx[s] = fmaf(wx0[2][2], xb.x, anx[s]);
      ar[s] = fmaf(wx0[3][0], xb.y, ar[s]);
      az[s] = fmaf(wx0[3][1], xb.y, az[s]);
      anx[s] = fmaf(wx0[3][2], xb.y, anx[s]);
      ar[s] = fmaf(wx0[4][0], xc.x, ar[s]);
      az[s] = fmaf(wx0[4][1], xc.x, az[s]);
      anx[s] = fmaf(wx0[4][2], xc.x, anx[s]);
      ar[s] = fmaf(wx0[5][0], xc.y, ar[s]);
      az[s] = fmaf(wx0[5][1], xc.y, az[s]);
      anx[s] = fmaf(wx0[5][2], xc.y, anx[s]);
    }
    // ---- layer0 epilogue: lane j owns all 3 gates of unit j
#pragma unroll
    for (int s = 0; s < E_SPW; ++s) {
      float r = sigm(ar[s] + br0);
      float z = sigm(az[s] + bz0);
      float n = tanh_f(anx[s] + bxn0 + r * (anh[s] + bhn0));
      float h0 = (1.0f - z) * n + z * h0r[s];
      h0r[s] = h0;
      lds[HBW + s * 128 + j] = h0;
    }

#pragma unroll
    for (int s = 0; s < E_SPW; ++s) { ar[s] = 0.f; az[s] = 0.f; anx[s] = 0.f; anh[s] = 0.f; }
    // ---- layer1 x-part over fresh h0 (ROLLED)
#pragma clang loop unroll(disable)
    for (int q = 0; q < 16; ++q) {
      const int wb = L_W1X + q * 768 + j4;
      const float4 wA = *(const float4*)&lds[wb];
      const float4 wB = *(const float4*)&lds[wb + 256];
      const float4 wC = *(const float4*)&lds[wb + 512];
      const int hb = HBW + q * 4;
#pragma unroll
      for (int s = 0; s < E_SPW; ++s) {
        const float4 hv = *(const float4*)&lds[hb + s * 128];
        FMA12(ar[s], az[s], anx[s])
      }
    }
    // ---- layer1 h-part over h1_old (ROLLED)
#pragma clang loop unroll(disable)
    for (int q = 0; q < 16; ++q) {
      const int wb = L_W1H + q * 768 + j4;
      const float4 wA = *(const float4*)&lds[wb];
      const float4 wB = *(const float4*)&lds[wb + 256];
      const float4 wC = *(const float4*)&lds[wb + 512];
      const int hb = HBW + 64 + q * 4;
#pragma unroll
      for (int s = 0; s < E_SPW; ++s) {
        const float4 hv = *(const float4*)&lds[hb + s * 128];
        FMA12(ar[s], az[s], anh[s])
      }
    }
    // ---- layer1 epilogue
#pragma unroll
    for (int s = 0; s < E_SPW; ++s) {
      float r = sigm(ar[s] + br1);
      float z = sigm(az[s] + bz1);
      float n = tanh_f(anx[s] + bxn1 + r * (anh[s] + bhn1));
      float h1 = (1.0f - z) * n + z * h1r[s];
      h1r[s] = h1;
      lds[HBW + s * 128 + 64 + j] = h1;
    }
    xcur = xnext;
  }

#pragma unroll
  for (int s = 0; s < E_SPW; ++s)
    h_out[(size_t)(seq0 + s) * 64 + j] = h1r[s];
}

// ---------------------------------------------------------------------------
// Single-layer GRU for the ALSTM (I = 64). 8 waves/block (2/SIMD), 1 seq per
// wave -> grid 64 blocks. Unchanged (validated R2-R5; small share of time).
// ---------------------------------------------------------------------------
constexpr int A_W_DW = 128 * 192;  // 24576
constexpr int A_WAVES = 8;
constexpr int A_LDS = (A_W_DW + A_WAVES * 128) * 4;  // 102400 B

__launch_bounds__(512, 2)
__global__ void gru1(const float* __restrict__ xin,  // [N][T][64]
                     const float* __restrict__ w3,   // [128][192]
                     const float* __restrict__ bih, const float* __restrict__ bhh,
                     int T,
                     float* __restrict__ rout) {     // [N][T][64]
  extern __shared__ float lds[];
  const int tid = threadIdx.x;
  const int wave = tid >> 6;
  const int j = tid & 63;
  const int j3 = j * 3;
  const int XB = A_W_DW + wave * 128;  // [0..63]=x_t, [64..127]=h

  {
    const float4* sp = (const float4*)w3;
    for (int i = tid; i < A_W_DW / 4; i += 512) ((float4*)lds)[i] = sp[i];
  }
  const float br = bih[j] + bhh[j];
  const float bz = bih[64 + j] + bhh[64 + j];
  const float bxn = bih[128 + j];
  const float bhn = bhh[128 + j];

  float hr = 0.0f;
  lds[XB + 64 + j] = 0.0f;
  __syncthreads();

  const int seq = blockIdx.x * A_WAVES + wave;
  const float* xs = xin + (size_t)seq * T * 64;

#define A_QUAD(WROW0, HOFF, AN)                                            \
  {                                                                        \
    float4 hv = *(const float4*)&lds[XB + (HOFF)];                         \
    _Pragma("unroll") for (int c = 0; c < 4; ++c) {                        \
      const float wr = lds[((WROW0) + c) * 192 + j3];                      \
      const float wz = lds[((WROW0) + c) * 192 + j3 + 1];                  \
      const float wn = lds[((WROW0) + c) * 192 + j3 + 2];                  \
      const float hc = (c == 0) ? hv.x : (c == 1) ? hv.y                   \
                      : (c == 2) ? hv.z : hv.w;                            \
      ar = fmaf(wr, hc, ar);                                               \
      az = fmaf(wz, hc, az);                                               \
      AN = fmaf(wn, hc, AN);                                               \
    }                                                                      \
  }

  float xcur = xs[j];  // t = 0
  for (int t = 0; t < T; ++t) {
    float xnext = (t + 1 < T) ? xs[(size_t)(t + 1) * 64 + j] : 0.0f;
    lds[XB + j] = xcur;  // wave-private; ordered by lgkmcnt

    float ar = 0.f, az = 0.f, anx = 0.f, anh = 0.f;
#pragma unroll
    for (int kq = 0; kq < 16; ++kq) A_QUAD(kq * 4, kq * 4, anx);        // input
#pragma unroll
    for (int kq = 0; kq < 16; ++kq) A_QUAD(64 + kq * 4, 64 + kq * 4, anh);  // rec

    float r = sigm(ar + br);
    float z = sigm(az + bz);
    float n = tanh_f(anx + bxn + r * (anh + bhn));
    float h = (1.0f - z) * n + z * hr;
    hr = h;
    lds[XB + 64 + j] = h;
    rout[((size_t)seq * T + t) * 64 + j] = h;
    xcur = xnext;
  }
#undef A_QUAD
}

// ---------------------------------------------------------------------------
// Weight prep. Sections (8 blocks each):
//  0: wx0   [6][192] j3-interleave  <- Wih0 (192x6)
//  1: w4h0  [16][3][64][4] planes   <- Whh0 (192x64)
//  2: w4x1  [16][3][64][4]          <- Wih1 (192x64)
//  3: w4h1  [16][3][64][4]          <- Whh1 (192x64)
//  4: a0    [128][192] w3-format    <- aWih0+aWhh0
//  5: a1    [128][192] w3-format    <- aWih1+aWhh1
// plane-pack: idx=(q,p,j,c); m=p*4+c; kk=m/3; g=m%3;
//   dst[idx] = W[(g*64+j)*64 + q*4+kk]
// ---------------------------------------------------------------------------
__global__ void w3_prep(const float* __restrict__ Wih0, const float* __restrict__ Whh0,
                        const float* __restrict__ Wih1, const float* __restrict__ Whh1,
                        const float* __restrict__ aWih0, const float* __restrict__ aWhh0,
                        const float* __restrict__ aWih1, const float* __restrict__ aWhh1,
                        float* __restrict__ d_wx0, float* __restrict__ d_w4h0,
                        float* __restrict__ d_w4x1, float* __restrict__ d_w4h1,
                        float* __restrict__ d_a0, float* __restrict__ d_a1) {
  const int sec = blockIdx.x >> 3;
  const int bi = blockIdx.x & 7;

  if (sec == 0) {  // wx0: [6][192], idx = k*192 + j*3 + g
    for (int idx = bi * blockDim.x + threadIdx.x; idx < 6 * 192; idx += 8 * blockDim.x) {
      const int k = idx / 192;
      const int rem = idx - k * 192;
      const int jj = rem / 3;
      const int g = rem - jj * 3;
      d_wx0[idx] = Wih0[(g * 64 + jj) * 6 + k];
    }
  } else if (sec <= 3) {  // 3-plane quad-pack sections
    const float* src = (sec == 1) ? Whh0 : (sec == 2) ? Wih1 : Whh1;
    float* dst = (sec == 1) ? d_w4h0 : (sec == 2) ? d_w4x1 : d_w4h1;
    for (int idx = bi * blockDim.x + threadIdx.x; idx < 12288; idx += 8 * blockDim.x) {
      const int q = idx / 768;
      const int r768 = idx - q * 768;
      const int p = r768 / 256;
      const int r256 = r768 - p * 256;
      const int jj = r256 / 4;
      const int c = r256 - jj * 4;
      const int m = p * 4 + c;
      const int kk = m / 3;
      const int g = m - kk * 3;
      dst[idx] = src[(g * 64 + jj) * 64 + q * 4 + kk];
    }
  } else {  // ALSTM w3 format: [128][192]
    const float* Wih = (sec == 4) ? aWih0 : aWih1;
    const float* Whh = (sec == 4) ? aWhh0 : aWhh1;
    float* dst = (sec == 4) ? d_a0 : d_a1;
    for (int idx = bi * blockDim.x + threadIdx.x; idx < 128 * 192; idx += 8 * blockDim.x) {
      const int k = idx / 192;
      const int rem = idx - k * 192;
      const int jj = rem / 3;
      const int g = rem - jj * 3;
      dst[idx] = (k < 64) ? Wih[(g * 64 + jj) * 64 + k] : Whh[(g * 64 + jj) * 64 + (k - 64)];
    }
  }
}

// ---------------------------------------------------------------------------
// GAT algebraic prep
// ---------------------------------------------------------------------------
__global__ void gat_prep(const float* __restrict__ tW, const float* __restrict__ tb,
                         const float* __restrict__ a, float* __restrict__ vbuf) {
  const int d = threadIdx.x;  // 64 threads
  float vd = 0.0f, vs = 0.0f;
  for (int e = 0; e < 64; ++e) {
    float w = tW[e * 64 + d];
    vd = fmaf(w, a[e], vd);
    vs = fmaf(w, a[64 + e], vs);
  }
  vbuf[d] = vd;
  vbuf[64 + d] = vs;
  if (d == 0) {
    float cd = 0.0f, cs = 0.0f;
    for (int e = 0; e < 64; ++e) {
      cd = fmaf(tb[e], a[e], cd);
      cs = fmaf(tb[e], a[64 + e], cs);
    }
    vbuf[128] = cd;
    vbuf[129] = cs;
  }
}

__global__ void gat_svals(const float* __restrict__ h_enc, const float* __restrict__ vbuf,
                          float* __restrict__ s_src, float* __restrict__ s_dst) {
  const int wave = (blockIdx.x * blockDim.x + threadIdx.x) >> 6;
  const int lane = threadIdx.x & 63;
  float h = h_enc[(size_t)wave * 64 + lane];
  float pd = h * vbuf[lane];
  float ps = h * vbuf[64 + lane];
  pd = wave_sum(pd);
  ps = wave_sum(ps);
  if (lane == 0) {
    s_dst[wave] = pd + vbuf[128];
    s_src[wave] = ps + vbuf[129];
  }
}

// ---------------------------------------------------------------------------
// Dense all-pairs attention per group k (m=512)
// ---------------------------------------------------------------------------
__launch_bounds__(256)
__global__ void gat_attn(const float* __restrict__ h_enc,
                         const float* __restrict__ s_src,
                         const float* __restrict__ s_dst,
                         float* __restrict__ hout) {
  const int k = blockIdx.x >> 7;
  const int tile = blockIdx.x & 127;
  const int wv = threadIdx.x >> 6;
  const int lane = threadIdx.x & 63;
  const int i = tile * 4 + wv;
  __shared__ float sdbuf[512];
  __shared__ __align__(16) float pbuf[4][512];

  for (int u = threadIdx.x; u < 512; u += 256) sdbuf[u] = s_dst[k * 512 + u];
  __syncthreads();

  const float si = s_src[k * 512 + i];
  float ev[8];
  float mx = -1e30f;
#pragma unroll
  for (int u = 0; u < 8; ++u) {
    ev[u] = lrelu(si + sdbuf[lane + u * 64]);
    mx = fmaxf(mx, ev[u]);
  }
  mx = wave_max(mx);
  float lsum = 0.0f;
#pragma unroll
  for (int u = 0; u < 8; ++u) {
    float p = __expf(ev[u] - mx);
    pbuf[wv][lane + u * 64] = p;
    lsum += p;
  }
  lsum = wave_sum(lsum);
  const float inv = fast_rcp(lsum);

  const float* hk = h_enc + (size_t)k * 512 * 64;
  const float4* pv = (const float4*)pbuf[wv];
  float acc0 = 0.0f, acc1 = 0.0f;
#pragma unroll 2
  for (int jj = 0; jj < 128; ++jj) {
    float4 p = pv[jj];
    const float* hp = hk + (size_t)(jj * 4) * 64 + lane;
    acc0 = fmaf(p.x, hp[0], acc0);
    acc1 = fmaf(p.y, hp[64], acc1);
    acc0 = fmaf(p.z, hp[128], acc0);
    acc1 = fmaf(p.w, hp[192], acc1);
  }
  hout[((size_t)k * 512 + i) * 64 + lane] =
      (acc0 + acc1) * inv + hk[(size_t)i * 64 + lane];
}

// ---------------------------------------------------------------------------
// Post-GAT transform + pred head + ALSTM input transform
// ---------------------------------------------------------------------------
__launch_bounds__(256)
__global__ void gat_out(const float* __restrict__ hin,
                        const float* __restrict__ fcW, const float* __restrict__ fcb,
                        const float* __restrict__ fcoW, const float* __restrict__ fcob,
                        const float* __restrict__ alinW, const float* __restrict__ alinb,
                        float* __restrict__ zout, float* __restrict__ pred) {
  const int wv = threadIdx.x >> 6;
  const int lane = threadIdx.x & 63;
  const int n = blockIdx.x * 4 + wv;  // [0,10240)
  const int k = n >> 9;
  const int i = n & 511;
  __shared__ __align__(16) float rbuf[4][64];
  __shared__ __align__(16) float rbuf2[4][64];

  float4 fw[16], aw[16];
  {
    const float4* p1 = (const float4*)(fcW + lane * 64);
    const float4* p2 = (const float4*)(alinW + lane * 64);
#pragma unroll
    for (int kk = 0; kk < 16; ++kk) fw[kk] = p1[kk];
#pragma unroll
    for (int kk = 0; kk < 16; ++kk) aw[kk] = p2[kk];
  }

  rbuf[wv][lane] = hin[(size_t)n * 64 + lane];
  float h2 = fcb[lane];
  const float4* rv = (const float4*)rbuf[wv];
#pragma unroll
  for (int kk = 0; kk < 16; ++kk) h2 = dot4(fw[kk], rv[kk], h2);

  if (k == 19) {
    float pv = lrelu(h2) * fcoW[lane];
    pv = wave_sum(pv);
    if (lane == 0) pred[i] = pv + fcob[0];
  }

  rbuf2[wv][lane] = h2;
  float zz = alinb[lane];
  const float4* rv2 = (const float4*)rbuf2[wv];
#pragma unroll
  for (int kk = 0; kk < 16; ++kk) zz = dot4(aw[kk], rv2[kk], zz);
  zout[((size_t)i * 20 + k) * 64 + lane] = tanh_f(zz);
}

// ---------------------------------------------------------------------------
// ALSTM attention head
// ---------------------------------------------------------------------------
__launch_bounds__(256)
__global__ void alstm_head(const float* __restrict__ r1,  // [512][20][64]
                           const float* __restrict__ W1,  // [32][64]
                           const float* __restrict__ b1,  // [32]
                           const float* __restrict__ W2,  // [32]
                           const float* __restrict__ Wo,  // [128]
                           const float* __restrict__ bo,  // [1]
                           float* __restrict__ alstm_out) {
  const int wv = threadIdx.x >> 6;
  const int lane = threadIdx.x & 63;
  const int i = blockIdx.x * 4 + wv;  // [0,512)
  const int e = lane & 31;
  __shared__ __align__(16) float rbuf[4][64];
  __shared__ float scb[4][20];

  float4 w1r[16];
  {
    const float4* p = (const float4*)(W1 + e * 64);
#pragma unroll
    for (int kk = 0; kk < 16; ++kk) w1r[kk] = p[kk];
  }
  const float b1e = b1[e];
  const float w2e = W2[e];

  for (int k = 0; k < 20; ++k) {
    rbuf[wv][lane] = r1[((size_t)i * 20 + k) * 64 + lane];
    float u = b1e;
    const float4* rp = (const float4*)rbuf[wv];
#pragma unroll
    for (int kk = 0; kk < 16; ++kk) u = dot4(w1r[kk], rp[kk], u);
    u = tanh_f(u) * w2e;
#pragma unroll
    for (int m = 16; m; m >>= 1) u += __shfl_xor(u, m);
    if (lane == 0) scb[wv][k] = u;
  }

  float mx = -1e30f;
#pragma unroll
  for (int k = 0; k < 20; ++k) mx = fmaxf(mx, scb[wv][k]);
  float p[20];
  float l = 0.0f;
#pragma unroll
  for (int k = 0; k < 20; ++k) {
    p[k] = __expf(scb[wv][k] - mx);
    l += p[k];
  }
  const float inv = fast_rcp(l);

  float oa = 0.0f, rlast = 0.0f;
#pragma unroll
  for (int k = 0; k < 20; ++k) {
    float rv = r1[((size_t)i * 20 + k) * 64 + lane];
    oa = fmaf(p[k], rv, oa);
    if (k == 19) rlast = rv;
  }
  oa *= inv;
  float v = fmaf(Wo[lane], rlast, Wo[64 + lane] * oa);
  v = wave_sum(v);
  if (lane == 0) alstm_out[i] = v + bo[0];
}

// ---------------------------------------------------------------------------
extern "C" void kernel_launch(void* const* d_in, const int* in_sizes, int n_in,
                              void* d_out, int out_size, void* d_ws, size_t ws_size,
                              hipStream_t stream) {
  const float* x      = (const float*)d_in[0];
  const float* Wih0   = (const float*)d_in[1];
  const float* Whh0   = (const float*)d_in[2];
  const float* bih0   = (const float*)d_in[3];
  const float* bhh0   = (const float*)d_in[4];
  const float* Wih1   = (const float*)d_in[5];
  const float* Whh1   = (const float*)d_in[6];
  const float* bih1   = (const float*)d_in[7];
  const float* bhh1   = (const float*)d_in[8];
  const float* transW = (const float*)d_in[9];
  const float* transb = (const float*)d_in[10];
  const float* a_vec  = (const float*)d_in[11];
  const float* fcW    = (const float*)d_in[12];
  const float* fcb    = (const float*)d_in[13];
  const float* fcoW   = (const float*)d_in[14];
  const float* fcob   = (const float*)d_in[15];
  const float* alinW  = (const float*)d_in[16];
  const float* alinb  = (const float*)d_in[17];
  const float* aWih0  = (const float*)d_in[18];
  const float* aWhh0  = (const float*)d_in[19];
  const float* abih0  = (const float*)d_in[20];
  const float* abhh0  = (const float*)d_in[21];
  const float* aWih1  = (const float*)d_in[22];
  const float* aWhh1  = (const float*)d_in[23];
  const float* abih1  = (const float*)d_in[24];
  const float* abhh1  = (const float*)d_in[25];
  const float* att1W  = (const float*)d_in[26];
  const float* att1b  = (const float*)d_in[27];
  const float* att2W  = (const float*)d_in[28];
  const float* aloutW = (const float*)d_in[29];
  const float* aloutb = (const float*)d_in[30];

  float* out = (float*)d_out;  // [0:512) alstm_out, [512:1024) pred

  float* W = (float*)d_ws;
  float* h_enc = W; W += 10240 * 64;      // reused as r0 (steps 7-8)
  float* vbuf  = W; W += 256;
  float* s_src = W; W += 10240;
  float* s_dst = W; W += 10240;
  float* hout  = W; W += 10240 * 64;
  float* zbuf  = W; W += 512 * 20 * 64;
  float* r1    = W; W += 512 * 20 * 64;
  float* w3a0  = W; W += 24576;
  float* w3a1  = W; W += 24576;
  // time-disjoint aliases: encoder weight buffers live in the zbuf region
  // (consumed at step 2; zbuf written at step 6).
  float* wx0b = zbuf;                  // 1152
  float* w4h0 = zbuf + 1152;           // 12288
  float* w4x1 = zbuf + 13440;          // 12288
  float* w4h1 = zbuf + 25728;          // 12288 (end 38016 << 655360)

  static bool attr_done = false;
  if (!attr_done) {
    hipFuncSetAttribute((const void*)gru2_enc,
                        hipFuncAttributeMaxDynamicSharedMemorySize, E_LDS);
    hipFuncSetAttribute((const void*)gru1,
                        hipFuncAttributeMaxDynamicSharedMemorySize, A_LDS);
    attr_done = true;
  }

  // 1) weight prep (encoder 3-plane quad-pack + ALSTM w3)
  w3_prep<<<48, 256, 0, stream>>>(Wih0, Whh0, Wih1, Whh1, aWih0, aWhh0,
                                  aWih1, aWhh1, wx0b, w4h0, w4x1, w4h1,
                                  w3a0, w3a1);
  // 2) fused 2-layer persistent GRU encoder: 256 blocks x 8 waves x SPW=5
  //    = 10240 seqs in ONE balanced round, 2 waves/SIMD
  gru2_enc<<<256, 512, E_LDS, stream>>>(x, wx0b, w4h0, w4x1, w4h1,
                                        bih0, bhh0, bih1, bhh1, h_enc);
  // 3) GAT score-vector prep
  gat_prep<<<1, 64, 0, stream>>>(transW, transb, a_vec, vbuf);
  // 4) per-row s_src/s_dst
  gat_svals<<<2560, 256, 0, stream>>>(h_enc, vbuf, s_src, s_dst);
  // 5) dense attention + residual
  gat_attn<<<2560, 256, 0, stream>>>(h_enc, s_src, s_dst, hout);
  // 6) fc + pred head + ALSTM input transform (z in [i][k][64])
  gat_out<<<2560, 256, 0, stream>>>(hout, fcW, fcb, fcoW, fcob, alinW, alinb,
                                    zbuf, out + 512);
  // 7) ALSTM GRU layer 0: z -> r0 (reuses h_enc storage)
  gru1<<<64, 512, A_LDS, stream>>>(zbuf, w3a0, abih0, abhh0, 20, h_enc);
  // 8) ALSTM GRU layer 1: r0 -> r1
  gru1<<<64, 512, A_LDS, stream>>>(h_enc, w3a1, abih1, abhh1, 20, r1);
  // 9) ALSTM attention head -> alstm_out
  alstm_head<<<128, 256, 0, stream>>>(r1, att1W, att1b, att2W, aloutW, aloutb,
                                      out);
}

// Round 7
// 1416.074 us; speedup vs baseline: 19.2964x; 1.2874x over previous
//
#include <hip/hip_runtime.h>

#define DEV __device__ __forceinline__

DEV float fast_rcp(float x) {
#if __has_builtin(__builtin_amdgcn_rcpf)
  return __builtin_amdgcn_rcpf(x);
#else
  return 1.0f / x;
#endif
}
DEV float sigm(float x) { return fast_rcp(1.0f + __expf(-x)); }
DEV float tanh_f(float x) {
  float e = __expf(-2.0f * fabsf(x));
  float t = 1.0f - 2.0f * e * fast_rcp(1.0f + e);
  return copysignf(t, x);
}
DEV float lrelu(float x) { return x > 0.0f ? x : 0.01f * x; }

DEV float wave_sum(float v) {
#pragma unroll
  for (int m = 32; m; m >>= 1) v += __shfl_xor(v, m);
  return v;
}
DEV float wave_max(float v) {
#pragma unroll
  for (int m = 32; m; m >>= 1) v = fmaxf(v, __shfl_xor(v, m));
  return v;
}
DEV float dot4(float4 w, float4 x, float acc) {
  acc = fmaf(w.x, x.x, acc);
  acc = fmaf(w.y, x.y, acc);
  acc = fmaf(w.z, x.z, acc);
  acc = fmaf(w.w, x.w, acc);
  return acc;
}

// SGPR broadcast of another lane's register value — VALU pipe, NOT DS pipe
// (__shfl lowers to ds_bpermute which shares the saturated LDS pipe).
DEV float bcast(float v, int lane) {
  return __int_as_float(__builtin_amdgcn_readlane(__float_as_int(v), lane));
}

// ---------------------------------------------------------------------------
// Persistent-GRU encoder, R10. Counter-driven diagnosis:
//  * R8->R9 conflicts 2.043e8 -> 4.078e8 (exactly 2x when waves 4->8): the
//    conflicts are the WEIGHT ds_read_b128s (~24 extra cyc each; 16B lane
//    stride -> 8-way bank collision per b32 phase), NOT the h-broadcasts.
//  * DS-pipe cost model matches both R8/R9 step times -> encoder is DS-bound.
// R10 removes BOTH load classes from the DS pipe:
//  * h state lives only in registers; h[k] broadcast via v_readlane (SGPR
//    path, VALU pipe). No h LDS reads, writes, or state. x likewise.
//  * weights in the R1-proven [k][192] j3-interleave; 3 scalar b32 reads per
//    k-row at dword stride 3 -> banks (3j+c)%32 -> 2 lanes/bank = FREE
//    (R1 measured literally zero conflicts with this exact pattern).
// Hard rules kept: k-loops rolled (unroll_count(4), RULE 1 — only 3 weight
// regs live per iter); no min-waves launch-bounds arg (RULE 3).
// Partition: 256 blocks x 8 waves x SPW=5 = 10240 seqs, ONE balanced round,
// 2 waves/SIMD for VALU/DS overlap. LDS = weights only: 147,456 B.
// ---------------------------------------------------------------------------
constexpr int E_SPW = 5;
constexpr int E_WAVES = 8;
constexpr int L_W0 = 0;          // Whh0 rows (w3e0 rows 6..69): 64*192 dw
constexpr int L_W1 = 12288;      // w3e1: 128*192 dw
constexpr int E_DW = 36864;
constexpr int E_LDS = E_DW * 4;  // 147,456 B <= 160 KiB

__launch_bounds__(512)
__global__ void gru2_enc(const float* __restrict__ x,      // [10240][60][6]
                         const float* __restrict__ w3e0,   // [70][192] j3-interleave
                         const float* __restrict__ w3e1,   // [128][192]
                         const float* __restrict__ bih0, const float* __restrict__ bhh0,
                         const float* __restrict__ bih1, const float* __restrict__ bhh1,
                         float* __restrict__ h_out) {      // [10240][64]
  extern __shared__ float lds[];
  const int tid = threadIdx.x;
  const int wave = tid >> 6;
  const int j = tid & 63;
  const int j3 = j * 3;

  // cooperative weight load into LDS (coalesced float4)
  {
    const float4* s0 = (const float4*)(w3e0 + 6 * 192);  // Whh0 rows
    for (int i = tid; i < 12288 / 4; i += 512) ((float4*)(lds + L_W0))[i] = s0[i];
    const float4* s1 = (const float4*)w3e1;
    for (int i = tid; i < 24576 / 4; i += 512) ((float4*)(lds + L_W1))[i] = s1[i];
  }
  // register weights: Wih0 (6 rows x 3 gates per lane)
  float wx0[6][3];
#pragma unroll
  for (int k = 0; k < 6; ++k)
#pragma unroll
    for (int g = 0; g < 3; ++g) wx0[k][g] = w3e0[k * 192 + j3 + g];

  const float br0 = bih0[j] + bhh0[j];
  const float bz0 = bih0[64 + j] + bhh0[64 + j];
  const float bxn0 = bih0[128 + j];
  const float bhn0 = bhh0[128 + j];
  const float br1 = bih1[j] + bhh1[j];
  const float bz1 = bih1[64 + j] + bhh1[64 + j];
  const float bxn1 = bih1[128 + j];
  const float bhn1 = bhh1[128 + j];

  float h0r[E_SPW], h1r[E_SPW];
#pragma unroll
  for (int s = 0; s < E_SPW; ++s) { h0r[s] = 0.0f; h1r[s] = 0.0f; }
  __syncthreads();  // weights visible; the only barrier

  const int seq0 = blockIdx.x * (E_WAVES * E_SPW) + wave * E_SPW;
  // x carrier: lane j<30 holds component ci of seq si; consumed via readlane
  const int si = j / 6;
  const int ci = j - si * 6;
  const bool xlane = (j < 6 * E_SPW);
  const float* xg = x + (size_t)(seq0 + si) * 360 + ci;

  float xcur = xlane ? xg[0] : 0.0f;  // t = 0

  for (int t = 0; t < 60; ++t) {
    float xnext = (xlane && t + 1 < 60) ? xg[(size_t)(t + 1) * 6] : 0.0f;

    float ar[E_SPW], az[E_SPW], anx[E_SPW], anh[E_SPW];
#pragma unroll
    for (int s = 0; s < E_SPW; ++s) { ar[s] = 0.f; az[s] = 0.f; anx[s] = 0.f; anh[s] = 0.f; }

    // ---- layer0 h-part: 64 k-rows; weights 3xb32 (conflict-free), h via
    //      readlane of old h0r (register state)
#pragma clang loop unroll_count(4)
    for (int k = 0; k < 64; ++k) {
      const int wb = L_W0 + k * 192 + j3;
      const float wr = lds[wb], wz = lds[wb + 1], wn = lds[wb + 2];
#pragma unroll
      for (int s = 0; s < E_SPW; ++s) {
        const float hk = bcast(h0r[s], k);
        ar[s] = fmaf(wr, hk, ar[s]);
        az[s] = fmaf(wz, hk, az[s]);
        anh[s] = fmaf(wn, hk, anh[s]);
      }
    }
    // ---- layer0 x-part: register weights, x via readlane (const lane idx)
#pragma unroll
    for (int s = 0; s < E_SPW; ++s) {
#pragma unroll
      for (int c = 0; c < 6; ++c) {
        const float xk = bcast(xcur, s * 6 + c);
        ar[s] = fmaf(wx0[c][0], xk, ar[s]);
        az[s] = fmaf(wx0[c][1], xk, az[s]);
        anx[s] = fmaf(wx0[c][2], xk, anx[s]);
      }
    }
    // ---- layer0 epilogue: lane j owns all 3 gates of unit j; pure register
#pragma unroll
    for (int s = 0; s < E_SPW; ++s) {
      float r = sigm(ar[s] + br0);
      float z = sigm(az[s] + bz0);
      float n = tanh_f(anx[s] + bxn0 + r * (anh[s] + bhn0));
      h0r[s] = (1.0f - z) * n + z * h0r[s];
    }

#pragma unroll
    for (int s = 0; s < E_SPW; ++s) { ar[s] = 0.f; az[s] = 0.f; anx[s] = 0.f; anh[s] = 0.f; }
    // ---- layer1 x-part over fresh h0 (readlane of new h0r)
#pragma clang loop unroll_count(4)
    for (int k = 0; k < 64; ++k) {
      const int wb = L_W1 + k * 192 + j3;
      const float wr = lds[wb], wz = lds[wb + 1], wn = lds[wb + 2];
#pragma unroll
      for (int s = 0; s < E_SPW; ++s) {
        const float hk = bcast(h0r[s], k);
        ar[s] = fmaf(wr, hk, ar[s]);
        az[s] = fmaf(wz, hk, az[s]);
        anx[s] = fmaf(wn, hk, anx[s]);
      }
    }
    // ---- layer1 h-part over h1_old
#pragma clang loop unroll_count(4)
    for (int k = 0; k < 64; ++k) {
      const int wb = L_W1 + (64 + k) * 192 + j3;
      const float wr = lds[wb], wz = lds[wb + 1], wn = lds[wb + 2];
#pragma unroll
      for (int s = 0; s < E_SPW; ++s) {
        const float hk = bcast(h1r[s], k);
        ar[s] = fmaf(wr, hk, ar[s]);
        az[s] = fmaf(wz, hk, az[s]);
        anh[s] = fmaf(wn, hk, anh[s]);
      }
    }
    // ---- layer1 epilogue
#pragma unroll
    for (int s = 0; s < E_SPW; ++s) {
      float r = sigm(ar[s] + br1);
      float z = sigm(az[s] + bz1);
      float n = tanh_f(anx[s] + bxn1 + r * (anh[s] + bhn1));
      h1r[s] = (1.0f - z) * n + z * h1r[s];
    }
    xcur = xnext;
  }

#pragma unroll
  for (int s = 0; s < E_SPW; ++s)
    h_out[(size_t)(seq0 + s) * 64 + j] = h1r[s];
}

// ---------------------------------------------------------------------------
// Single-layer GRU for the ALSTM (I = 64). Unchanged from R9 (validated;
// small share of runtime). 8 waves/block, 1 seq/wave, grid 64.
// ---------------------------------------------------------------------------
constexpr int A_W_DW = 128 * 192;  // 24576
constexpr int A_WAVES = 8;
constexpr int A_LDS = (A_W_DW + A_WAVES * 128) * 4;  // 102400 B

__launch_bounds__(512, 2)
__global__ void gru1(const float* __restrict__ xin,  // [N][T][64]
                     const float* __restrict__ w3,   // [128][192]
                     const float* __restrict__ bih, const float* __restrict__ bhh,
                     int T,
                     float* __restrict__ rout) {     // [N][T][64]
  extern __shared__ float lds[];
  const int tid = threadIdx.x;
  const int wave = tid >> 6;
  const int j = tid & 63;
  const int j3 = j * 3;
  const int XB = A_W_DW + wave * 128;  // [0..63]=x_t, [64..127]=h

  {
    const float4* sp = (const float4*)w3;
    for (int i = tid; i < A_W_DW / 4; i += 512) ((float4*)lds)[i] = sp[i];
  }
  const float br = bih[j] + bhh[j];
  const float bz = bih[64 + j] + bhh[64 + j];
  const float bxn = bih[128 + j];
  const float bhn = bhh[128 + j];

  float hr = 0.0f;
  lds[XB + 64 + j] = 0.0f;
  __syncthreads();

  const int seq = blockIdx.x * A_WAVES + wave;
  const float* xs = xin + (size_t)seq * T * 64;

#define A_QUAD(WROW0, HOFF, AN)                                            \
  {                                                                        \
    float4 hv = *(const float4*)&lds[XB + (HOFF)];                         \
    _Pragma("unroll") for (int c = 0; c < 4; ++c) {                        \
      const float wr = lds[((WROW0) + c) * 192 + j3];                      \
      const float wz = lds[((WROW0) + c) * 192 + j3 + 1];                  \
      const float wn = lds[((WROW0) + c) * 192 + j3 + 2];                  \
      const float hc = (c == 0) ? hv.x : (c == 1) ? hv.y                   \
                      : (c == 2) ? hv.z : hv.w;                            \
      ar = fmaf(wr, hc, ar);                                               \
      az = fmaf(wz, hc, az);                                               \
      AN = fmaf(wn, hc, AN);                                               \
    }                                                                      \
  }

  float xcur = xs[j];  // t = 0
  for (int t = 0; t < T; ++t) {
    float xnext = (t + 1 < T) ? xs[(size_t)(t + 1) * 64 + j] : 0.0f;
    lds[XB + j] = xcur;  // wave-private; ordered by lgkmcnt

    float ar = 0.f, az = 0.f, anx = 0.f, anh = 0.f;
#pragma unroll
    for (int kq = 0; kq < 16; ++kq) A_QUAD(kq * 4, kq * 4, anx);        // input
#pragma unroll
    for (int kq = 0; kq < 16; ++kq) A_QUAD(64 + kq * 4, 64 + kq * 4, anh);  // rec

    float r = sigm(ar + br);
    float z = sigm(az + bz);
    float n = tanh_f(anx + bxn + r * (anh + bhn));
    float h = (1.0f - z) * n + z * hr;
    hr = h;
    lds[XB + 64 + j] = h;
    rout[((size_t)seq * T + t) * 64 + j] = h;
    xcur = xnext;
  }
#undef A_QUAD
}

// ---------------------------------------------------------------------------
// Weight interleave prep (R1 format): W3[k][j*3+g] =
//   (k<I ? Wih[g*64+j][k] : Whh[g*64+j][k-I])
// Sections: 0: e0 [70][192] (I=6); 1: e1 [128][192]; 2,3: ALSTM a0,a1.
// ---------------------------------------------------------------------------
__global__ void w3_prep(const float* __restrict__ Wih0, const float* __restrict__ Whh0,
                        const float* __restrict__ Wih1, const float* __restrict__ Whh1,
                        const float* __restrict__ aWih0, const float* __restrict__ aWhh0,
                        const float* __restrict__ aWih1, const float* __restrict__ aWhh1,
                        float* __restrict__ d_e0, float* __restrict__ d_e1,
                        float* __restrict__ d_a0, float* __restrict__ d_a1) {
  const int sec = blockIdx.x >> 3;
  const int bi = blockIdx.x & 7;
  const float* Wih; const float* Whh; float* dst; int I;
  if (sec == 0)      { Wih = Wih0;  Whh = Whh0;  dst = d_e0; I = 6; }
  else if (sec == 1) { Wih = Wih1;  Whh = Whh1;  dst = d_e1; I = 64; }
  else if (sec == 2) { Wih = aWih0; Whh = aWhh0; dst = d_a0; I = 64; }
  else               { Wih = aWih1; Whh = aWhh1; dst = d_a1; I = 64; }
  const int tot = (I + 64) * 192;
  for (int idx = bi * blockDim.x + threadIdx.x; idx < tot; idx += 8 * blockDim.x) {
    const int k = idx / 192;
    const int rem = idx - k * 192;
    const int jj = rem / 3;
    const int g = rem - jj * 3;
    dst[idx] = (k < I) ? Wih[(g * 64 + jj) * I + k] : Whh[(g * 64 + jj) * 64 + (k - I)];
  }
}

// ---------------------------------------------------------------------------
// GAT algebraic prep
// ---------------------------------------------------------------------------
__global__ void gat_prep(const float* __restrict__ tW, const float* __restrict__ tb,
                         const float* __restrict__ a, float* __restrict__ vbuf) {
  const int d = threadIdx.x;  // 64 threads
  float vd = 0.0f, vs = 0.0f;
  for (int e = 0; e < 64; ++e) {
    float w = tW[e * 64 + d];
    vd = fmaf(w, a[e], vd);
    vs = fmaf(w, a[64 + e], vs);
  }
  vbuf[d] = vd;
  vbuf[64 + d] = vs;
  if (d == 0) {
    float cd = 0.0f, cs = 0.0f;
    for (int e = 0; e < 64; ++e) {
      cd = fmaf(tb[e], a[e], cd);
      cs = fmaf(tb[e], a[64 + e], cs);
    }
    vbuf[128] = cd;
    vbuf[129] = cs;
  }
}

__global__ void gat_svals(const float* __restrict__ h_enc, const float* __restrict__ vbuf,
                          float* __restrict__ s_src, float* __restrict__ s_dst) {
  const int wave = (blockIdx.x * blockDim.x + threadIdx.x) >> 6;
  const int lane = threadIdx.x & 63;
  float h = h_enc[(size_t)wave * 64 + lane];
  float pd = h * vbuf[lane];
  float ps = h * vbuf[64 + lane];
  pd = wave_sum(pd);
  ps = wave_sum(ps);
  if (lane == 0) {
    s_dst[wave] = pd + vbuf[128];
    s_src[wave] = ps + vbuf[129];
  }
}

// ---------------------------------------------------------------------------
// Dense all-pairs attention per group k (m=512)
// ---------------------------------------------------------------------------
__launch_bounds__(256)
__global__ void gat_attn(const float* __restrict__ h_enc,
                         const float* __restrict__ s_src,
                         const float* __restrict__ s_dst,
                         float* __restrict__ hout) {
  const int k = blockIdx.x >> 7;
  const int tile = blockIdx.x & 127;
  const int wv = threadIdx.x >> 6;
  const int lane = threadIdx.x & 63;
  const int i = tile * 4 + wv;
  __shared__ float sdbuf[512];
  __shared__ __align__(16) float pbuf[4][512];

  for (int u = threadIdx.x; u < 512; u += 256) sdbuf[u] = s_dst[k * 512 + u];
  __syncthreads();

  const float si = s_src[k * 512 + i];
  float ev[8];
  float mx = -1e30f;
#pragma unroll
  for (int u = 0; u < 8; ++u) {
    ev[u] = lrelu(si + sdbuf[lane + u * 64]);
    mx = fmaxf(mx, ev[u]);
  }
  mx = wave_max(mx);
  float lsum = 0.0f;
#pragma unroll
  for (int u = 0; u < 8; ++u) {
    float p = __expf(ev[u] - mx);
    pbuf[wv][lane + u * 64] = p;
    lsum += p;
  }
  lsum = wave_sum(lsum);
  const float inv = fast_rcp(lsum);

  const float* hk = h_enc + (size_t)k * 512 * 64;
  const float4* pv = (const float4*)pbuf[wv];
  float acc0 = 0.0f, acc1 = 0.0f;
#pragma unroll 2
  for (int jj = 0; jj < 128; ++jj) {
    float4 p = pv[jj];
    const float* hp = hk + (size_t)(jj * 4) * 64 + lane;
    acc0 = fmaf(p.x, hp[0], acc0);
    acc1 = fmaf(p.y, hp[64], acc1);
    acc0 = fmaf(p.z, hp[128], acc0);
    acc1 = fmaf(p.w, hp[192], acc1);
  }
  hout[((size_t)k * 512 + i) * 64 + lane] =
      (acc0 + acc1) * inv + hk[(size_t)i * 64 + lane];
}

// ---------------------------------------------------------------------------
// Post-GAT transform + pred head + ALSTM input transform
// ---------------------------------------------------------------------------
__launch_bounds__(256)
__global__ void gat_out(const float* __restrict__ hin,
                        const float* __restrict__ fcW, const float* __restrict__ fcb,
                        const float* __restrict__ fcoW, const float* __restrict__ fcob,
                        const float* __restrict__ alinW, const float* __restrict__ alinb,
                        float* __restrict__ zout, float* __restrict__ pred) {
  const int wv = threadIdx.x >> 6;
  const int lane = threadIdx.x & 63;
  const int n = blockIdx.x * 4 + wv;  // [0,10240)
  const int k = n >> 9;
  const int i = n & 511;
  __shared__ __align__(16) float rbuf[4][64];
  __shared__ __align__(16) float rbuf2[4][64];

  float4 fw[16], aw[16];
  {
    const float4* p1 = (const float4*)(fcW + lane * 64);
    const float4* p2 = (const float4*)(alinW + lane * 64);
#pragma unroll
    for (int kk = 0; kk < 16; ++kk) fw[kk] = p1[kk];
#pragma unroll
    for (int kk = 0; kk < 16; ++kk) aw[kk] = p2[kk];
  }

  rbuf[wv][lane] = hin[(size_t)n * 64 + lane];
  float h2 = fcb[lane];
  const float4* rv = (const float4*)rbuf[wv];
#pragma unroll
  for (int kk = 0; kk < 16; ++kk) h2 = dot4(fw[kk], rv[kk], h2);

  if (k == 19) {
    float pv = lrelu(h2) * fcoW[lane];
    pv = wave_sum(pv);
    if (lane == 0) pred[i] = pv + fcob[0];
  }

  rbuf2[wv][lane] = h2;
  float zz = alinb[lane];
  const float4* rv2 = (const float4*)rbuf2[wv];
#pragma unroll
  for (int kk = 0; kk < 16; ++kk) zz = dot4(aw[kk], rv2[kk], zz);
  zout[((size_t)i * 20 + k) * 64 + lane] = tanh_f(zz);
}

// ---------------------------------------------------------------------------
// ALSTM attention head
// ---------------------------------------------------------------------------
__launch_bounds__(256)
__global__ void alstm_head(const float* __restrict__ r1,  // [512][20][64]
                           const float* __restrict__ W1,  // [32][64]
                           const float* __restrict__ b1,  // [32]
                           const float* __restrict__ W2,  // [32]
                           const float* __restrict__ Wo,  // [128]
                           const float* __restrict__ bo,  // [1]
                           float* __restrict__ alstm_out) {
  const int wv = threadIdx.x >> 6;
  const int lane = threadIdx.x & 63;
  const int i = blockIdx.x * 4 + wv;  // [0,512)
  const int e = lane & 31;
  __shared__ __align__(16) float rbuf[4][64];
  __shared__ float scb[4][20];

  float4 w1r[16];
  {
    const float4* p = (const float4*)(W1 + e * 64);
#pragma unroll
    for (int kk = 0; kk < 16; ++kk) w1r[kk] = p[kk];
  }
  const float b1e = b1[e];
  const float w2e = W2[e];

  for (int k = 0; k < 20; ++k) {
    rbuf[wv][lane] = r1[((size_t)i * 20 + k) * 64 + lane];
    float u = b1e;
    const float4* rp = (const float4*)rbuf[wv];
#pragma unroll
    for (int kk = 0; kk < 16; ++kk) u = dot4(w1r[kk], rp[kk], u);
    u = tanh_f(u) * w2e;
#pragma unroll
    for (int m = 16; m; m >>= 1) u += __shfl_xor(u, m);
    if (lane == 0) scb[wv][k] = u;
  }

  float mx = -1e30f;
#pragma unroll
  for (int k = 0; k < 20; ++k) mx = fmaxf(mx, scb[wv][k]);
  float p[20];
  float l = 0.0f;
#pragma unroll
  for (int k = 0; k < 20; ++k) {
    p[k] = __expf(scb[wv][k] - mx);
    l += p[k];
  }
  const float inv = fast_rcp(l);

  float oa = 0.0f, rlast = 0.0f;
#pragma unroll
  for (int k = 0; k < 20; ++k) {
    float rv = r1[((size_t)i * 20 + k) * 64 + lane];
    oa = fmaf(p[k], rv, oa);
    if (k == 19) rlast = rv;
  }
  oa *= inv;
  float v = fmaf(Wo[lane], rlast, Wo[64 + lane] * oa);
  v = wave_sum(v);
  if (lane == 0) alstm_out[i] = v + bo[0];
}

// ---------------------------------------------------------------------------
extern "C" void kernel_launch(void* const* d_in, const int* in_sizes, int n_in,
                              void* d_out, int out_size, void* d_ws, size_t ws_size,
                              hipStream_t stream) {
  const float* x      = (const float*)d_in[0];
  const float* Wih0   = (const float*)d_in[1];
  const float* Whh0   = (const float*)d_in[2];
  const float* bih0   = (const float*)d_in[3];
  const float* bhh0   = (const float*)d_in[4];
  const float* Wih1   = (const float*)d_in[5];
  const float* Whh1   = (const float*)d_in[6];
  const float* bih1   = (const float*)d_in[7];
  const float* bhh1   = (const float*)d_in[8];
  const float* transW = (const float*)d_in[9];
  const float* transb = (const float*)d_in[10];
  const float* a_vec  = (const float*)d_in[11];
  const float* fcW    = (const float*)d_in[12];
  const float* fcb    = (const float*)d_in[13];
  const float* fcoW   = (const float*)d_in[14];
  const float* fcob   = (const float*)d_in[15];
  const float* alinW  = (const float*)d_in[16];
  const float* alinb  = (const float*)d_in[17];
  const float* aWih0  = (const float*)d_in[18];
  const float* aWhh0  = (const float*)d_in[19];
  const float* abih0  = (const float*)d_in[20];
  const float* abhh0  = (const float*)d_in[21];
  const float* aWih1  = (const float*)d_in[22];
  const float* aWhh1  = (const float*)d_in[23];
  const float* abih1  = (const float*)d_in[24];
  const float* abhh1  = (const float*)d_in[25];
  const float* att1W  = (const float*)d_in[26];
  const float* att1b  = (const float*)d_in[27];
  const float* att2W  = (const float*)d_in[28];
  const float* aloutW = (const float*)d_in[29];
  const float* aloutb = (const float*)d_in[30];

  float* out = (float*)d_out;  // [0:512) alstm_out, [512:1024) pred

  float* W = (float*)d_ws;
  float* h_enc = W; W += 10240 * 64;      // reused as r0 (steps 7-8)
  float* vbuf  = W; W += 256;
  float* s_src = W; W += 10240;
  float* s_dst = W; W += 10240;
  float* hout  = W; W += 10240 * 64;
  float* zbuf  = W; W += 512 * 20 * 64;
  float* r1    = W; W += 512 * 20 * 64;
  float* w3a0  = W; W += 24576;
  float* w3a1  = W; W += 24576;
  // time-disjoint aliases: encoder weight buffers live in the zbuf region
  // (consumed at step 2; zbuf written at step 6).
  float* w3e0 = zbuf;                  // [70][192]  = 13440 dw
  float* w3e1 = zbuf + 13440;          // [128][192] = 24576 dw (end 38016)

  static bool attr_done = false;
  if (!attr_done) {
    hipFuncSetAttribute((const void*)gru2_enc,
                        hipFuncAttributeMaxDynamicSharedMemorySize, E_LDS);
    hipFuncSetAttribute((const void*)gru1,
                        hipFuncAttributeMaxDynamicSharedMemorySize, A_LDS);
    attr_done = true;
  }

  // 1) weight prep (R1 j3-interleave format for all 4 GRU layers)
  w3_prep<<<32, 256, 0, stream>>>(Wih0, Whh0, Wih1, Whh1, aWih0, aWhh0,
                                  aWih1, aWhh1, w3e0, w3e1, w3a0, w3a1);
  // 2) fused 2-layer persistent GRU encoder: 256 blocks x 8 waves x SPW=5
  //    = 10240 seqs in ONE balanced round; register h-state + readlane
  gru2_enc<<<256, 512, E_LDS, stream>>>(x, w3e0, w3e1, bih0, bhh0, bih1,
                                        bhh1, h_enc);
  // 3) GAT score-vector prep
  gat_prep<<<1, 64, 0, stream>>>(transW, transb, a_vec, vbuf);
  // 4) per-row s_src/s_dst
  gat_svals<<<2560, 256, 0, stream>>>(h_enc, vbuf, s_src, s_dst);
  // 5) dense attention + residual
  gat_attn<<<2560, 256, 0, stream>>>(h_enc, s_src, s_dst, hout);
  // 6) fc + pred head + ALSTM input transform (z in [i][k][64])
  gat_out<<<2560, 256, 0, stream>>>(hout, fcW, fcb, fcoW, fcob, alinW, alinb,
                                    zbuf, out + 512);
  // 7) ALSTM GRU layer 0: z -> r0 (reuses h_enc storage)
  gru1<<<64, 512, A_LDS, stream>>>(zbuf, w3a0, abih0, abhh0, 20, h_enc);
  // 8) ALSTM GRU layer 1: r0 -> r1
  gru1<<<64, 512, A_LDS, stream>>>(h_enc, w3a1, abih1, abhh1, 20, r1);
  // 9) ALSTM attention head -> alstm_out
  alstm_head<<<128, 256, 0, stream>>>(r1, att1W, att1b, att2W, aloutW, aloutb,
                                      out);
}

// Round 8
// 1384.652 us; speedup vs baseline: 19.7343x; 1.0227x over previous
//
#include <hip/hip_runtime.h>

#define DEV __device__ __forceinline__

typedef float f2 __attribute__((ext_vector_type(2)));

DEV float fast_rcp(float x) {
#if __has_builtin(__builtin_amdgcn_rcpf)
  return __builtin_amdgcn_rcpf(x);
#else
  return 1.0f / x;
#endif
}
DEV float sigm(float x) { return fast_rcp(1.0f + __expf(-x)); }
DEV float tanh_f(float x) {
  float e = __expf(-2.0f * fabsf(x));
  float t = 1.0f - 2.0f * e * fast_rcp(1.0f + e);
  return copysignf(t, x);
}
DEV float lrelu(float x) { return x > 0.0f ? x : 0.01f * x; }

DEV float wave_sum(float v) {
#pragma unroll
  for (int m = 32; m; m >>= 1) v += __shfl_xor(v, m);
  return v;
}
DEV float wave_max(float v) {
#pragma unroll
  for (int m = 32; m; m >>= 1) v = fmaxf(v, __shfl_xor(v, m));
  return v;
}
DEV float dot4(float4 w, float4 x, float acc) {
  acc = fmaf(w.x, x.x, acc);
  acc = fmaf(w.y, x.y, acc);
  acc = fmaf(w.z, x.z, acc);
  acc = fmaf(w.w, x.w, acc);
  return acc;
}

// SGPR broadcast of another lane's register value — VALU pipe, NOT DS pipe.
DEV float bcast(float v, int lane) {
  return __int_as_float(__builtin_amdgcn_readlane(__float_as_int(v), lane));
}

// ---------------------------------------------------------------------------
// Persistent-GRU encoder, R11. R10 (1135us) verified: conflicts ~0 (weight
// b128s were the 4e8 source; scalar stride-3 weights are free), VALUBusy 84%
// -> VALU-issue-bound. R11 cuts FMA issue slots ~40% by packing the SEQ
// dimension into float2 and emitting llvm.fma.v2f32 -> v_pk_fma_f32 (gfx950
// has full-rate packed fp32). Seq pairs (0,1),(2,3) + scalar tail s=4.
// h-pairs are wave-uniform (2x readlane) -> SGPR pair operand; weight splats
// {w,w} broadcast via VOP3P op_sel. If codegen falls back to scalar FMA the
// semantics are identical -> neutral floor.
// Hard rules kept: k-loops ROLLED (unroll_count(4), RULE 1); scalar b32
// weights stride-3 (RULE 2 outcome); no min-waves launch-bounds (RULE 3).
// Partition: 256 blocks x 8 waves x SPW=5 = 10240 seqs, ONE balanced round,
// 2 waves/SIMD. LDS = weights only: 147,456 B. h/x state in registers.
// ---------------------------------------------------------------------------
constexpr int E_SPW = 5;
constexpr int E_WAVES = 8;
constexpr int L_W0 = 0;          // Whh0 rows (w3e0 rows 6..69): 64*192 dw
constexpr int L_W1 = 12288;      // w3e1: 128*192 dw
constexpr int E_DW = 36864;
constexpr int E_LDS = E_DW * 4;  // 147,456 B <= 160 KiB

// One 64-row dot phase: weights 3x scalar b32 (conflict-free), h broadcast
// via readlane from register state HA[0..4]; seq-packed pk-FMA accumulate.
// ar01/ar23/ar4, az01/az23/az4 fixed accumulator names; n-gate targets passed.
#define DOT_PHASE(WBASE, HA, AN01, AN23, AN4)                         \
  _Pragma("clang loop unroll_count(4)")                               \
  for (int k = 0; k < 64; ++k) {                                      \
    const int wb = (WBASE) + k * 192 + j3;                            \
    const float wr = lds[wb], wz = lds[wb + 1], wn = lds[wb + 2];     \
    const f2 h01v = {bcast(HA[0], k), bcast(HA[1], k)};               \
    const f2 h23v = {bcast(HA[2], k), bcast(HA[3], k)};               \
    const float h4v = bcast(HA[4], k);                                \
    const f2 wr2 = {wr, wr}, wz2 = {wz, wz}, wn2 = {wn, wn};          \
    ar01 = __builtin_elementwise_fma(wr2, h01v, ar01);                \
    ar23 = __builtin_elementwise_fma(wr2, h23v, ar23);                \
    ar4 = fmaf(wr, h4v, ar4);                                         \
    az01 = __builtin_elementwise_fma(wz2, h01v, az01);                \
    az23 = __builtin_elementwise_fma(wz2, h23v, az23);                \
    az4 = fmaf(wz, h4v, az4);                                         \
    AN01 = __builtin_elementwise_fma(wn2, h01v, AN01);                \
    AN23 = __builtin_elementwise_fma(wn2, h23v, AN23);                \
    AN4 = fmaf(wn, h4v, AN4);                                         \
  }

// layer-0 x-part for one seq (scalar; only 6 components)
#define XPART(S, ARx, AZx, ANXx)                       \
  _Pragma("unroll") for (int c = 0; c < 6; ++c) {      \
    const float xk = bcast(xcur, (S) * 6 + c);         \
    ARx = fmaf(wx0[c][0], xk, ARx);                    \
    AZx = fmaf(wx0[c][1], xk, AZx);                    \
    ANXx = fmaf(wx0[c][2], xk, ANXx);                  \
  }

// GRU epilogue for one seq
#define EPI(S, ARx, AZx, ANXx, ANHx, HARR, BR, BZ, BXN, BHN)   \
  {                                                            \
    float r_ = sigm((ARx) + (BR));                             \
    float z_ = sigm((AZx) + (BZ));                             \
    float n_ = tanh_f((ANXx) + (BXN) + r_ * ((ANHx) + (BHN))); \
    HARR[S] = (1.0f - z_) * n_ + z_ * HARR[S];                 \
  }

__launch_bounds__(512)
__global__ void gru2_enc(const float* __restrict__ x,      // [10240][60][6]
                         const float* __restrict__ w3e0,   // [70][192] j3-interleave
                         const float* __restrict__ w3e1,   // [128][192]
                         const float* __restrict__ bih0, const float* __restrict__ bhh0,
                         const float* __restrict__ bih1, const float* __restrict__ bhh1,
                         float* __restrict__ h_out) {      // [10240][64]
  extern __shared__ float lds[];
  const int tid = threadIdx.x;
  const int wave = tid >> 6;
  const int j = tid & 63;
  const int j3 = j * 3;

  // cooperative weight load into LDS (coalesced float4)
  {
    const float4* s0 = (const float4*)(w3e0 + 6 * 192);  // Whh0 rows
    for (int i = tid; i < 12288 / 4; i += 512) ((float4*)(lds + L_W0))[i] = s0[i];
    const float4* s1 = (const float4*)w3e1;
    for (int i = tid; i < 24576 / 4; i += 512) ((float4*)(lds + L_W1))[i] = s1[i];
  }
  // register weights: Wih0 (6 rows x 3 gates per lane)
  float wx0[6][3];
#pragma unroll
  for (int k = 0; k < 6; ++k)
#pragma unroll
    for (int g = 0; g < 3; ++g) wx0[k][g] = w3e0[k * 192 + j3 + g];

  const float br0 = bih0[j] + bhh0[j];
  const float bz0 = bih0[64 + j] + bhh0[64 + j];
  const float bxn0 = bih0[128 + j];
  const float bhn0 = bhh0[128 + j];
  const float br1 = bih1[j] + bhh1[j];
  const float bz1 = bih1[64 + j] + bhh1[64 + j];
  const float bxn1 = bih1[128 + j];
  const float bhn1 = bhh1[128 + j];

  float h0r[E_SPW], h1r[E_SPW];
#pragma unroll
  for (int s = 0; s < E_SPW; ++s) { h0r[s] = 0.0f; h1r[s] = 0.0f; }
  __syncthreads();  // weights visible; the only barrier

  const int seq0 = blockIdx.x * (E_WAVES * E_SPW) + wave * E_SPW;
  // x carrier: lane j<30 holds component ci of seq si; consumed via readlane
  const int si = j / 6;
  const int ci = j - si * 6;
  const bool xlane = (j < 6 * E_SPW);
  const float* xg = x + (size_t)(seq0 + si) * 360 + ci;

  float xcur = xlane ? xg[0] : 0.0f;  // t = 0

  for (int t = 0; t < 60; ++t) {
    float xnext = (xlane && t + 1 < 60) ? xg[(size_t)(t + 1) * 6] : 0.0f;

    // ======== layer 0 ========
    f2 ar01 = {0.f, 0.f}, ar23 = {0.f, 0.f};
    f2 az01 = {0.f, 0.f}, az23 = {0.f, 0.f};
    f2 anx01 = {0.f, 0.f}, anx23 = {0.f, 0.f};
    f2 anh01 = {0.f, 0.f}, anh23 = {0.f, 0.f};
    float ar4 = 0.f, az4 = 0.f, anx4 = 0.f, anh4 = 0.f;

    DOT_PHASE(L_W0, h0r, anh01, anh23, anh4)

    XPART(0, ar01.x, az01.x, anx01.x)
    XPART(1, ar01.y, az01.y, anx01.y)
    XPART(2, ar23.x, az23.x, anx23.x)
    XPART(3, ar23.y, az23.y, anx23.y)
    XPART(4, ar4, az4, anx4)

    EPI(0, ar01.x, az01.x, anx01.x, anh01.x, h0r, br0, bz0, bxn0, bhn0)
    EPI(1, ar01.y, az01.y, anx01.y, anh01.y, h0r, br0, bz0, bxn0, bhn0)
    EPI(2, ar23.x, az23.x, anx23.x, anh23.x, h0r, br0, bz0, bxn0, bhn0)
    EPI(3, ar23.y, az23.y, anx23.y, anh23.y, h0r, br0, bz0, bxn0, bhn0)
    EPI(4, ar4, az4, anx4, anh4, h0r, br0, bz0, bxn0, bhn0)

    // ======== layer 1 ========
    ar01 = (f2){0.f, 0.f}; ar23 = (f2){0.f, 0.f};
    az01 = (f2){0.f, 0.f}; az23 = (f2){0.f, 0.f};
    anx01 = (f2){0.f, 0.f}; anx23 = (f2){0.f, 0.f};
    anh01 = (f2){0.f, 0.f}; anh23 = (f2){0.f, 0.f};
    ar4 = 0.f; az4 = 0.f; anx4 = 0.f; anh4 = 0.f;

    DOT_PHASE(L_W1, h0r, anx01, anx23, anx4)               // x-part over fresh h0
    DOT_PHASE(L_W1 + 64 * 192, h1r, anh01, anh23, anh4)    // h-part over h1_old

    EPI(0, ar01.x, az01.x, anx01.x, anh01.x, h1r, br1, bz1, bxn1, bhn1)
    EPI(1, ar01.y, az01.y, anx01.y, anh01.y, h1r, br1, bz1, bxn1, bhn1)
    EPI(2, ar23.x, az23.x, anx23.x, anh23.x, h1r, br1, bz1, bxn1, bhn1)
    EPI(3, ar23.y, az23.y, anx23.y, anh23.y, h1r, br1, bz1, bxn1, bhn1)
    EPI(4, ar4, az4, anx4, anh4, h1r, br1, bz1, bxn1, bhn1)

    xcur = xnext;
  }

#pragma unroll
  for (int s = 0; s < E_SPW; ++s)
    h_out[(size_t)(seq0 + s) * 64 + j] = h1r[s];
}

// ---------------------------------------------------------------------------
// Single-layer GRU for the ALSTM (I = 64). Unchanged (validated; small share
// of runtime). 8 waves/block, 1 seq/wave, grid 64.
// ---------------------------------------------------------------------------
constexpr int A_W_DW = 128 * 192;  // 24576
constexpr int A_WAVES = 8;
constexpr int A_LDS = (A_W_DW + A_WAVES * 128) * 4;  // 102400 B

__launch_bounds__(512, 2)
__global__ void gru1(const float* __restrict__ xin,  // [N][T][64]
                     const float* __restrict__ w3,   // [128][192]
                     const float* __restrict__ bih, const float* __restrict__ bhh,
                     int T,
                     float* __restrict__ rout) {     // [N][T][64]
  extern __shared__ float lds[];
  const int tid = threadIdx.x;
  const int wave = tid >> 6;
  const int j = tid & 63;
  const int j3 = j * 3;
  const int XB = A_W_DW + wave * 128;  // [0..63]=x_t, [64..127]=h

  {
    const float4* sp = (const float4*)w3;
    for (int i = tid; i < A_W_DW / 4; i += 512) ((float4*)lds)[i] = sp[i];
  }
  const float br = bih[j] + bhh[j];
  const float bz = bih[64 + j] + bhh[64 + j];
  const float bxn = bih[128 + j];
  const float bhn = bhh[128 + j];

  float hr = 0.0f;
  lds[XB + 64 + j] = 0.0f;
  __syncthreads();

  const int seq = blockIdx.x * A_WAVES + wave;
  const float* xs = xin + (size_t)seq * T * 64;

#define A_QUAD(WROW0, HOFF, AN)                                            \
  {                                                                        \
    float4 hv = *(const float4*)&lds[XB + (HOFF)];                         \
    _Pragma("unroll") for (int c = 0; c < 4; ++c) {                        \
      const float wr = lds[((WROW0) + c) * 192 + j3];                      \
      const float wz = lds[((WROW0) + c) * 192 + j3 + 1];                  \
      const float wn = lds[((WROW0) + c) * 192 + j3 + 2];                  \
      const float hc = (c == 0) ? hv.x : (c == 1) ? hv.y                   \
                      : (c == 2) ? hv.z : hv.w;                            \
      ar = fmaf(wr, hc, ar);                                               \
      az = fmaf(wz, hc, az);                                               \
      AN = fmaf(wn, hc, AN);                                               \
    }                                                                      \
  }

  float xcur = xs[j];  // t = 0
  for (int t = 0; t < T; ++t) {
    float xnext = (t + 1 < T) ? xs[(size_t)(t + 1) * 64 + j] : 0.0f;
    lds[XB + j] = xcur;  // wave-private; ordered by lgkmcnt

    float ar = 0.f, az = 0.f, anx = 0.f, anh = 0.f;
#pragma unroll
    for (int kq = 0; kq < 16; ++kq) A_QUAD(kq * 4, kq * 4, anx);        // input
#pragma unroll
    for (int kq = 0; kq < 16; ++kq) A_QUAD(64 + kq * 4, 64 + kq * 4, anh);  // rec

    float r = sigm(ar + br);
    float z = sigm(az + bz);
    float n = tanh_f(anx + bxn + r * (anh + bhn));
    float h = (1.0f - z) * n + z * hr;
    hr = h;
    lds[XB + 64 + j] = h;
    rout[((size_t)seq * T + t) * 64 + j] = h;
    xcur = xnext;
  }
#undef A_QUAD
}

// ---------------------------------------------------------------------------
// Weight interleave prep (R1 format): W3[k][j*3+g] =
//   (k<I ? Wih[g*64+j][k] : Whh[g*64+j][k-I])
// Sections: 0: e0 [70][192] (I=6); 1: e1 [128][192]; 2,3: ALSTM a0,a1.
// ---------------------------------------------------------------------------
__global__ void w3_prep(const float* __restrict__ Wih0, const float* __restrict__ Whh0,
                        const float* __restrict__ Wih1, const float* __restrict__ Whh1,
                        const float* __restrict__ aWih0, const float* __restrict__ aWhh0,
                        const float* __restrict__ aWih1, const float* __restrict__ aWhh1,
                        float* __restrict__ d_e0, float* __restrict__ d_e1,
                        float* __restrict__ d_a0, float* __restrict__ d_a1) {
  const int sec = blockIdx.x >> 3;
  const int bi = blockIdx.x & 7;
  const float* Wih; const float* Whh; float* dst; int I;
  if (sec == 0)      { Wih = Wih0;  Whh = Whh0;  dst = d_e0; I = 6; }
  else if (sec == 1) { Wih = Wih1;  Whh = Whh1;  dst = d_e1; I = 64; }
  else if (sec == 2) { Wih = aWih0; Whh = aWhh0; dst = d_a0; I = 64; }
  else               { Wih = aWih1; Whh = aWhh1; dst = d_a1; I = 64; }
  const int tot = (I + 64) * 192;
  for (int idx = bi * blockDim.x + threadIdx.x; idx < tot; idx += 8 * blockDim.x) {
    const int k = idx / 192;
    const int rem = idx - k * 192;
    const int jj = rem / 3;
    const int g = rem - jj * 3;
    dst[idx] = (k < I) ? Wih[(g * 64 + jj) * I + k] : Whh[(g * 64 + jj) * 64 + (k - I)];
  }
}

// ---------------------------------------------------------------------------
// GAT algebraic prep
// ---------------------------------------------------------------------------
__global__ void gat_prep(const float* __restrict__ tW, const float* __restrict__ tb,
                         const float* __restrict__ a, float* __restrict__ vbuf) {
  const int d = threadIdx.x;  // 64 threads
  float vd = 0.0f, vs = 0.0f;
  for (int e = 0; e < 64; ++e) {
    float w = tW[e * 64 + d];
    vd = fmaf(w, a[e], vd);
    vs = fmaf(w, a[64 + e], vs);
  }
  vbuf[d] = vd;
  vbuf[64 + d] = vs;
  if (d == 0) {
    float cd = 0.0f, cs = 0.0f;
    for (int e = 0; e < 64; ++e) {
      cd = fmaf(tb[e], a[e], cd);
      cs = fmaf(tb[e], a[64 + e], cs);
    }
    vbuf[128] = cd;
    vbuf[129] = cs;
  }
}

__global__ void gat_svals(const float* __restrict__ h_enc, const float* __restrict__ vbuf,
                          float* __restrict__ s_src, float* __restrict__ s_dst) {
  const int wave = (blockIdx.x * blockDim.x + threadIdx.x) >> 6;
  const int lane = threadIdx.x & 63;
  float h = h_enc[(size_t)wave * 64 + lane];
  float pd = h * vbuf[lane];
  float ps = h * vbuf[64 + lane];
  pd = wave_sum(pd);
  ps = wave_sum(ps);
  if (lane == 0) {
    s_dst[wave] = pd + vbuf[128];
    s_src[wave] = ps + vbuf[129];
  }
}

// ---------------------------------------------------------------------------
// Dense all-pairs attention per group k (m=512)
// ---------------------------------------------------------------------------
__launch_bounds__(256)
__global__ void gat_attn(const float* __restrict__ h_enc,
                         const float* __restrict__ s_src,
                         const float* __restrict__ s_dst,
                         float* __restrict__ hout) {
  const int k = blockIdx.x >> 7;
  const int tile = blockIdx.x & 127;
  const int wv = threadIdx.x >> 6;
  const int lane = threadIdx.x & 63;
  const int i = tile * 4 + wv;
  __shared__ float sdbuf[512];
  __shared__ __align__(16) float pbuf[4][512];

  for (int u = threadIdx.x; u < 512; u += 256) sdbuf[u] = s_dst[k * 512 + u];
  __syncthreads();

  const float si = s_src[k * 512 + i];
  float ev[8];
  float mx = -1e30f;
#pragma unroll
  for (int u = 0; u < 8; ++u) {
    ev[u] = lrelu(si + sdbuf[lane + u * 64]);
    mx = fmaxf(mx, ev[u]);
  }
  mx = wave_max(mx);
  float lsum = 0.0f;
#pragma unroll
  for (int u = 0; u < 8; ++u) {
    float p = __expf(ev[u] - mx);
    pbuf[wv][lane + u * 64] = p;
    lsum += p;
  }
  lsum = wave_sum(lsum);
  const float inv = fast_rcp(lsum);

  const float* hk = h_enc + (size_t)k * 512 * 64;
  const float4* pv = (const float4*)pbuf[wv];
  float acc0 = 0.0f, acc1 = 0.0f;
#pragma unroll 2
  for (int jj = 0; jj < 128; ++jj) {
    float4 p = pv[jj];
    const float* hp = hk + (size_t)(jj * 4) * 64 + lane;
    acc0 = fmaf(p.x, hp[0], acc0);
    acc1 = fmaf(p.y, hp[64], acc1);
    acc0 = fmaf(p.z, hp[128], acc0);
    acc1 = fmaf(p.w, hp[192], acc1);
  }
  hout[((size_t)k * 512 + i) * 64 + lane] =
      (acc0 + acc1) * inv + hk[(size_t)i * 64 + lane];
}

// ---------------------------------------------------------------------------
// Post-GAT transform + pred head + ALSTM input transform
// ---------------------------------------------------------------------------
__launch_bounds__(256)
__global__ void gat_out(const float* __restrict__ hin,
                        const float* __restrict__ fcW, const float* __restrict__ fcb,
                        const float* __restrict__ fcoW, const float* __restrict__ fcob,
                        const float* __restrict__ alinW, const float* __restrict__ alinb,
                        float* __restrict__ zout, float* __restrict__ pred) {
  const int wv = threadIdx.x >> 6;
  const int lane = threadIdx.x & 63;
  const int n = blockIdx.x * 4 + wv;  // [0,10240)
  const int k = n >> 9;
  const int i = n & 511;
  __shared__ __align__(16) float rbuf[4][64];
  __shared__ __align__(16) float rbuf2[4][64];

  float4 fw[16], aw[16];
  {
    const float4* p1 = (const float4*)(fcW + lane * 64);
    const float4* p2 = (const float4*)(alinW + lane * 64);
#pragma unroll
    for (int kk = 0; kk < 16; ++kk) fw[kk] = p1[kk];
#pragma unroll
    for (int kk = 0; kk < 16; ++kk) aw[kk] = p2[kk];
  }

  rbuf[wv][lane] = hin[(size_t)n * 64 + lane];
  float h2 = fcb[lane];
  const float4* rv = (const float4*)rbuf[wv];
#pragma unroll
  for (int kk = 0; kk < 16; ++kk) h2 = dot4(fw[kk], rv[kk], h2);

  if (k == 19) {
    float pv = lrelu(h2) * fcoW[lane];
    pv = wave_sum(pv);
    if (lane == 0) pred[i] = pv + fcob[0];
  }

  rbuf2[wv][lane] = h2;
  float zz = alinb[lane];
  const float4* rv2 = (const float4*)rbuf2[wv];
#pragma unroll
  for (int kk = 0; kk < 16; ++kk) zz = dot4(aw[kk], rv2[kk], zz);
  zout[((size_t)i * 20 + k) * 64 + lane] = tanh_f(zz);
}

// ---------------------------------------------------------------------------
// ALSTM attention head
// ---------------------------------------------------------------------------
__launch_bounds__(256)
__global__ void alstm_head(const float* __restrict__ r1,  // [512][20][64]
                           const float* __restrict__ W1,  // [32][64]
                           const float* __restrict__ b1,  // [32]
                           const float* __restrict__ W2,  // [32]
                           const float* __restrict__ Wo,  // [128]
                           const float* __restrict__ bo,  // [1]
                           float* __restrict__ alstm_out) {
  const int wv = threadIdx.x >> 6;
  const int lane = threadIdx.x & 63;
  const int i = blockIdx.x * 4 + wv;  // [0,512)
  const int e = lane & 31;
  __shared__ __align__(16) float rbuf[4][64];
  __shared__ float scb[4][20];

  float4 w1r[16];
  {
    const float4* p = (const float4*)(W1 + e * 64);
#pragma unroll
    for (int kk = 0; kk < 16; ++kk) w1r[kk] = p[kk];
  }
  const float b1e = b1[e];
  const float w2e = W2[e];

  for (int k = 0; k < 20; ++k) {
    rbuf[wv][lane] = r1[((size_t)i * 20 + k) * 64 + lane];
    float u = b1e;
    const float4* rp = (const float4*)rbuf[wv];
#pragma unroll
    for (int kk = 0; kk < 16; ++kk) u = dot4(w1r[kk], rp[kk], u);
    u = tanh_f(u) * w2e;
#pragma unroll
    for (int m = 16; m; m >>= 1) u += __shfl_xor(u, m);
    if (lane == 0) scb[wv][k] = u;
  }

  float mx = -1e30f;
#pragma unroll
  for (int k = 0; k < 20; ++k) mx = fmaxf(mx, scb[wv][k]);
  float p[20];
  float l = 0.0f;
#pragma unroll
  for (int k = 0; k < 20; ++k) {
    p[k] = __expf(scb[wv][k] - mx);
    l += p[k];
  }
  const float inv = fast_rcp(l);

  float oa = 0.0f, rlast = 0.0f;
#pragma unroll
  for (int k = 0; k < 20; ++k) {
    float rv = r1[((size_t)i * 20 + k) * 64 + lane];
    oa = fmaf(p[k], rv, oa);
    if (k == 19) rlast = rv;
  }
  oa *= inv;
  float v = fmaf(Wo[lane], rlast, Wo[64 + lane] * oa);
  v = wave_sum(v);
  if (lane == 0) alstm_out[i] = v + bo[0];
}

// ---------------------------------------------------------------------------
extern "C" void kernel_launch(void* const* d_in, const int* in_sizes, int n_in,
                              void* d_out, int out_size, void* d_ws, size_t ws_size,
                              hipStream_t stream) {
  const float* x      = (const float*)d_in[0];
  const float* Wih0   = (const float*)d_in[1];
  const float* Whh0   = (const float*)d_in[2];
  const float* bih0   = (const float*)d_in[3];
  const float* bhh0   = (const float*)d_in[4];
  const float* Wih1   = (const float*)d_in[5];
  const float* Whh1   = (const float*)d_in[6];
  const float* bih1   = (const float*)d_in[7];
  const float* bhh1   = (const float*)d_in[8];
  const float* transW = (const float*)d_in[9];
  const float* transb = (const float*)d_in[10];
  const float* a_vec  = (const float*)d_in[11];
  const float* fcW    = (const float*)d_in[12];
  const float* fcb    = (const float*)d_in[13];
  const float* fcoW   = (const float*)d_in[14];
  const float* fcob   = (const float*)d_in[15];
  const float* alinW  = (const float*)d_in[16];
  const float* alinb  = (const float*)d_in[17];
  const float* aWih0  = (const float*)d_in[18];
  const float* aWhh0  = (const float*)d_in[19];
  const float* abih0  = (const float*)d_in[20];
  const float* abhh0  = (const float*)d_in[21];
  const float* aWih1  = (const float*)d_in[22];
  const float* aWhh1  = (const float*)d_in[23];
  const float* abih1  = (const float*)d_in[24];
  const float* abhh1  = (const float*)d_in[25];
  const float* att1W  = (const float*)d_in[26];
  const float* att1b  = (const float*)d_in[27];
  const float* att2W  = (const float*)d_in[28];
  const float* aloutW = (const float*)d_in[29];
  const float* aloutb = (const float*)d_in[30];

  float* out = (float*)d_out;  // [0:512) alstm_out, [512:1024) pred

  float* W = (float*)d_ws;
  float* h_enc = W; W += 10240 * 64;      // reused as r0 (steps 7-8)
  float* vbuf  = W; W += 256;
  float* s_src = W; W += 10240;
  float* s_dst = W; W += 10240;
  float* hout  = W; W += 10240 * 64;
  float* zbuf  = W; W += 512 * 20 * 64;
  float* r1    = W; W += 512 * 20 * 64;
  float* w3a0  = W; W += 24576;
  float* w3a1  = W; W += 24576;
  // time-disjoint aliases: encoder weight buffers live in the zbuf region
  // (consumed at step 2; zbuf written at step 6).
  float* w3e0 = zbuf;                  // [70][192]  = 13440 dw
  float* w3e1 = zbuf + 13440;          // [128][192] = 24576 dw (end 38016)

  static bool attr_done = false;
  if (!attr_done) {
    hipFuncSetAttribute((const void*)gru2_enc,
                        hipFuncAttributeMaxDynamicSharedMemorySize, E_LDS);
    hipFuncSetAttribute((const void*)gru1,
                        hipFuncAttributeMaxDynamicSharedMemorySize, A_LDS);
    attr_done = true;
  }

  // 1) weight prep (R1 j3-interleave format for all 4 GRU layers)
  w3_prep<<<32, 256, 0, stream>>>(Wih0, Whh0, Wih1, Whh1, aWih0, aWhh0,
                                  aWih1, aWhh1, w3e0, w3e1, w3a0, w3a1);
  // 2) fused 2-layer persistent GRU encoder: 256 blocks x 8 waves x SPW=5
  //    = 10240 seqs in ONE balanced round; register h-state + readlane +
  //    seq-packed v_pk_fma_f32
  gru2_enc<<<256, 512, E_LDS, stream>>>(x, w3e0, w3e1, bih0, bhh0, bih1,
                                        bhh1, h_enc);
  // 3) GAT score-vector prep
  gat_prep<<<1, 64, 0, stream>>>(transW, transb, a_vec, vbuf);
  // 4) per-row s_src/s_dst
  gat_svals<<<2560, 256, 0, stream>>>(h_enc, vbuf, s_src, s_dst);
  // 5) dense attention + residual
  gat_attn<<<2560, 256, 0, stream>>>(h_enc, s_src, s_dst, hout);
  // 6) fc + pred head + ALSTM input transform (z in [i][k][64])
  gat_out<<<2560, 256, 0, stream>>>(hout, fcW, fcb, fcoW, fcob, alinW, alinb,
                                    zbuf, out + 512);
  // 7) ALSTM GRU layer 0: z -> r0 (reuses h_enc storage)
  gru1<<<64, 512, A_LDS, stream>>>(zbuf, w3a0, abih0, abhh0, 20, h_enc);
  // 8) ALSTM GRU layer 1: r0 -> r1
  gru1<<<64, 512, A_LDS, stream>>>(h_enc, w3a1, abih1, abhh1, 20, r1);
  // 9) ALSTM attention head -> alstm_out
  alstm_head<<<128, 256, 0, stream>>>(r1, att1W, att1b, att2W, aloutW, aloutb,
                                      out);
}

// Round 9
// 1366.609 us; speedup vs baseline: 19.9949x; 1.0132x over previous
//
#include <hip/hip_runtime.h>

#define DEV __device__ __forceinline__

typedef float f2 __attribute__((ext_vector_type(2)));

DEV float fast_rcp(float x) {
#if __has_builtin(__builtin_amdgcn_rcpf)
  return __builtin_amdgcn_rcpf(x);
#else
  return 1.0f / x;
#endif
}
DEV float sigm(float x) { return fast_rcp(1.0f + __expf(-x)); }
DEV float tanh_f(float x) {
  float e = __expf(-2.0f * fabsf(x));
  float t = 1.0f - 2.0f * e * fast_rcp(1.0f + e);
  return copysignf(t, x);
}
DEV float lrelu(float x) { return x > 0.0f ? x : 0.01f * x; }

DEV float wave_sum(float v) {
#pragma unroll
  for (int m = 32; m; m >>= 1) v += __shfl_xor(v, m);
  return v;
}
DEV float wave_max(float v) {
#pragma unroll
  for (int m = 32; m; m >>= 1) v = fmaxf(v, __shfl_xor(v, m));
  return v;
}
DEV float dot4(float4 w, float4 x, float acc) {
  acc = fmaf(w.x, x.x, acc);
  acc = fmaf(w.y, x.y, acc);
  acc = fmaf(w.z, x.z, acc);
  acc = fmaf(w.w, x.w, acc);
  return acc;
}

// SGPR broadcast of another lane's register value (used only in x-part, 30/step)
DEV float bcast(float v, int lane) {
  return __int_as_float(__builtin_amdgcn_readlane(__float_as_int(v), lane));
}

// ---------------------------------------------------------------------------
// Persistent-GRU encoder, R12. Counter history:
//  R10 (readlane h, scalar wts): 1135us, conflicts ~0, VALUBusy 84%.
//  R11 (+f2 pk attempt): 1086us, VGPR unchanged 52 -> pk scalarized; VALU
//    still 83%. Implied VALU issues (~9k/wave-step) are ~3x the hand count
//    -> inflation lives in readlane operand prep (VALU->SGPR->VALU hazard
//    wait-states + pair-packing movs), 990 readlanes/wave-step.
//  DS pipe meanwhile only ~45% loaded (weights only). Rebalance:
// R12: h back in LDS (R1-R9-validated wave-private pattern) in [unit][seq]
// layout so ONE wave-uniform ds_read_b64 at k*6+2p yields {h[2p][k],
// h[2p+1][k]} = the f2 operand as a natural VGPR pair. Inner loop has ZERO
// readlanes: per k-row = 3 weight b32 (proven conflict-free) + 2 h-b64 +
// 1 h-b32, all broadcast. Epilogue writes h as 2xb64+1xb32 (4-way write
// conflict on 10 writes/step - negligible).
// LDS 162,816B (R8-accepted size): Whh0 rows 52..63 move to registers.
// Hard rules kept: k-loops ROLLED (RULE 1); scalar stride-3 weights
// (RULE 2); no min-waves launch-bounds (RULE 3).
// Partition: 256 blocks x 8 waves x SPW=5 = 10240 seqs, ONE balanced round.
// ---------------------------------------------------------------------------
constexpr int E_SPW = 5;
constexpr int E_WAVES = 8;
constexpr int L_W0 = 0;          // Whh0 rows 0..51: 52*192 = 9984 dw
constexpr int L_W1 = 9984;       // w3e1: 128*192 = 24576 dw
constexpr int L_HB = 34560;      // + wave*768: h0buf[64][6] | h1buf[64][6]
constexpr int E_DW = 40704;
constexpr int E_LDS = E_DW * 4;  // 162,816 B <= 160 KiB

// One k-row: LDS weights (3x b32) + LDS h broadcasts (2x b64 + 1x b32),
// seq-packed FMA accumulate into fixed names ar01/ar23/ar4, az01/az23/az4
// and the passed n-gate targets.
#define DOT_ROW(WB, HBASE, K, AN01, AN23, AN4)                        \
  {                                                                   \
    const int wb_ = (WB);                                             \
    const float wr = lds[wb_], wz = lds[wb_ + 1], wn = lds[wb_ + 2];  \
    const f2 h01 = *(const f2*)&lds[(HBASE) + (K) * 6];               \
    const f2 h23 = *(const f2*)&lds[(HBASE) + (K) * 6 + 2];           \
    const float h4 = lds[(HBASE) + (K) * 6 + 4];                      \
    const f2 wr2 = {wr, wr}, wz2 = {wz, wz}, wn2 = {wn, wn};          \
    ar01 = __builtin_elementwise_fma(wr2, h01, ar01);                 \
    ar23 = __builtin_elementwise_fma(wr2, h23, ar23);                 \
    ar4 = fmaf(wr, h4, ar4);                                          \
    az01 = __builtin_elementwise_fma(wz2, h01, az01);                 \
    az23 = __builtin_elementwise_fma(wz2, h23, az23);                 \
    az4 = fmaf(wz, h4, az4);                                          \
    AN01 = __builtin_elementwise_fma(wn2, h01, AN01);                 \
    AN23 = __builtin_elementwise_fma(wn2, h23, AN23);                 \
    AN4 = fmaf(wn, h4, AN4);                                          \
  }

// Same but with register weights (Whh0 rows 52..63)
#define DOT_ROW_REG(WR, WZ, WN, HBASE, K, AN01, AN23, AN4)            \
  {                                                                   \
    const float wr = (WR), wz = (WZ), wn = (WN);                      \
    const f2 h01 = *(const f2*)&lds[(HBASE) + (K) * 6];               \
    const f2 h23 = *(const f2*)&lds[(HBASE) + (K) * 6 + 2];           \
    const float h4 = lds[(HBASE) + (K) * 6 + 4];                      \
    const f2 wr2 = {wr, wr}, wz2 = {wz, wz}, wn2 = {wn, wn};          \
    ar01 = __builtin_elementwise_fma(wr2, h01, ar01);                 \
    ar23 = __builtin_elementwise_fma(wr2, h23, ar23);                 \
    ar4 = fmaf(wr, h4, ar4);                                          \
    az01 = __builtin_elementwise_fma(wz2, h01, az01);                 \
    az23 = __builtin_elementwise_fma(wz2, h23, az23);                 \
    az4 = fmaf(wz, h4, az4);                                          \
    AN01 = __builtin_elementwise_fma(wn2, h01, AN01);                 \
    AN23 = __builtin_elementwise_fma(wn2, h23, AN23);                 \
    AN4 = fmaf(wn, h4, AN4);                                          \
  }

// layer-0 x-part for one seq (scalar; only 6 components, readlane OK here)
#define XPART(S, ARx, AZx, ANXx)                       \
  _Pragma("unroll") for (int c = 0; c < 6; ++c) {      \
    const float xk = bcast(xcur, (S) * 6 + c);         \
    ARx = fmaf(wx0[c][0], xk, ARx);                    \
    AZx = fmaf(wx0[c][1], xk, AZx);                    \
    ANXx = fmaf(wx0[c][2], xk, ANXx);                  \
  }

// GRU epilogue for one seq (register state update)
#define EPI(S, ARx, AZx, ANXx, ANHx, HARR, BR, BZ, BXN, BHN)   \
  {                                                            \
    float r_ = sigm((ARx) + (BR));                             \
    float z_ = sigm((AZx) + (BZ));                             \
    float n_ = tanh_f((ANXx) + (BXN) + r_ * ((ANHx) + (BHN))); \
    HARR[S] = (1.0f - z_) * n_ + z_ * HARR[S];                 \
  }

__launch_bounds__(512)
__global__ void gru2_enc(const float* __restrict__ x,      // [10240][60][6]
                         const float* __restrict__ w3e0,   // [70][192] j3-interleave
                         const float* __restrict__ w3e1,   // [128][192]
                         const float* __restrict__ bih0, const float* __restrict__ bhh0,
                         const float* __restrict__ bih1, const float* __restrict__ bhh1,
                         float* __restrict__ h_out) {      // [10240][64]
  extern __shared__ float lds[];
  const int tid = threadIdx.x;
  const int wave = tid >> 6;
  const int j = tid & 63;
  const int j3 = j * 3;
  const int h0base = L_HB + wave * 768;        // [64][6] this wave's h0
  const int h1base = h0base + 384;             // [64][6] this wave's h1

  // cooperative weight load into LDS (coalesced float4)
  {
    const float4* s0 = (const float4*)(w3e0 + 6 * 192);  // Whh0 rows 0..51
    for (int i = tid; i < 9984 / 4; i += 512) ((float4*)(lds + L_W0))[i] = s0[i];
    const float4* s1 = (const float4*)w3e1;
    for (int i = tid; i < 24576 / 4; i += 512) ((float4*)(lds + L_W1))[i] = s1[i];
  }
  // register weights: Wih0 (6 rows) + Whh0 rows 52..63 (w3e0 rows 58..69)
  float wx0[6][3], wh_hi[12][3];
#pragma unroll
  for (int k = 0; k < 6; ++k)
#pragma unroll
    for (int g = 0; g < 3; ++g) wx0[k][g] = w3e0[k * 192 + j3 + g];
#pragma unroll
  for (int r = 0; r < 12; ++r)
#pragma unroll
    for (int g = 0; g < 3; ++g) wh_hi[r][g] = w3e0[(58 + r) * 192 + j3 + g];

  const float br0 = bih0[j] + bhh0[j];
  const float bz0 = bih0[64 + j] + bhh0[64 + j];
  const float bxn0 = bih0[128 + j];
  const float bhn0 = bhh0[128 + j];
  const float br1 = bih1[j] + bhh1[j];
  const float bz1 = bih1[64 + j] + bhh1[64 + j];
  const float bxn1 = bih1[128 + j];
  const float bhn1 = bhh1[128 + j];

  float h0r[E_SPW], h1r[E_SPW];
#pragma unroll
  for (int s = 0; s < E_SPW; ++s) {
    h0r[s] = 0.0f; h1r[s] = 0.0f;
    lds[h0base + j * 6 + s] = 0.0f;   // lane j owns unit j's slots
    lds[h1base + j * 6 + s] = 0.0f;
  }
  __syncthreads();  // weights + zeroed state visible; the only barrier

  const int seq0 = blockIdx.x * (E_WAVES * E_SPW) + wave * E_SPW;
  // x carrier: lane j<30 holds component ci of seq si (readlane in XPART)
  const int si = j / 6;
  const int ci = j - si * 6;
  const bool xlane = (j < 6 * E_SPW);
  const float* xg = x + (size_t)(seq0 + si) * 360 + ci;

  float xcur = xlane ? xg[0] : 0.0f;  // t = 0

  for (int t = 0; t < 60; ++t) {
    float xnext = (xlane && t + 1 < 60) ? xg[(size_t)(t + 1) * 6] : 0.0f;

    // ======== layer 0 ========
    f2 ar01 = {0.f, 0.f}, ar23 = {0.f, 0.f};
    f2 az01 = {0.f, 0.f}, az23 = {0.f, 0.f};
    f2 anx01 = {0.f, 0.f}, anx23 = {0.f, 0.f};
    f2 anh01 = {0.f, 0.f}, anh23 = {0.f, 0.f};
    float ar4 = 0.f, az4 = 0.f, anx4 = 0.f, anh4 = 0.f;

    // h-part: rows 0..51 LDS weights, 52..63 register weights (ROLLED k-loop)
#pragma clang loop unroll_count(4)
    for (int k = 0; k < 52; ++k)
      DOT_ROW(L_W0 + k * 192 + j3, h0base, k, anh01, anh23, anh4)
#pragma unroll
    for (int r = 0; r < 12; ++r)
      DOT_ROW_REG(wh_hi[r][0], wh_hi[r][1], wh_hi[r][2], h0base, 52 + r,
                  anh01, anh23, anh4)

    XPART(0, ar01.x, az01.x, anx01.x)
    XPART(1, ar01.y, az01.y, anx01.y)
    XPART(2, ar23.x, az23.x, anx23.x)
    XPART(3, ar23.y, az23.y, anx23.y)
    XPART(4, ar4, az4, anx4)

    EPI(0, ar01.x, az01.x, anx01.x, anh01.x, h0r, br0, bz0, bxn0, bhn0)
    EPI(1, ar01.y, az01.y, anx01.y, anh01.y, h0r, br0, bz0, bxn0, bhn0)
    EPI(2, ar23.x, az23.x, anx23.x, anh23.x, h0r, br0, bz0, bxn0, bhn0)
    EPI(3, ar23.y, az23.y, anx23.y, anh23.y, h0r, br0, bz0, bxn0, bhn0)
    EPI(4, ar4, az4, anx4, anh4, h0r, br0, bz0, bxn0, bhn0)

    // publish fresh h0 (wave-private; same-wave ds ordering by program order)
    {
      f2 w01 = {h0r[0], h0r[1]};
      f2 w23 = {h0r[2], h0r[3]};
      *(f2*)&lds[h0base + j * 6] = w01;
      *(f2*)&lds[h0base + j * 6 + 2] = w23;
      lds[h0base + j * 6 + 4] = h0r[4];
    }

    // ======== layer 1 ========
    ar01 = (f2){0.f, 0.f}; ar23 = (f2){0.f, 0.f};
    az01 = (f2){0.f, 0.f}; az23 = (f2){0.f, 0.f};
    anx01 = (f2){0.f, 0.f}; anx23 = (f2){0.f, 0.f};
    anh01 = (f2){0.f, 0.f}; anh23 = (f2){0.f, 0.f};
    ar4 = 0.f; az4 = 0.f; anx4 = 0.f; anh4 = 0.f;

    // x-part over fresh h0 (W1 rows 0..63)
#pragma clang loop unroll_count(4)
    for (int k = 0; k < 64; ++k)
      DOT_ROW(L_W1 + k * 192 + j3, h0base, k, anx01, anx23, anx4)
    // h-part over h1_old (W1 rows 64..127; h1buf still holds old values)
#pragma clang loop unroll_count(4)
    for (int k = 0; k < 64; ++k)
      DOT_ROW(L_W1 + (64 + k) * 192 + j3, h1base, k, anh01, anh23, anh4)

    EPI(0, ar01.x, az01.x, anx01.x, anh01.x, h1r, br1, bz1, bxn1, bhn1)
    EPI(1, ar01.y, az01.y, anx01.y, anh01.y, h1r, br1, bz1, bxn1, bhn1)
    EPI(2, ar23.x, az23.x, anx23.x, anh23.x, h1r, br1, bz1, bxn1, bhn1)
    EPI(3, ar23.y, az23.y, anx23.y, anh23.y, h1r, br1, bz1, bxn1, bhn1)
    EPI(4, ar4, az4, anx4, anh4, h1r, br1, bz1, bxn1, bhn1)

    // publish fresh h1
    {
      f2 w01 = {h1r[0], h1r[1]};
      f2 w23 = {h1r[2], h1r[3]};
      *(f2*)&lds[h1base + j * 6] = w01;
      *(f2*)&lds[h1base + j * 6 + 2] = w23;
      lds[h1base + j * 6 + 4] = h1r[4];
    }

    xcur = xnext;
  }

#pragma unroll
  for (int s = 0; s < E_SPW; ++s)
    h_out[(size_t)(seq0 + s) * 64 + j] = h1r[s];
}

// ---------------------------------------------------------------------------
// Single-layer GRU for the ALSTM (I = 64). Unchanged (validated; small share
// of runtime). 8 waves/block, 1 seq/wave, grid 64.
// ---------------------------------------------------------------------------
constexpr int A_W_DW = 128 * 192;  // 24576
constexpr int A_WAVES = 8;
constexpr int A_LDS = (A_W_DW + A_WAVES * 128) * 4;  // 102400 B

__launch_bounds__(512, 2)
__global__ void gru1(const float* __restrict__ xin,  // [N][T][64]
                     const float* __restrict__ w3,   // [128][192]
                     const float* __restrict__ bih, const float* __restrict__ bhh,
                     int T,
                     float* __restrict__ rout) {     // [N][T][64]
  extern __shared__ float lds[];
  const int tid = threadIdx.x;
  const int wave = tid >> 6;
  const int j = tid & 63;
  const int j3 = j * 3;
  const int XB = A_W_DW + wave * 128;  // [0..63]=x_t, [64..127]=h

  {
    const float4* sp = (const float4*)w3;
    for (int i = tid; i < A_W_DW / 4; i += 512) ((float4*)lds)[i] = sp[i];
  }
  const float br = bih[j] + bhh[j];
  const float bz = bih[64 + j] + bhh[64 + j];
  const float bxn = bih[128 + j];
  const float bhn = bhh[128 + j];

  float hr = 0.0f;
  lds[XB + 64 + j] = 0.0f;
  __syncthreads();

  const int seq = blockIdx.x * A_WAVES + wave;
  const float* xs = xin + (size_t)seq * T * 64;

#define A_QUAD(WROW0, HOFF, AN)                                            \
  {                                                                        \
    float4 hv = *(const float4*)&lds[XB + (HOFF)];                         \
    _Pragma("unroll") for (int c = 0; c < 4; ++c) {                        \
      const float wr = lds[((WROW0) + c) * 192 + j3];                      \
      const float wz = lds[((WROW0) + c) * 192 + j3 + 1];                  \
      const float wn = lds[((WROW0) + c) * 192 + j3 + 2];                  \
      const float hc = (c == 0) ? hv.x : (c == 1) ? hv.y                   \
                      : (c == 2) ? hv.z : hv.w;                            \
      ar = fmaf(wr, hc, ar);                                               \
      az = fmaf(wz, hc, az);                                               \
      AN = fmaf(wn, hc, AN);                                               \
    }                                                                      \
  }

  float xcur = xs[j];  // t = 0
  for (int t = 0; t < T; ++t) {
    float xnext = (t + 1 < T) ? xs[(size_t)(t + 1) * 64 + j] : 0.0f;
    lds[XB + j] = xcur;  // wave-private; ordered by lgkmcnt

    float ar = 0.f, az = 0.f, anx = 0.f, anh = 0.f;
#pragma unroll
    for (int kq = 0; kq < 16; ++kq) A_QUAD(kq * 4, kq * 4, anx);        // input
#pragma unroll
    for (int kq = 0; kq < 16; ++kq) A_QUAD(64 + kq * 4, 64 + kq * 4, anh);  // rec

    float r = sigm(ar + br);
    float z = sigm(az + bz);
    float n = tanh_f(anx + bxn + r * (anh + bhn));
    float h = (1.0f - z) * n + z * hr;
    hr = h;
    lds[XB + 64 + j] = h;
    rout[((size_t)seq * T + t) * 64 + j] = h;
    xcur = xnext;
  }
#undef A_QUAD
}

// ---------------------------------------------------------------------------
// Weight interleave prep (R1 format): W3[k][j*3+g] =
//   (k<I ? Wih[g*64+j][k] : Whh[g*64+j][k-I])
// Sections: 0: e0 [70][192] (I=6); 1: e1 [128][192]; 2,3: ALSTM a0,a1.
// ---------------------------------------------------------------------------
__global__ void w3_prep(const float* __restrict__ Wih0, const float* __restrict__ Whh0,
                        const float* __restrict__ Wih1, const float* __restrict__ Whh1,
                        const float* __restrict__ aWih0, const float* __restrict__ aWhh0,
                        const float* __restrict__ aWih1, const float* __restrict__ aWhh1,
                        float* __restrict__ d_e0, float* __restrict__ d_e1,
                        float* __restrict__ d_a0, float* __restrict__ d_a1) {
  const int sec = blockIdx.x >> 3;
  const int bi = blockIdx.x & 7;
  const float* Wih; const float* Whh; float* dst; int I;
  if (sec == 0)      { Wih = Wih0;  Whh = Whh0;  dst = d_e0; I = 6; }
  else if (sec == 1) { Wih = Wih1;  Whh = Whh1;  dst = d_e1; I = 64; }
  else if (sec == 2) { Wih = aWih0; Whh = aWhh0; dst = d_a0; I = 64; }
  else               { Wih = aWih1; Whh = aWhh1; dst = d_a1; I = 64; }
  const int tot = (I + 64) * 192;
  for (int idx = bi * blockDim.x + threadIdx.x; idx < tot; idx += 8 * blockDim.x) {
    const int k = idx / 192;
    const int rem = idx - k * 192;
    const int jj = rem / 3;
    const int g = rem - jj * 3;
    dst[idx] = (k < I) ? Wih[(g * 64 + jj) * I + k] : Whh[(g * 64 + jj) * 64 + (k - I)];
  }
}

// ---------------------------------------------------------------------------
// GAT algebraic prep
// ---------------------------------------------------------------------------
__global__ void gat_prep(const float* __restrict__ tW, const float* __restrict__ tb,
                         const float* __restrict__ a, float* __restrict__ vbuf) {
  const int d = threadIdx.x;  // 64 threads
  float vd = 0.0f, vs = 0.0f;
  for (int e = 0; e < 64; ++e) {
    float w = tW[e * 64 + d];
    vd = fmaf(w, a[e], vd);
    vs = fmaf(w, a[64 + e], vs);
  }
  vbuf[d] = vd;
  vbuf[64 + d] = vs;
  if (d == 0) {
    float cd = 0.0f, cs = 0.0f;
    for (int e = 0; e < 64; ++e) {
      cd = fmaf(tb[e], a[e], cd);
      cs = fmaf(tb[e], a[64 + e], cs);
    }
    vbuf[128] = cd;
    vbuf[129] = cs;
  }
}

__global__ void gat_svals(const float* __restrict__ h_enc, const float* __restrict__ vbuf,
                          float* __restrict__ s_src, float* __restrict__ s_dst) {
  const int wave = (blockIdx.x * blockDim.x + threadIdx.x) >> 6;
  const int lane = threadIdx.x & 63;
  float h = h_enc[(size_t)wave * 64 + lane];
  float pd = h * vbuf[lane];
  float ps = h * vbuf[64 + lane];
  pd = wave_sum(pd);
  ps = wave_sum(ps);
  if (lane == 0) {
    s_dst[wave] = pd + vbuf[128];
    s_src[wave] = ps + vbuf[129];
  }
}

// ---------------------------------------------------------------------------
// Dense all-pairs attention per group k (m=512)
// ---------------------------------------------------------------------------
__launch_bounds__(256)
__global__ void gat_attn(const float* __restrict__ h_enc,
                         const float* __restrict__ s_src,
                         const float* __restrict__ s_dst,
                         float* __restrict__ hout) {
  const int k = blockIdx.x >> 7;
  const int tile = blockIdx.x & 127;
  const int wv = threadIdx.x >> 6;
  const int lane = threadIdx.x & 63;
  const int i = tile * 4 + wv;
  __shared__ float sdbuf[512];
  __shared__ __align__(16) float pbuf[4][512];

  for (int u = threadIdx.x; u < 512; u += 256) sdbuf[u] = s_dst[k * 512 + u];
  __syncthreads();

  const float si = s_src[k * 512 + i];
  float ev[8];
  float mx = -1e30f;
#pragma unroll
  for (int u = 0; u < 8; ++u) {
    ev[u] = lrelu(si + sdbuf[lane + u * 64]);
    mx = fmaxf(mx, ev[u]);
  }
  mx = wave_max(mx);
  float lsum = 0.0f;
#pragma unroll
  for (int u = 0; u < 8; ++u) {
    float p = __expf(ev[u] - mx);
    pbuf[wv][lane + u * 64] = p;
    lsum += p;
  }
  lsum = wave_sum(lsum);
  const float inv = fast_rcp(lsum);

  const float* hk = h_enc + (size_t)k * 512 * 64;
  const float4* pv = (const float4*)pbuf[wv];
  float acc0 = 0.0f, acc1 = 0.0f;
#pragma unroll 2
  for (int jj = 0; jj < 128; ++jj) {
    float4 p = pv[jj];
    const float* hp = hk + (size_t)(jj * 4) * 64 + lane;
    acc0 = fmaf(p.x, hp[0], acc0);
    acc1 = fmaf(p.y, hp[64], acc1);
    acc0 = fmaf(p.z, hp[128], acc0);
    acc1 = fmaf(p.w, hp[192], acc1);
  }
  hout[((size_t)k * 512 + i) * 64 + lane] =
      (acc0 + acc1) * inv + hk[(size_t)i * 64 + lane];
}

// ---------------------------------------------------------------------------
// Post-GAT transform + pred head + ALSTM input transform
// ---------------------------------------------------------------------------
__launch_bounds__(256)
__global__ void gat_out(const float* __restrict__ hin,
                        const float* __restrict__ fcW, const float* __restrict__ fcb,
                        const float* __restrict__ fcoW, const float* __restrict__ fcob,
                        const float* __restrict__ alinW, const float* __restrict__ alinb,
                        float* __restrict__ zout, float* __restrict__ pred) {
  const int wv = threadIdx.x >> 6;
  const int lane = threadIdx.x & 63;
  const int n = blockIdx.x * 4 + wv;  // [0,10240)
  const int k = n >> 9;
  const int i = n & 511;
  __shared__ __align__(16) float rbuf[4][64];
  __shared__ __align__(16) float rbuf2[4][64];

  float4 fw[16], aw[16];
  {
    const float4* p1 = (const float4*)(fcW + lane * 64);
    const float4* p2 = (const float4*)(alinW + lane * 64);
#pragma unroll
    for (int kk = 0; kk < 16; ++kk) fw[kk] = p1[kk];
#pragma unroll
    for (int kk = 0; kk < 16; ++kk) aw[kk] = p2[kk];
  }

  rbuf[wv][lane] = hin[(size_t)n * 64 + lane];
  float h2 = fcb[lane];
  const float4* rv = (const float4*)rbuf[wv];
#pragma unroll
  for (int kk = 0; kk < 16; ++kk) h2 = dot4(fw[kk], rv[kk], h2);

  if (k == 19) {
    float pv = lrelu(h2) * fcoW[lane];
    pv = wave_sum(pv);
    if (lane == 0) pred[i] = pv + fcob[0];
  }

  rbuf2[wv][lane] = h2;
  float zz = alinb[lane];
  const float4* rv2 = (const float4*)rbuf2[wv];
#pragma unroll
  for (int kk = 0; kk < 16; ++kk) zz = dot4(aw[kk], rv2[kk], zz);
  zout[((size_t)i * 20 + k) * 64 + lane] = tanh_f(zz);
}

// ---------------------------------------------------------------------------
// ALSTM attention head
// ---------------------------------------------------------------------------
__launch_bounds__(256)
__global__ void alstm_head(const float* __restrict__ r1,  // [512][20][64]
                           const float* __restrict__ W1,  // [32][64]
                           const float* __restrict__ b1,  // [32]
                           const float* __restrict__ W2,  // [32]
                           const float* __restrict__ Wo,  // [128]
                           const float* __restrict__ bo,  // [1]
                           float* __restrict__ alstm_out) {
  const int wv = threadIdx.x >> 6;
  const int lane = threadIdx.x & 63;
  const int i = blockIdx.x * 4 + wv;  // [0,512)
  const int e = lane & 31;
  __shared__ __align__(16) float rbuf[4][64];
  __shared__ float scb[4][20];

  float4 w1r[16];
  {
    const float4* p = (const float4*)(W1 + e * 64);
#pragma unroll
    for (int kk = 0; kk < 16; ++kk) w1r[kk] = p[kk];
  }
  const float b1e = b1[e];
  const float w2e = W2[e];

  for (int k = 0; k < 20; ++k) {
    rbuf[wv][lane] = r1[((size_t)i * 20 + k) * 64 + lane];
    float u = b1e;
    const float4* rp = (const float4*)rbuf[wv];
#pragma unroll
    for (int kk = 0; kk < 16; ++kk) u = dot4(w1r[kk], rp[kk], u);
    u = tanh_f(u) * w2e;
#pragma unroll
    for (int m = 16; m; m >>= 1) u += __shfl_xor(u, m);
    if (lane == 0) scb[wv][k] = u;
  }

  float mx = -1e30f;
#pragma unroll
  for (int k = 0; k < 20; ++k) mx = fmaxf(mx, scb[wv][k]);
  float p[20];
  float l = 0.0f;
#pragma unroll
  for (int k = 0; k < 20; ++k) {
    p[k] = __expf(scb[wv][k] - mx);
    l += p[k];
  }
  const float inv = fast_rcp(l);

  float oa = 0.0f, rlast = 0.0f;
#pragma unroll
  for (int k = 0; k < 20; ++k) {
    float rv = r1[((size_t)i * 20 + k) * 64 + lane];
    oa = fmaf(p[k], rv, oa);
    if (k == 19) rlast = rv;
  }
  oa *= inv;
  float v = fmaf(Wo[lane], rlast, Wo[64 + lane] * oa);
  v = wave_sum(v);
  if (lane == 0) alstm_out[i] = v + bo[0];
}

// ---------------------------------------------------------------------------
extern "C" void kernel_launch(void* const* d_in, const int* in_sizes, int n_in,
                              void* d_out, int out_size, void* d_ws, size_t ws_size,
                              hipStream_t stream) {
  const float* x      = (const float*)d_in[0];
  const float* Wih0   = (const float*)d_in[1];
  const float* Whh0   = (const float*)d_in[2];
  const float* bih0   = (const float*)d_in[3];
  const float* bhh0   = (const float*)d_in[4];
  const float* Wih1   = (const float*)d_in[5];
  const float* Whh1   = (const float*)d_in[6];
  const float* bih1   = (const float*)d_in[7];
  const float* bhh1   = (const float*)d_in[8];
  const float* transW = (const float*)d_in[9];
  const float* transb = (const float*)d_in[10];
  const float* a_vec  = (const float*)d_in[11];
  const float* fcW    = (const float*)d_in[12];
  const float* fcb    = (const float*)d_in[13];
  const float* fcoW   = (const float*)d_in[14];
  const float* fcob   = (const float*)d_in[15];
  const float* alinW  = (const float*)d_in[16];
  const float* alinb  = (const float*)d_in[17];
  const float* aWih0  = (const float*)d_in[18];
  const float* aWhh0  = (const float*)d_in[19];
  const float* abih0  = (const float*)d_in[20];
  const float* abhh0  = (const float*)d_in[21];
  const float* aWih1  = (const float*)d_in[22];
  const float* aWhh1  = (const float*)d_in[23];
  const float* abih1  = (const float*)d_in[24];
  const float* abhh1  = (const float*)d_in[25];
  const float* att1W  = (const float*)d_in[26];
  const float* att1b  = (const float*)d_in[27];
  const float* att2W  = (const float*)d_in[28];
  const float* aloutW = (const float*)d_in[29];
  const float* aloutb = (const float*)d_in[30];

  float* out = (float*)d_out;  // [0:512) alstm_out, [512:1024) pred

  float* W = (float*)d_ws;
  float* h_enc = W; W += 10240 * 64;      // reused as r0 (steps 7-8)
  float* vbuf  = W; W += 256;
  float* s_src = W; W += 10240;
  float* s_dst = W; W += 10240;
  float* hout  = W; W += 10240 * 64;
  float* zbuf  = W; W += 512 * 20 * 64;
  float* r1    = W; W += 512 * 20 * 64;
  float* w3a0  = W; W += 24576;
  float* w3a1  = W; W += 24576;
  // time-disjoint aliases: encoder weight buffers live in the zbuf region
  // (consumed at step 2; zbuf written at step 6).
  float* w3e0 = zbuf;                  // [70][192]  = 13440 dw
  float* w3e1 = zbuf + 13440;          // [128][192] = 24576 dw (end 38016)

  static bool attr_done = false;
  if (!attr_done) {
    hipFuncSetAttribute((const void*)gru2_enc,
                        hipFuncAttributeMaxDynamicSharedMemorySize, E_LDS);
    hipFuncSetAttribute((const void*)gru1,
                        hipFuncAttributeMaxDynamicSharedMemorySize, A_LDS);
    attr_done = true;
  }

  // 1) weight prep (R1 j3-interleave format for all 4 GRU layers)
  w3_prep<<<32, 256, 0, stream>>>(Wih0, Whh0, Wih1, Whh1, aWih0, aWhh0,
                                  aWih1, aWhh1, w3e0, w3e1, w3a0, w3a1);
  // 2) fused 2-layer persistent GRU encoder: 256 blocks x 8 waves x SPW=5
  //    = 10240 seqs in ONE balanced round; h in LDS [unit][seq] for b64
  //    pair-broadcasts, zero inner-loop readlanes
  gru2_enc<<<256, 512, E_LDS, stream>>>(x, w3e0, w3e1, bih0, bhh0, bih1,
                                        bhh1, h_enc);
  // 3) GAT score-vector prep
  gat_prep<<<1, 64, 0, stream>>>(transW, transb, a_vec, vbuf);
  // 4) per-row s_src/s_dst
  gat_svals<<<2560, 256, 0, stream>>>(h_enc, vbuf, s_src, s_dst);
  // 5) dense attention + residual
  gat_attn<<<2560, 256, 0, stream>>>(h_enc, s_src, s_dst, hout);
  // 6) fc + pred head + ALSTM input transform (z in [i][k][64])
  gat_out<<<2560, 256, 0, stream>>>(hout, fcW, fcb, fcoW, fcob, alinW, alinb,
                                    zbuf, out + 512);
  // 7) ALSTM GRU layer 0: z -> r0 (reuses h_enc storage)
  gru1<<<64, 512, A_LDS, stream>>>(zbuf, w3a0, abih0, abhh0, 20, h_enc);
  // 8) ALSTM GRU layer 1: r0 -> r1
  gru1<<<64, 512, A_LDS, stream>>>(h_enc, w3a1, abih1, abhh1, 20, r1);
  // 9) ALSTM attention head -> alstm_out
  alstm_head<<<128, 256, 0, stream>>>(r1, att1W, att1b, att2W, aloutW, aloutb,
                                      out);
}

// Round 11
// 1365.893 us; speedup vs baseline: 20.0053x; 1.0005x over previous
//
#include <hip/hip_runtime.h>

#define DEV __device__ __forceinline__

typedef float f2 __attribute__((ext_vector_type(2)));

DEV float fast_rcp(float x) {
#if __has_builtin(__builtin_amdgcn_rcpf)
  return __builtin_amdgcn_rcpf(x);
#else
  return 1.0f / x;
#endif
}
DEV float sigm(float x) { return fast_rcp(1.0f + __expf(-x)); }
DEV float tanh_f(float x) {
  float e = __expf(-2.0f * fabsf(x));
  float t = 1.0f - 2.0f * e * fast_rcp(1.0f + e);
  return copysignf(t, x);
}
DEV float lrelu(float x) { return x > 0.0f ? x : 0.01f * x; }

DEV float wave_sum(float v) {
#pragma unroll
  for (int m = 32; m; m >>= 1) v += __shfl_xor(v, m);
  return v;
}
DEV float wave_max(float v) {
#pragma unroll
  for (int m = 32; m; m >>= 1) v = fmaxf(v, __shfl_xor(v, m));
  return v;
}
DEV float dot4(float4 w, float4 x, float acc) {
  acc = fmaf(w.x, x.x, acc);
  acc = fmaf(w.y, x.y, acc);
  acc = fmaf(w.z, x.z, acc);
  acc = fmaf(w.w, x.w, acc);
  return acc;
}

// SGPR broadcast (x-part only, 30/step)
DEV float bcast(float v, int lane) {
  return __int_as_float(__builtin_amdgcn_readlane(__float_as_int(v), lane));
}

// ---------------------------------------------------------------------------
// Persistent-GRU encoder, R13 (resubmit — R10's bench died at container
// acquisition, no kernel signal; source re-audited, no defect found).
// Cost model fitted across R8-R12:
//  DS pipe is OP-ISSUE-limited (~4-5 cyc/op floor; b32=4, b64=6, b128=10),
//  R12 = 8640 DS ops/CU-step = 44k cyc = measured -> DS-bound. VALU 27k.
// R13 halves DS op count:
//  * weight rows repacked [k][(wr,wz)x128 | wn x64]: wA = ONE b64 at 2j
//    (8B aligned, 2-way bank = free), wn = b32 -> 2 ops/row (was 3).
//  * k-rows processed in PAIRS: h rows 2m,2m+1 = 12 contiguous dwords in
//    the [64][6] state layout (16B aligned at 12m) -> 3x b128 for both
//    rows' h (1.5 ops/row, was 3).
//  -> 3.5 DS ops/row vs 6; ~5.2k ops/CU-step ~ 28k cyc, co-bound w/ VALU.
// Validated envelope kept: scalar FMA accs (pk scalarizes, R11), pair
// loops ROLLED unroll_count(2) (RULE 1), no min-waves cap (RULE 3),
// 8 waves x SPW=5 x 256 blocks = ONE balanced round, LDS 162,816 B.
// Whh0 rows 52..63 + Wih0 in registers (from old-format w3e0).
// ---------------------------------------------------------------------------
constexpr int E_SPW = 5;
constexpr int E_WAVES = 8;
constexpr int L_W0 = 0;          // Whh0 rows 0..51, packed [192]: 9984 dw
constexpr int L_W1 = 9984;       // W1 rows 0..127, packed [192]: 24576 dw
constexpr int L_HB = 34560;      // + wave*768: h0[64][6] | h1[64][6]
constexpr int E_DW = 40704;
constexpr int E_LDS = E_DW * 4;  // 162,816 B <= 160 KiB

// 30 FMAs for a row pair (rows 2M, 2M+1): weights scalar, h from 3 b128.
// h[2M][s] = hq0.xyzw (s0..3), hq1.x (s4); h[2M+1][s] = hq1.zw (s0,1),
// hq2.xyz (s2..4).  (slot 5 of each row is pad, zero-initialized.)
#define PAIR_FMA(WRa, WZa, WNa, WRb, WZb, WNb, HB, M, AN)                    \
  {                                                                          \
    const float4 hq0 = *(const float4*)&lds[(HB) + (M) * 12];                \
    const float4 hq1 = *(const float4*)&lds[(HB) + (M) * 12 + 4];            \
    const float4 hq2 = *(const float4*)&lds[(HB) + (M) * 12 + 8];            \
    ar[0] = fmaf(WRa, hq0.x, ar[0]); az[0] = fmaf(WZa, hq0.x, az[0]);        \
    AN[0] = fmaf(WNa, hq0.x, AN[0]);                                         \
    ar[1] = fmaf(WRa, hq0.y, ar[1]); az[1] = fmaf(WZa, hq0.y, az[1]);        \
    AN[1] = fmaf(WNa, hq0.y, AN[1]);                                         \
    ar[2] = fmaf(WRa, hq0.z, ar[2]); az[2] = fmaf(WZa, hq0.z, az[2]);        \
    AN[2] = fmaf(WNa, hq0.z, AN[2]);                                         \
    ar[3] = fmaf(WRa, hq0.w, ar[3]); az[3] = fmaf(WZa, hq0.w, az[3]);        \
    AN[3] = fmaf(WNa, hq0.w, AN[3]);                                         \
    ar[4] = fmaf(WRa, hq1.x, ar[4]); az[4] = fmaf(WZa, hq1.x, az[4]);        \
    AN[4] = fmaf(WNa, hq1.x, AN[4]);                                         \
    ar[0] = fmaf(WRb, hq1.z, ar[0]); az[0] = fmaf(WZb, hq1.z, az[0]);        \
    AN[0] = fmaf(WNb, hq1.z, AN[0]);                                         \
    ar[1] = fmaf(WRb, hq1.w, ar[1]); az[1] = fmaf(WZb, hq1.w, az[1]);        \
    AN[1] = fmaf(WNb, hq1.w, AN[1]);                                         \
    ar[2] = fmaf(WRb, hq2.x, ar[2]); az[2] = fmaf(WZb, hq2.x, az[2]);        \
    AN[2] = fmaf(WNb, hq2.x, AN[2]);                                         \
    ar[3] = fmaf(WRb, hq2.y, ar[3]); az[3] = fmaf(WZb, hq2.y, az[3]);        \
    AN[3] = fmaf(WNb, hq2.y, AN[3]);                                         \
    ar[4] = fmaf(WRb, hq2.z, ar[4]); az[4] = fmaf(WZb, hq2.z, az[4]);        \
    AN[4] = fmaf(WNb, hq2.z, AN[4]);                                         \
  }

// Pair with LDS weights: packed row = [ (wr,wz) pairs (128 dw) | wn (64) ]
#define PAIR_LDS(WBASE, M, HB, AN)                                           \
  {                                                                          \
    const int ra_ = (WBASE) + (2 * (M)) * 192;                               \
    const int rb_ = ra_ + 192;                                               \
    const f2 wa_ = *(const f2*)&lds[ra_ + j2];                               \
    const float wna_ = lds[ra_ + 128 + j];                                   \
    const f2 wb_ = *(const f2*)&lds[rb_ + j2];                               \
    const float wnb_ = lds[rb_ + 128 + j];                                   \
    PAIR_FMA(wa_.x, wa_.y, wna_, wb_.x, wb_.y, wnb_, HB, M, AN)              \
  }

// layer-0 x-part for one seq (6 components via readlane)
#define XPART(S, ARx, AZx, ANXx)                       \
  _Pragma("unroll") for (int c = 0; c < 6; ++c) {      \
    const float xk = bcast(xcur, (S) * 6 + c);         \
    ARx = fmaf(wx0[c][0], xk, ARx);                    \
    AZx = fmaf(wx0[c][1], xk, AZx);                    \
    ANXx = fmaf(wx0[c][2], xk, ANXx);                  \
  }

__launch_bounds__(512)
__global__ void gru2_enc(const float* __restrict__ x,      // [10240][60][6]
                         const float* __restrict__ w3e0,   // [70][192] j3 (reg rows)
                         const float* __restrict__ e2h0,   // [52][192] pair-packed
                         const float* __restrict__ e2w1,   // [128][192] pair-packed
                         const float* __restrict__ bih0, const float* __restrict__ bhh0,
                         const float* __restrict__ bih1, const float* __restrict__ bhh1,
                         float* __restrict__ h_out) {      // [10240][64]
  extern __shared__ float lds[];
  const int tid = threadIdx.x;
  const int wave = tid >> 6;
  const int j = tid & 63;
  const int j3 = j * 3;
  const int j2 = j * 2;
  const int h0base = L_HB + wave * 768;        // [64][6] this wave's h0
  const int h1base = h0base + 384;             // [64][6] this wave's h1

  // cooperative weight load into LDS (coalesced float4)
  {
    const float4* s0 = (const float4*)e2h0;
    for (int i = tid; i < 9984 / 4; i += 512) ((float4*)(lds + L_W0))[i] = s0[i];
    const float4* s1 = (const float4*)e2w1;
    for (int i = tid; i < 24576 / 4; i += 512) ((float4*)(lds + L_W1))[i] = s1[i];
  }
  // register weights: Wih0 (rows 0..5) + Whh0 rows 52..63 (w3e0 rows 58..69)
  float wx0[6][3], wh_hi[12][3];
#pragma unroll
  for (int k = 0; k < 6; ++k)
#pragma unroll
    for (int g = 0; g < 3; ++g) wx0[k][g] = w3e0[k * 192 + j3 + g];
#pragma unroll
  for (int r = 0; r < 12; ++r)
#pragma unroll
    for (int g = 0; g < 3; ++g) wh_hi[r][g] = w3e0[(58 + r) * 192 + j3 + g];

  const float br0 = bih0[j] + bhh0[j];
  const float bz0 = bih0[64 + j] + bhh0[64 + j];
  const float bxn0 = bih0[128 + j];
  const float bhn0 = bhh0[128 + j];
  const float br1 = bih1[j] + bhh1[j];
  const float bz1 = bih1[64 + j] + bhh1[64 + j];
  const float bxn1 = bih1[128 + j];
  const float bhn1 = bhh1[128 + j];

  float h0r[E_SPW], h1r[E_SPW];
#pragma unroll
  for (int s = 0; s < E_SPW; ++s) { h0r[s] = 0.0f; h1r[s] = 0.0f; }
#pragma unroll
  for (int s = 0; s < 6; ++s) {     // zero all 6 slots incl. pad
    lds[h0base + j * 6 + s] = 0.0f;
    lds[h1base + j * 6 + s] = 0.0f;
  }
  __syncthreads();  // weights + zeroed state visible; the only barrier

  const int seq0 = blockIdx.x * (E_WAVES * E_SPW) + wave * E_SPW;
  // x carrier: lane j<30 holds component ci of seq si (readlane in XPART)
  const int si = j / 6;
  const int ci = j - si * 6;
  const bool xlane = (j < 6 * E_SPW);
  const float* xg = x + (size_t)(seq0 + si) * 360 + ci;

  float xcur = xlane ? xg[0] : 0.0f;  // t = 0

  for (int t = 0; t < 60; ++t) {
    float xnext = (xlane && t + 1 < 60) ? xg[(size_t)(t + 1) * 6] : 0.0f;

    float ar[E_SPW], az[E_SPW], anx[E_SPW], anh[E_SPW];
#pragma unroll
    for (int s = 0; s < E_SPW; ++s) { ar[s] = 0.f; az[s] = 0.f; anx[s] = 0.f; anh[s] = 0.f; }

    // ---- layer0 h-part: rows 0..51 LDS (26 pairs, ROLLED), 52..63 regs
#pragma clang loop unroll_count(2)
    for (int m = 0; m < 26; ++m) PAIR_LDS(L_W0, m, h0base, anh)
#pragma unroll
    for (int p = 0; p < 6; ++p)
      PAIR_FMA(wh_hi[2 * p][0], wh_hi[2 * p][1], wh_hi[2 * p][2],
               wh_hi[2 * p + 1][0], wh_hi[2 * p + 1][1], wh_hi[2 * p + 1][2],
               h0base, 26 + p, anh)

    XPART(0, ar[0], az[0], anx[0])
    XPART(1, ar[1], az[1], anx[1])
    XPART(2, ar[2], az[2], anx[2])
    XPART(3, ar[3], az[3], anx[3])
    XPART(4, ar[4], az[4], anx[4])

    // ---- layer0 epilogue: lane j owns all 3 gates of unit j
#pragma unroll
    for (int s = 0; s < E_SPW; ++s) {
      float r = sigm(ar[s] + br0);
      float z = sigm(az[s] + bz0);
      float n = tanh_f(anx[s] + bxn0 + r * (anh[s] + bhn0));
      h0r[s] = (1.0f - z) * n + z * h0r[s];
    }
    // publish fresh h0 (wave-private; same-wave ds ordering)
    {
      *(f2*)&lds[h0base + j * 6] = (f2){h0r[0], h0r[1]};
      *(f2*)&lds[h0base + j * 6 + 2] = (f2){h0r[2], h0r[3]};
      lds[h0base + j * 6 + 4] = h0r[4];
    }

    // ---- layer1 ----
#pragma unroll
    for (int s = 0; s < E_SPW; ++s) { ar[s] = 0.f; az[s] = 0.f; anx[s] = 0.f; anh[s] = 0.f; }
    // x-part over fresh h0 (W1 rows 0..63, 32 pairs)
#pragma clang loop unroll_count(2)
    for (int m = 0; m < 32; ++m) PAIR_LDS(L_W1, m, h0base, anx)
    // h-part over h1_old (W1 rows 64..127)
#pragma clang loop unroll_count(2)
    for (int m = 0; m < 32; ++m) PAIR_LDS(L_W1 + 64 * 192, m, h1base, anh)

#pragma unroll
    for (int s = 0; s < E_SPW; ++s) {
      float r = sigm(ar[s] + br1);
      float z = sigm(az[s] + bz1);
      float n = tanh_f(anx[s] + bxn1 + r * (anh[s] + bhn1));
      h1r[s] = (1.0f - z) * n + z * h1r[s];
    }
    // publish fresh h1
    {
      *(f2*)&lds[h1base + j * 6] = (f2){h1r[0], h1r[1]};
      *(f2*)&lds[h1base + j * 6 + 2] = (f2){h1r[2], h1r[3]};
      lds[h1base + j * 6 + 4] = h1r[4];
    }

    xcur = xnext;
  }

#pragma unroll
  for (int s = 0; s < E_SPW; ++s)
    h_out[(size_t)(seq0 + s) * 64 + j] = h1r[s];
}

// ---------------------------------------------------------------------------
// Single-layer GRU for the ALSTM (I = 64). Unchanged (validated; small share
// of runtime). 8 waves/block, 1 seq/wave, grid 64.
// ---------------------------------------------------------------------------
constexpr int A_W_DW = 128 * 192;  // 24576
constexpr int A_WAVES = 8;
constexpr int A_LDS = (A_W_DW + A_WAVES * 128) * 4;  // 102400 B

__launch_bounds__(512, 2)
__global__ void gru1(const float* __restrict__ xin,  // [N][T][64]
                     const float* __restrict__ w3,   // [128][192]
                     const float* __restrict__ bih, const float* __restrict__ bhh,
                     int T,
                     float* __restrict__ rout) {     // [N][T][64]
  extern __shared__ float lds[];
  const int tid = threadIdx.x;
  const int wave = tid >> 6;
  const int j = tid & 63;
  const int j3 = j * 3;
  const int XB = A_W_DW + wave * 128;  // [0..63]=x_t, [64..127]=h

  {
    const float4* sp = (const float4*)w3;
    for (int i = tid; i < A_W_DW / 4; i += 512) ((float4*)lds)[i] = sp[i];
  }
  const float br = bih[j] + bhh[j];
  const float bz = bih[64 + j] + bhh[64 + j];
  const float bxn = bih[128 + j];
  const float bhn = bhh[128 + j];

  float hr = 0.0f;
  lds[XB + 64 + j] = 0.0f;
  __syncthreads();

  const int seq = blockIdx.x * A_WAVES + wave;
  const float* xs = xin + (size_t)seq * T * 64;

#define A_QUAD(WROW0, HOFF, AN)                                            \
  {                                                                        \
    float4 hv = *(const float4*)&lds[XB + (HOFF)];                         \
    _Pragma("unroll") for (int c = 0; c < 4; ++c) {                        \
      const float wr = lds[((WROW0) + c) * 192 + j3];                      \
      const float wz = lds[((WROW0) + c) * 192 + j3 + 1];                  \
      const float wn = lds[((WROW0) + c) * 192 + j3 + 2];                  \
      const float hc = (c == 0) ? hv.x : (c == 1) ? hv.y                   \
                      : (c == 2) ? hv.z : hv.w;                            \
      ar = fmaf(wr, hc, ar);                                               \
      az = fmaf(wz, hc, az);                                               \
      AN = fmaf(wn, hc, AN);                                               \
    }                                                                      \
  }

  float xcur = xs[j];  // t = 0
  for (int t = 0; t < T; ++t) {
    float xnext = (t + 1 < T) ? xs[(size_t)(t + 1) * 64 + j] : 0.0f;
    lds[XB + j] = xcur;  // wave-private; ordered by lgkmcnt

    float ar = 0.f, az = 0.f, anx = 0.f, anh = 0.f;
#pragma unroll
    for (int kq = 0; kq < 16; ++kq) A_QUAD(kq * 4, kq * 4, anx);        // input
#pragma unroll
    for (int kq = 0; kq < 16; ++kq) A_QUAD(64 + kq * 4, 64 + kq * 4, anh);  // rec

    float r = sigm(ar + br);
    float z = sigm(az + bz);
    float n = tanh_f(anx + bxn + r * (anh + bhn));
    float h = (1.0f - z) * n + z * hr;
    hr = h;
    lds[XB + 64 + j] = h;
    rout[((size_t)seq * T + t) * 64 + j] = h;
    xcur = xnext;
  }
#undef A_QUAD
}

// ---------------------------------------------------------------------------
// Weight prep. Sections (8 blocks each):
//  0: w3e0 [70][192] j3-interleave (register rows; I=6)
//  1: e2h0 [52][192] pair-packed  <- Whh0 rows 0..51
//  2: e2w1 [128][192] pair-packed <- Wih1 (k<64) / Whh1 (k>=64)
//  3: a0   [128][192] j3-interleave (ALSTM L0)
//  4: a1   [128][192] j3-interleave (ALSTM L1)
// pair-packed row: rem<128 -> jj=rem>>1, g=rem&1 ((wr,wz) pairs);
//                  rem>=128 -> jj=rem-128, g=2 (wn plane)
// ---------------------------------------------------------------------------
__global__ void w3_prep(const float* __restrict__ Wih0, const float* __restrict__ Whh0,
                        const float* __restrict__ Wih1, const float* __restrict__ Whh1,
                        const float* __restrict__ aWih0, const float* __restrict__ aWhh0,
                        const float* __restrict__ aWih1, const float* __restrict__ aWhh1,
                        float* __restrict__ d_e0, float* __restrict__ d_h0,
                        float* __restrict__ d_w1,
                        float* __restrict__ d_a0, float* __restrict__ d_a1) {
  const int sec = blockIdx.x >> 3;
  const int bi = blockIdx.x & 7;

  if (sec == 0) {  // old j3 format, encoder L0 (I=6): [70][192]
    for (int idx = bi * blockDim.x + threadIdx.x; idx < 70 * 192; idx += 8 * blockDim.x) {
      const int k = idx / 192;
      const int rem = idx - k * 192;
      const int jj = rem / 3;
      const int g = rem - jj * 3;
      d_e0[idx] = (k < 6) ? Wih0[(g * 64 + jj) * 6 + k]
                          : Whh0[(g * 64 + jj) * 64 + (k - 6)];
    }
  } else if (sec == 1) {  // pair-packed Whh0 rows 0..51
    for (int idx = bi * blockDim.x + threadIdx.x; idx < 52 * 192; idx += 8 * blockDim.x) {
      const int k = idx / 192;
      const int rem = idx - k * 192;
      int jj, g;
      if (rem < 128) { jj = rem >> 1; g = rem & 1; }
      else           { jj = rem - 128; g = 2; }
      d_h0[idx] = Whh0[(g * 64 + jj) * 64 + k];
    }
  } else if (sec == 2) {  // pair-packed W1 (Wih1 | Whh1)
    for (int idx = bi * blockDim.x + threadIdx.x; idx < 128 * 192; idx += 8 * blockDim.x) {
      const int k = idx / 192;
      const int rem = idx - k * 192;
      int jj, g;
      if (rem < 128) { jj = rem >> 1; g = rem & 1; }
      else           { jj = rem - 128; g = 2; }
      d_w1[idx] = (k < 64) ? Wih1[(g * 64 + jj) * 64 + k]
                           : Whh1[(g * 64 + jj) * 64 + (k - 64)];
    }
  } else {  // ALSTM j3 format: [128][192]
    const float* Wih = (sec == 3) ? aWih0 : aWih1;
    const float* Whh = (sec == 3) ? aWhh0 : aWhh1;
    float* dst = (sec == 3) ? d_a0 : d_a1;
    for (int idx = bi * blockDim.x + threadIdx.x; idx < 128 * 192; idx += 8 * blockDim.x) {
      const int k = idx / 192;
      const int rem = idx - k * 192;
      const int jj = rem / 3;
      const int g = rem - jj * 3;
      dst[idx] = (k < 64) ? Wih[(g * 64 + jj) * 64 + k] : Whh[(g * 64 + jj) * 64 + (k - 64)];
    }
  }
}

// ---------------------------------------------------------------------------
// GAT algebraic prep
// ---------------------------------------------------------------------------
__global__ void gat_prep(const float* __restrict__ tW, const float* __restrict__ tb,
                         const float* __restrict__ a, float* __restrict__ vbuf) {
  const int d = threadIdx.x;  // 64 threads
  float vd = 0.0f, vs = 0.0f;
  for (int e = 0; e < 64; ++e) {
    float w = tW[e * 64 + d];
    vd = fmaf(w, a[e], vd);
    vs = fmaf(w, a[64 + e], vs);
  }
  vbuf[d] = vd;
  vbuf[64 + d] = vs;
  if (d == 0) {
    float cd = 0.0f, cs = 0.0f;
    for (int e = 0; e < 64; ++e) {
      cd = fmaf(tb[e], a[e], cd);
      cs = fmaf(tb[e], a[64 + e], cs);
    }
    vbuf[128] = cd;
    vbuf[129] = cs;
  }
}

__global__ void gat_svals(const float* __restrict__ h_enc, const float* __restrict__ vbuf,
                          float* __restrict__ s_src, float* __restrict__ s_dst) {
  const int wave = (blockIdx.x * blockDim.x + threadIdx.x) >> 6;
  const int lane = threadIdx.x & 63;
  float h = h_enc[(size_t)wave * 64 + lane];
  float pd = h * vbuf[lane];
  float ps = h * vbuf[64 + lane];
  pd = wave_sum(pd);
  ps = wave_sum(ps);
  if (lane == 0) {
    s_dst[wave] = pd + vbuf[128];
    s_src[wave] = ps + vbuf[129];
  }
}

// ---------------------------------------------------------------------------
// Dense all-pairs attention per group k (m=512)
// ---------------------------------------------------------------------------
__launch_bounds__(256)
__global__ void gat_attn(const float* __restrict__ h_enc,
                         const float* __restrict__ s_src,
                         const float* __restrict__ s_dst,
                         float* __restrict__ hout) {
  const int k = blockIdx.x >> 7;
  const int tile = blockIdx.x & 127;
  const int wv = threadIdx.x >> 6;
  const int lane = threadIdx.x & 63;
  const int i = tile * 4 + wv;
  __shared__ float sdbuf[512];
  __shared__ __align__(16) float pbuf[4][512];

  for (int u = threadIdx.x; u < 512; u += 256) sdbuf[u] = s_dst[k * 512 + u];
  __syncthreads();

  const float si = s_src[k * 512 + i];
  float ev[8];
  float mx = -1e30f;
#pragma unroll
  for (int u = 0; u < 8; ++u) {
    ev[u] = lrelu(si + sdbuf[lane + u * 64]);
    mx = fmaxf(mx, ev[u]);
  }
  mx = wave_max(mx);
  float lsum = 0.0f;
#pragma unroll
  for (int u = 0; u < 8; ++u) {
    float p = __expf(ev[u] - mx);
    pbuf[wv][lane + u * 64] = p;
    lsum += p;
  }
  lsum = wave_sum(lsum);
  const float inv = fast_rcp(lsum);

  const float* hk = h_enc + (size_t)k * 512 * 64;
  const float4* pv = (const float4*)pbuf[wv];
  float acc0 = 0.0f, acc1 = 0.0f;
#pragma unroll 2
  for (int jj = 0; jj < 128; ++jj) {
    float4 p = pv[jj];
    const float* hp = hk + (size_t)(jj * 4) * 64 + lane;
    acc0 = fmaf(p.x, hp[0], acc0);
    acc1 = fmaf(p.y, hp[64], acc1);
    acc0 = fmaf(p.z, hp[128], acc0);
    acc1 = fmaf(p.w, hp[192], acc1);
  }
  hout[((size_t)k * 512 + i) * 64 + lane] =
      (acc0 + acc1) * inv + hk[(size_t)i * 64 + lane];
}

// ---------------------------------------------------------------------------
// Post-GAT transform + pred head + ALSTM input transform
// ---------------------------------------------------------------------------
__launch_bounds__(256)
__global__ void gat_out(const float* __restrict__ hin,
                        const float* __restrict__ fcW, const float* __restrict__ fcb,
                        const float* __restrict__ fcoW, const float* __restrict__ fcob,
                        const float* __restrict__ alinW, const float* __restrict__ alinb,
                        float* __restrict__ zout, float* __restrict__ pred) {
  const int wv = threadIdx.x >> 6;
  const int lane = threadIdx.x & 63;
  const int n = blockIdx.x * 4 + wv;  // [0,10240)
  const int k = n >> 9;
  const int i = n & 511;
  __shared__ __align__(16) float rbuf[4][64];
  __shared__ __align__(16) float rbuf2[4][64];

  float4 fw[16], aw[16];
  {
    const float4* p1 = (const float4*)(fcW + lane * 64);
    const float4* p2 = (const float4*)(alinW + lane * 64);
#pragma unroll
    for (int kk = 0; kk < 16; ++kk) fw[kk] = p1[kk];
#pragma unroll
    for (int kk = 0; kk < 16; ++kk) aw[kk] = p2[kk];
  }

  rbuf[wv][lane] = hin[(size_t)n * 64 + lane];
  float h2 = fcb[lane];
  const float4* rv = (const float4*)rbuf[wv];
#pragma unroll
  for (int kk = 0; kk < 16; ++kk) h2 = dot4(fw[kk], rv[kk], h2);

  if (k == 19) {
    float pv = lrelu(h2) * fcoW[lane];
    pv = wave_sum(pv);
    if (lane == 0) pred[i] = pv + fcob[0];
  }

  rbuf2[wv][lane] = h2;
  float zz = alinb[lane];
  const float4* rv2 = (const float4*)rbuf2[wv];
#pragma unroll
  for (int kk = 0; kk < 16; ++kk) zz = dot4(aw[kk], rv2[kk], zz);
  zout[((size_t)i * 20 + k) * 64 + lane] = tanh_f(zz);
}

// ---------------------------------------------------------------------------
// ALSTM attention head
// ---------------------------------------------------------------------------
__launch_bounds__(256)
__global__ void alstm_head(const float* __restrict__ r1,  // [512][20][64]
                           const float* __restrict__ W1,  // [32][64]
                           const float* __restrict__ b1,  // [32]
                           const float* __restrict__ W2,  // [32]
                           const float* __restrict__ Wo,  // [128]
                           const float* __restrict__ bo,  // [1]
                           float* __restrict__ alstm_out) {
  const int wv = threadIdx.x >> 6;
  const int lane = threadIdx.x & 63;
  const int i = blockIdx.x * 4 + wv;  // [0,512)
  const int e = lane & 31;
  __shared__ __align__(16) float rbuf[4][64];
  __shared__ float scb[4][20];

  float4 w1r[16];
  {
    const float4* p = (const float4*)(W1 + e * 64);
#pragma unroll
    for (int kk = 0; kk < 16; ++kk) w1r[kk] = p[kk];
  }
  const float b1e = b1[e];
  const float w2e = W2[e];

  for (int k = 0; k < 20; ++k) {
    rbuf[wv][lane] = r1[((size_t)i * 20 + k) * 64 + lane];
    float u = b1e;
    const float4* rp = (const float4*)rbuf[wv];
#pragma unroll
    for (int kk = 0; kk < 16; ++kk) u = dot4(w1r[kk], rp[kk], u);
    u = tanh_f(u) * w2e;
#pragma unroll
    for (int m = 16; m; m >>= 1) u += __shfl_xor(u, m);
    if (lane == 0) scb[wv][k] = u;
  }

  float mx = -1e30f;
#pragma unroll
  for (int k = 0; k < 20; ++k) mx = fmaxf(mx, scb[wv][k]);
  float p[20];
  float l = 0.0f;
#pragma unroll
  for (int k = 0; k < 20; ++k) {
    p[k] = __expf(scb[wv][k] - mx);
    l += p[k];
  }
  const float inv = fast_rcp(l);

  float oa = 0.0f, rlast = 0.0f;
#pragma unroll
  for (int k = 0; k < 20; ++k) {
    float rv = r1[((size_t)i * 20 + k) * 64 + lane];
    oa = fmaf(p[k], rv, oa);
    if (k == 19) rlast = rv;
  }
  oa *= inv;
  float v = fmaf(Wo[lane], rlast, Wo[64 + lane] * oa);
  v = wave_sum(v);
  if (lane == 0) alstm_out[i] = v + bo[0];
}

// ---------------------------------------------------------------------------
extern "C" void kernel_launch(void* const* d_in, const int* in_sizes, int n_in,
                              void* d_out, int out_size, void* d_ws, size_t ws_size,
                              hipStream_t stream) {
  const float* x      = (const float*)d_in[0];
  const float* Wih0   = (const float*)d_in[1];
  const float* Whh0   = (const float*)d_in[2];
  const float* bih0   = (const float*)d_in[3];
  const float* bhh0   = (const float*)d_in[4];
  const float* Wih1   = (const float*)d_in[5];
  const float* Whh1   = (const float*)d_in[6];
  const float* bih1   = (const float*)d_in[7];
  const float* bhh1   = (const float*)d_in[8];
  const float* transW = (const float*)d_in[9];
  const float* transb = (const float*)d_in[10];
  const float* a_vec  = (const float*)d_in[11];
  const float* fcW    = (const float*)d_in[12];
  const float* fcb    = (const float*)d_in[13];
  const float* fcoW   = (const float*)d_in[14];
  const float* fcob   = (const float*)d_in[15];
  const float* alinW  = (const float*)d_in[16];
  const float* alinb  = (const float*)d_in[17];
  const float* aWih0  = (const float*)d_in[18];
  const float* aWhh0  = (const float*)d_in[19];
  const float* abih0  = (const float*)d_in[20];
  const float* abhh0  = (const float*)d_in[21];
  const float* aWih1  = (const float*)d_in[22];
  const float* aWhh1  = (const float*)d_in[23];
  const float* abih1  = (const float*)d_in[24];
  const float* abhh1  = (const float*)d_in[25];
  const float* att1W  = (const float*)d_in[26];
  const float* att1b  = (const float*)d_in[27];
  const float* att2W  = (const float*)d_in[28];
  const float* aloutW = (const float*)d_in[29];
  const float* aloutb = (const float*)d_in[30];

  float* out = (float*)d_out;  // [0:512) alstm_out, [512:1024) pred

  float* W = (float*)d_ws;
  float* h_enc = W; W += 10240 * 64;      // reused as r0 (steps 7-8)
  float* vbuf  = W; W += 256;
  float* s_src = W; W += 10240;
  float* s_dst = W; W += 10240;
  float* hout  = W; W += 10240 * 64;
  float* zbuf  = W; W += 512 * 20 * 64;
  float* r1    = W; W += 512 * 20 * 64;
  float* w3a0  = W; W += 24576;
  float* w3a1  = W; W += 24576;
  // time-disjoint aliases: encoder weight buffers live in the zbuf region
  // (consumed at step 2; zbuf written at step 6).
  float* w3e0 = zbuf;                  // [70][192]  old fmt = 13440 dw
  float* e2h0 = zbuf + 13440;          // [52][192]  pair-packed = 9984 dw
  float* e2w1 = zbuf + 23424;          // [128][192] pair-packed = 24576 dw

  static bool attr_done = false;
  if (!attr_done) {
    hipFuncSetAttribute((const void*)gru2_enc,
                        hipFuncAttributeMaxDynamicSharedMemorySize, E_LDS);
    hipFuncSetAttribute((const void*)gru1,
                        hipFuncAttributeMaxDynamicSharedMemorySize, A_LDS);
    attr_done = true;
  }

  // 1) weight prep
  w3_prep<<<40, 256, 0, stream>>>(Wih0, Whh0, Wih1, Whh1, aWih0, aWhh0,
                                  aWih1, aWhh1, w3e0, e2h0, e2w1,
                                  w3a0, w3a1);
  // 2) fused 2-layer persistent GRU encoder: 256 blocks x 8 waves x SPW=5
  //    = 10240 seqs in ONE balanced round; pair-packed weights (b64+b32)
  //    + paired k-rows (3x b128 h) -> 3.5 DS ops/row
  gru2_enc<<<256, 512, E_LDS, stream>>>(x, w3e0, e2h0, e2w1,
                                        bih0, bhh0, bih1, bhh1, h_enc);
  // 3) GAT score-vector prep
  gat_prep<<<1, 64, 0, stream>>>(transW, transb, a_vec, vbuf);
  // 4) per-row s_src/s_dst
  gat_svals<<<2560, 256, 0, stream>>>(h_enc, vbuf, s_src, s_dst);
  // 5) dense attention + residual
  gat_attn<<<2560, 256, 0, stream>>>(h_enc, s_src, s_dst, hout);
  // 6) fc + pred head + ALSTM input transform (z in [i][k][64])
  gat_out<<<2560, 256, 0, stream>>>(hout, fcW, fcb, fcoW, fcob, alinW, alinb,
                                    zbuf, out + 512);
  // 7) ALSTM GRU layer 0: z -> r0 (reuses h_enc storage)
  gru1<<<64, 512, A_LDS, stream>>>(zbuf, w3a0, abih0, abhh0, 20, h_enc);
  // 8) ALSTM GRU layer 1: r0 -> r1
  gru1<<<64, 512, A_LDS, stream>>>(h_enc, w3a1, abih1, abhh1, 20, r1);
  // 9) ALSTM attention head -> alstm_out
  alstm_head<<<128, 256, 0, stream>>>(r1, att1W, att1b, att2W, aloutW, aloutb,
                                      out);
}